// Round 1
// baseline (4429.621 us; speedup 1.0000x reference)
//
#include <hip/hip_runtime.h>
#include <math.h>

#define NB 16
#define LQ 512
#define LKK 2048
#define DD 1024

constexpr int TM = 64, TN = 64, TK = 32;
constexpr int PAD = 4;

// C[m,n] = scale * sum_k A[m,k] * Bt[n,k]   (both K-contiguous, "NT")
__global__ __launch_bounds__(256) void gemm_nt_k(
    const float* __restrict__ A, int lda, long sA,
    const float* __restrict__ Bt, int ldb, long sB,
    float* __restrict__ C, int ldc, long sC,
    int K, float scale)
{
    __shared__ float As[TK][TM + PAD];
    __shared__ float Bs[TK][TN + PAD];
    const float* Ab = A + (long)blockIdx.z * sA;
    const float* Bb = Bt + (long)blockIdx.z * sB;
    float* Cb = C + (long)blockIdx.z * sC;
    const int m0 = blockIdx.y * TM, n0 = blockIdx.x * TN;
    const int tid = threadIdx.x;
    const int tn = tid & 15, tm = tid >> 4;
    float acc[4][4] = {};

    for (int k0 = 0; k0 < K; k0 += TK) {
        #pragma unroll
        for (int c = tid; c < (TM * TK) / 4; c += 256) {
            const int row = c >> 3, kc = (c & 7) << 2;
            const float4 g = *(const float4*)(Ab + (long)(m0 + row) * lda + (k0 + kc));
            As[kc + 0][row] = g.x; As[kc + 1][row] = g.y;
            As[kc + 2][row] = g.z; As[kc + 3][row] = g.w;
        }
        #pragma unroll
        for (int c = tid; c < (TN * TK) / 4; c += 256) {
            const int row = c >> 3, kc = (c & 7) << 2;
            const float4 g = *(const float4*)(Bb + (long)(n0 + row) * ldb + (k0 + kc));
            Bs[kc + 0][row] = g.x; Bs[kc + 1][row] = g.y;
            Bs[kc + 2][row] = g.z; Bs[kc + 3][row] = g.w;
        }
        __syncthreads();
        #pragma unroll
        for (int kk = 0; kk < TK; ++kk) {
            const float4 av = *(const float4*)&As[kk][tm << 2];
            const float4 bv = *(const float4*)&Bs[kk][tn << 2];
            const float a[4] = {av.x, av.y, av.z, av.w};
            const float b[4] = {bv.x, bv.y, bv.z, bv.w};
            #pragma unroll
            for (int i = 0; i < 4; ++i)
                #pragma unroll
                for (int j = 0; j < 4; ++j)
                    acc[i][j] = fmaf(a[i], b[j], acc[i][j]);
        }
        __syncthreads();
    }
    #pragma unroll
    for (int i = 0; i < 4; ++i) {
        float4 o = make_float4(acc[i][0] * scale, acc[i][1] * scale,
                               acc[i][2] * scale, acc[i][3] * scale);
        *(float4*)(Cb + (long)(m0 + (tm << 2) + i) * ldc + n0 + (tn << 2)) = o;
    }
}

// C[m,n] = sum_k A[m,k] * B[k,n]   (A K-contiguous, B N-contiguous, "NN")
__global__ __launch_bounds__(256) void gemm_nn_k(
    const float* __restrict__ A, int lda, long sA,
    const float* __restrict__ B, int ldb, long sB,
    float* __restrict__ C, int ldc, long sC,
    int K)
{
    __shared__ float As[TK][TM + PAD];
    __shared__ float Bs[TK][TN + PAD];
    const float* Ab = A + (long)blockIdx.z * sA;
    const float* Bb = B + (long)blockIdx.z * sB;
    float* Cb = C + (long)blockIdx.z * sC;
    const int m0 = blockIdx.y * TM, n0 = blockIdx.x * TN;
    const int tid = threadIdx.x;
    const int tn = tid & 15, tm = tid >> 4;
    float acc[4][4] = {};

    for (int k0 = 0; k0 < K; k0 += TK) {
        #pragma unroll
        for (int c = tid; c < (TM * TK) / 4; c += 256) {
            const int row = c >> 3, kc = (c & 7) << 2;
            const float4 g = *(const float4*)(Ab + (long)(m0 + row) * lda + (k0 + kc));
            As[kc + 0][row] = g.x; As[kc + 1][row] = g.y;
            As[kc + 2][row] = g.z; As[kc + 3][row] = g.w;
        }
        #pragma unroll
        for (int c = tid; c < (TK * TN) / 4; c += 256) {
            const int krow = c >> 4, nc = (c & 15) << 2;
            *(float4*)&Bs[krow][nc] =
                *(const float4*)(Bb + (long)(k0 + krow) * ldb + n0 + nc);
        }
        __syncthreads();
        #pragma unroll
        for (int kk = 0; kk < TK; ++kk) {
            const float4 av = *(const float4*)&As[kk][tm << 2];
            const float4 bv = *(const float4*)&Bs[kk][tn << 2];
            const float a[4] = {av.x, av.y, av.z, av.w};
            const float b[4] = {bv.x, bv.y, bv.z, bv.w};
            #pragma unroll
            for (int i = 0; i < 4; ++i)
                #pragma unroll
                for (int j = 0; j < 4; ++j)
                    acc[i][j] = fmaf(a[i], b[j], acc[i][j]);
        }
        __syncthreads();
    }
    #pragma unroll
    for (int i = 0; i < 4; ++i) {
        float4 o = make_float4(acc[i][0], acc[i][1], acc[i][2], acc[i][3]);
        *(float4*)(Cb + (long)(m0 + (tm << 2) + i) * ldc + n0 + (tn << 2)) = o;
    }
}

// C[m,n] = tanh(bias[n] + sum_{e<2048} cat[m,e]*W[n,e]), cat = [Qh | R]
__global__ __launch_bounds__(256) void gemm_cat_k(
    const float* __restrict__ Qh, const float* __restrict__ R,
    const float* __restrict__ W, const float* __restrict__ bias,
    float* __restrict__ C)
{
    __shared__ float As[TK][TM + PAD];
    __shared__ float Bs[TK][TN + PAD];
    const float* Qb = Qh + (long)blockIdx.z * LQ * DD;
    const float* Rb = R + (long)blockIdx.z * LQ * DD;
    float* Cb = C + (long)blockIdx.z * LQ * DD;
    const int m0 = blockIdx.y * TM, n0 = blockIdx.x * TN;
    const int tid = threadIdx.x;
    const int tn = tid & 15, tm = tid >> 4;
    float acc[4][4] = {};

    for (int k0 = 0; k0 < 2 * DD; k0 += TK) {
        const float* src = (k0 < DD) ? Qb : Rb;
        const int kb = (k0 < DD) ? k0 : k0 - DD;
        #pragma unroll
        for (int c = tid; c < (TM * TK) / 4; c += 256) {
            const int row = c >> 3, kc = (c & 7) << 2;
            const float4 g = *(const float4*)(src + (long)(m0 + row) * DD + (kb + kc));
            As[kc + 0][row] = g.x; As[kc + 1][row] = g.y;
            As[kc + 2][row] = g.z; As[kc + 3][row] = g.w;
        }
        #pragma unroll
        for (int c = tid; c < (TN * TK) / 4; c += 256) {
            const int row = c >> 3, kc = (c & 7) << 2;
            const float4 g = *(const float4*)(W + (long)(n0 + row) * (2 * DD) + (k0 + kc));
            Bs[kc + 0][row] = g.x; Bs[kc + 1][row] = g.y;
            Bs[kc + 2][row] = g.z; Bs[kc + 3][row] = g.w;
        }
        __syncthreads();
        #pragma unroll
        for (int kk = 0; kk < TK; ++kk) {
            const float4 av = *(const float4*)&As[kk][tm << 2];
            const float4 bv = *(const float4*)&Bs[kk][tn << 2];
            const float a[4] = {av.x, av.y, av.z, av.w};
            const float b[4] = {bv.x, bv.y, bv.z, bv.w};
            #pragma unroll
            for (int i = 0; i < 4; ++i)
                #pragma unroll
                for (int j = 0; j < 4; ++j)
                    acc[i][j] = fmaf(a[i], b[j], acc[i][j]);
        }
        __syncthreads();
    }
    #pragma unroll
    for (int i = 0; i < 4; ++i) {
        float4 o;
        o.x = tanhf(acc[i][0] + bias[n0 + (tn << 2) + 0]);
        o.y = tanhf(acc[i][1] + bias[n0 + (tn << 2) + 1]);
        o.z = tanhf(acc[i][2] + bias[n0 + (tn << 2) + 2]);
        o.w = tanhf(acc[i][3] + bias[n0 + (tn << 2) + 3]);
        *(float4*)(Cb + (long)(m0 + (tm << 2) + i) * DD + n0 + (tn << 2)) = o;
    }
}

// in-place softmax over rows of 2048
__global__ __launch_bounds__(256) void softmax_rows(float* __restrict__ S) {
    __shared__ float red[8];
    float* p = S + (size_t)blockIdx.x * LKK;
    const int tid = threadIdx.x;
    float4 v0 = ((const float4*)p)[tid];
    float4 v1 = ((const float4*)p)[tid + 256];
    float m = fmaxf(fmaxf(fmaxf(v0.x, v0.y), fmaxf(v0.z, v0.w)),
                    fmaxf(fmaxf(v1.x, v1.y), fmaxf(v1.z, v1.w)));
    #pragma unroll
    for (int off = 32; off > 0; off >>= 1) m = fmaxf(m, __shfl_down(m, off));
    if ((tid & 63) == 0) red[tid >> 6] = m;
    __syncthreads();
    m = fmaxf(fmaxf(red[0], red[1]), fmaxf(red[2], red[3]));
    v0.x = expf(v0.x - m); v0.y = expf(v0.y - m);
    v0.z = expf(v0.z - m); v0.w = expf(v0.w - m);
    v1.x = expf(v1.x - m); v1.y = expf(v1.y - m);
    v1.z = expf(v1.z - m); v1.w = expf(v1.w - m);
    float s = v0.x + v0.y + v0.z + v0.w + v1.x + v1.y + v1.z + v1.w;
    #pragma unroll
    for (int off = 32; off > 0; off >>= 1) s += __shfl_down(s, off);
    if ((tid & 63) == 0) red[4 + (tid >> 6)] = s;
    __syncthreads();
    s = red[4] + red[5] + red[6] + red[7];
    const float inv = 1.0f / s;
    v0.x *= inv; v0.y *= inv; v0.z *= inv; v0.w *= inv;
    v1.x *= inv; v1.y *= inv; v1.z *= inv; v1.w *= inv;
    ((float4*)p)[tid] = v0;
    ((float4*)p)[tid + 256] = v1;
}

extern "C" void kernel_launch(void* const* d_in, const int* in_sizes, int n_in,
                              void* d_out, int out_size, void* d_ws, size_t ws_size,
                              hipStream_t stream) {
    const float* Q    = (const float*)d_in[0];
    const float* Km   = (const float*)d_in[1];
    const float* V    = (const float*)d_in[2];
    const float* W    = (const float*)d_in[3];
    const float* bias = (const float*)d_in[4];

    float* outQ = (float*)d_out;                       // [16,512,1024]
    float* S    = outQ + (size_t)NB * LQ * DD;         // attn region, used as scores scratch every hop
    float* R    = (float*)d_ws;                        // [16,512,1024] scratch
    float* T    = R + (size_t)NB * LQ * DD;            // Qh staging [16,512,1024]

    const float scale = 0.03125f;                      // 1/sqrt(1024)
    dim3 blk(256);
    dim3 gS(LKK / TN, LQ / TM, NB);
    dim3 gR(DD / TN, LQ / TM, NB);

    for (int h = 0; h < 3; ++h) {
        const float* Qh = (h == 0) ? Q : (h == 1 ? (const float*)T : (const float*)outQ);
        float* cout = (h == 1) ? outQ : T;

        gemm_nt_k<<<gS, blk, 0, stream>>>(Qh, DD, (long)LQ * DD,
                                          Km, DD, (long)LKK * DD,
                                          S, LKK, (long)LQ * LKK,
                                          DD, scale);
        softmax_rows<<<NB * LQ, blk, 0, stream>>>(S);
        gemm_nn_k<<<gR, blk, 0, stream>>>(S, LKK, (long)LQ * LKK,
                                          V, DD, (long)LKK * DD,
                                          R, DD, (long)LQ * DD,
                                          LKK);
        gemm_cat_k<<<gR, blk, 0, stream>>>(Qh, R, W, bias, cout);
    }
    hipMemcpyAsync(outQ, T, (size_t)NB * LQ * DD * sizeof(float),
                   hipMemcpyDeviceToDevice, stream);
}

// Round 2
// 690.241 us; speedup vs baseline: 6.4175x; 6.4175x over previous
//
#include <hip/hip_runtime.h>
#include <math.h>

#define NB 16
#define LQ 512
#define LKK 2048
#define DD 1024

typedef _Float16 half8 __attribute__((ext_vector_type(8)));
typedef _Float16 half4 __attribute__((ext_vector_type(4)));
typedef float f32x4 __attribute__((ext_vector_type(4)));

__device__ __forceinline__ void gl_lds16(const void* g, void* l) {
    __builtin_amdgcn_global_load_lds(
        (const __attribute__((address_space(1))) void*)g,
        (__attribute__((address_space(3))) void*)l, 16, 0, 0);
}

// ---------------------------------------------------------------------------
// f16 MFMA NT-GEMM: C[m,n] = epilogue( sum_k A[m,k] * B[n,k] )
// A split into lo/hi at ksplit (for the concat GEMM). 128x128 tile, BK=64.
// LDS staged via global_load_lds(16B) with XOR-swizzled source, swizzled reads.
// mode 0: out32 = acc*scale   mode 1: out16 = acc   mode 2: tanh(acc+bias[n])
// ---------------------------------------------------------------------------
__global__ __launch_bounds__(256) void gemm_f16_nt(
    const _Float16* __restrict__ Alo, long sAlo, int lda_lo,
    const _Float16* __restrict__ Ahi, long sAhi, int lda_hi,
    int ksplit,
    const _Float16* __restrict__ B, long sB, int ldb,
    int K, int mode, float scale,
    float* __restrict__ out32, long s32, int ldc32,
    _Float16* __restrict__ out16, long s16, int ldc16,
    const float* __restrict__ bias)
{
    __shared__ _Float16 lsA[128 * 64];
    __shared__ _Float16 lsB[128 * 64];
    const int tid = threadIdx.x;
    const int w = tid >> 6, l = tid & 63;
    const int wr = w >> 1, wc = w & 1;
    const int z = blockIdx.z;
    const int m0 = blockIdx.y * 128, n0 = blockIdx.x * 128;

    const _Float16* Abase_lo = Alo + (size_t)z * sAlo + (size_t)m0 * lda_lo;
    const _Float16* Abase_hi = Ahi ? (Ahi + (size_t)z * sAhi + (size_t)m0 * lda_hi) : (const _Float16*)0;
    const _Float16* Bbase = B + (size_t)z * sB + (size_t)n0 * ldb;

    const int srow = l >> 3;                  // row within the 8-row chunk
    const int sswz = ((l & 7) ^ srow) << 3;   // swizzled f16-element slot offset

    f32x4 acc[4][4] = {};

    for (int k0 = 0; k0 < K; k0 += 64) {
        const _Float16* Ap; int kloc, ldaA;
        if (k0 < ksplit) { Ap = Abase_lo; kloc = k0;          ldaA = lda_lo; }
        else             { Ap = Abase_hi; kloc = k0 - ksplit; ldaA = lda_hi; }
        #pragma unroll
        for (int i = 0; i < 4; ++i) {
            const int c = w * 4 + i;
            const int row = c * 8 + srow;
            gl_lds16(Ap + (size_t)row * ldaA + kloc + sswz, &lsA[c * 512]);
        }
        #pragma unroll
        for (int i = 0; i < 4; ++i) {
            const int c = w * 4 + i;
            const int row = c * 8 + srow;
            gl_lds16(Bbase + (size_t)row * ldb + k0 + sswz, &lsB[c * 512]);
        }
        __syncthreads();

        half8 af[4][2], bf[4][2];
        const char* lA = (const char*)lsA;
        const char* lB = (const char*)lsB;
        const int rs = (l & 7) << 4;        // row-XOR bits (row&7)<<4
        const int cb = (l >> 4) << 4;       // 16B slot within 32-k half
        #pragma unroll
        for (int i = 0; i < 4; ++i) {
            const int rowa = wr * 64 + i * 16 + (l & 15);
            const int rowb = wc * 64 + i * 16 + (l & 15);
            #pragma unroll
            for (int kk = 0; kk < 2; ++kk) {
                af[i][kk] = *(const half8*)(lA + rowa * 128 + ((kk * 64 + cb) ^ rs));
                bf[i][kk] = *(const half8*)(lB + rowb * 128 + ((kk * 64 + cb) ^ rs));
            }
        }
        #pragma unroll
        for (int kk = 0; kk < 2; ++kk)
            #pragma unroll
            for (int i = 0; i < 4; ++i)
                #pragma unroll
                for (int j = 0; j < 4; ++j)
                    acc[i][j] = __builtin_amdgcn_mfma_f32_16x16x32_f16(
                        af[i][kk], bf[j][kk], acc[i][j], 0, 0, 0);
        __syncthreads();
    }

    const int lr = (l >> 4) * 4;
    const int lc = l & 15;
    if (mode == 0) {
        float* Cb = out32 + (size_t)z * s32;
        #pragma unroll
        for (int i = 0; i < 4; ++i)
            #pragma unroll
            for (int j = 0; j < 4; ++j) {
                const int n = n0 + wc * 64 + j * 16 + lc;
                #pragma unroll
                for (int r = 0; r < 4; ++r) {
                    const int m = m0 + wr * 64 + i * 16 + lr + r;
                    Cb[(size_t)m * ldc32 + n] = acc[i][j][r] * scale;
                }
            }
    } else if (mode == 1) {
        _Float16* Cb = out16 + (size_t)z * s16;
        #pragma unroll
        for (int i = 0; i < 4; ++i)
            #pragma unroll
            for (int j = 0; j < 4; ++j) {
                const int n = n0 + wc * 64 + j * 16 + lc;
                #pragma unroll
                for (int r = 0; r < 4; ++r) {
                    const int m = m0 + wr * 64 + i * 16 + lr + r;
                    Cb[(size_t)m * ldc16 + n] = (_Float16)acc[i][j][r];
                }
            }
    } else {
        float bv[4];
        #pragma unroll
        for (int j = 0; j < 4; ++j)
            bv[j] = bias[n0 + wc * 64 + j * 16 + lc];
        #pragma unroll
        for (int i = 0; i < 4; ++i)
            #pragma unroll
            for (int j = 0; j < 4; ++j) {
                const int n = n0 + wc * 64 + j * 16 + lc;
                #pragma unroll
                for (int r = 0; r < 4; ++r) {
                    const int m = m0 + wr * 64 + i * 16 + lr + r;
                    const float t = tanhf(acc[i][j][r] + bv[j]);
                    if (out16) out16[(size_t)z * s16 + (size_t)m * ldc16 + n] = (_Float16)t;
                    if (out32) out32[(size_t)z * s32 + (size_t)m * ldc32 + n] = t;
                }
            }
    }
}

// row softmax over 2048 f32; writes f16 attn to f16out (+row*f16stride);
// optionally writes normalized f32 back in place (final hop).
__global__ __launch_bounds__(256) void softmax_rows2(
    float* __restrict__ S, _Float16* __restrict__ f16out,
    long f16stride, int write_f32)
{
    __shared__ float red[8];
    const long row = blockIdx.x;
    float* p = S + row * LKK;
    const int tid = threadIdx.x;
    float4 v0 = ((const float4*)p)[tid];
    float4 v1 = ((const float4*)p)[tid + 256];
    float m = fmaxf(fmaxf(fmaxf(v0.x, v0.y), fmaxf(v0.z, v0.w)),
                    fmaxf(fmaxf(v1.x, v1.y), fmaxf(v1.z, v1.w)));
    #pragma unroll
    for (int off = 32; off > 0; off >>= 1) m = fmaxf(m, __shfl_down(m, off));
    if ((tid & 63) == 0) red[tid >> 6] = m;
    __syncthreads();
    m = fmaxf(fmaxf(red[0], red[1]), fmaxf(red[2], red[3]));
    v0.x = expf(v0.x - m); v0.y = expf(v0.y - m);
    v0.z = expf(v0.z - m); v0.w = expf(v0.w - m);
    v1.x = expf(v1.x - m); v1.y = expf(v1.y - m);
    v1.z = expf(v1.z - m); v1.w = expf(v1.w - m);
    float s = v0.x + v0.y + v0.z + v0.w + v1.x + v1.y + v1.z + v1.w;
    #pragma unroll
    for (int off = 32; off > 0; off >>= 1) s += __shfl_down(s, off);
    if ((tid & 63) == 0) red[4 + (tid >> 6)] = s;
    __syncthreads();
    s = red[4] + red[5] + red[6] + red[7];
    const float inv = 1.0f / s;
    v0.x *= inv; v0.y *= inv; v0.z *= inv; v0.w *= inv;
    v1.x *= inv; v1.y *= inv; v1.z *= inv; v1.w *= inv;
    if (write_f32) {
        ((float4*)p)[tid] = v0;
        ((float4*)p)[tid + 256] = v1;
    }
    _Float16* q = f16out + row * f16stride;
    half4 h0 = { (_Float16)v0.x, (_Float16)v0.y, (_Float16)v0.z, (_Float16)v0.w };
    half4 h1 = { (_Float16)v1.x, (_Float16)v1.y, (_Float16)v1.z, (_Float16)v1.w };
    *(half4*)(q + tid * 4) = h0;            // after the reduction barriers:
    *(half4*)(q + 1024 + tid * 4) = h1;     // all f32 reads already done
}

__global__ __launch_bounds__(256) void cvt_f32_to_f16(
    const float* __restrict__ in, _Float16* __restrict__ out, long n)
{
    const long i = ((long)blockIdx.x * 256 + threadIdx.x) * 8;
    if (i + 8 > n) return;
    float4 a = *(const float4*)(in + i);
    float4 b = *(const float4*)(in + i + 4);
    half8 h = { (_Float16)a.x, (_Float16)a.y, (_Float16)a.z, (_Float16)a.w,
                (_Float16)b.x, (_Float16)b.y, (_Float16)b.z, (_Float16)b.w };
    *(half8*)(out + i) = h;
}

// V [B, Lk, D] f32 -> Vt [B, D, Lk] f16, 64x64 tiles via LDS
__global__ __launch_bounds__(256) void transpose_cvt_v(
    const float* __restrict__ V, _Float16* __restrict__ Vt)
{
    __shared__ _Float16 t[64][80];
    const int z = blockIdx.z;
    const int k0 = blockIdx.y * 64, d0 = blockIdx.x * 64;
    const float* Vb = V + (size_t)z * LKK * DD;
    _Float16* Vtb = Vt + (size_t)z * DD * LKK;
    const int r = threadIdx.x >> 2;
    const int c0 = (threadIdx.x & 3) * 16;
    #pragma unroll
    for (int j = 0; j < 4; ++j) {
        float4 v = *(const float4*)(Vb + (size_t)(k0 + r) * DD + d0 + c0 + j * 4);
        t[c0 + j * 4 + 0][r] = (_Float16)v.x;
        t[c0 + j * 4 + 1][r] = (_Float16)v.y;
        t[c0 + j * 4 + 2][r] = (_Float16)v.z;
        t[c0 + j * 4 + 3][r] = (_Float16)v.w;
    }
    __syncthreads();
    #pragma unroll
    for (int j = 0; j < 2; ++j) {
        half8 h = *(const half8*)&t[r][c0 + j * 8];
        *(half8*)(Vtb + (size_t)(d0 + r) * LKK + k0 + c0 + j * 8) = h;
    }
}

// ======================= round-1 f32 fallback kernels =======================
constexpr int TM = 64, TN = 64, TK = 32;
constexpr int PAD = 4;

__global__ __launch_bounds__(256) void gemm_nt_k(
    const float* __restrict__ A, int lda, long sA,
    const float* __restrict__ Bt, int ldb, long sB,
    float* __restrict__ C, int ldc, long sC, int K, float scale)
{
    __shared__ float As[TK][TM + PAD];
    __shared__ float Bs[TK][TN + PAD];
    const float* Ab = A + (long)blockIdx.z * sA;
    const float* Bb = Bt + (long)blockIdx.z * sB;
    float* Cb = C + (long)blockIdx.z * sC;
    const int m0 = blockIdx.y * TM, n0 = blockIdx.x * TN;
    const int tid = threadIdx.x;
    const int tn = tid & 15, tm = tid >> 4;
    float acc[4][4] = {};
    for (int k0 = 0; k0 < K; k0 += TK) {
        #pragma unroll
        for (int c = tid; c < (TM * TK) / 4; c += 256) {
            const int row = c >> 3, kc = (c & 7) << 2;
            const float4 g = *(const float4*)(Ab + (long)(m0 + row) * lda + (k0 + kc));
            As[kc + 0][row] = g.x; As[kc + 1][row] = g.y;
            As[kc + 2][row] = g.z; As[kc + 3][row] = g.w;
        }
        #pragma unroll
        for (int c = tid; c < (TN * TK) / 4; c += 256) {
            const int row = c >> 3, kc = (c & 7) << 2;
            const float4 g = *(const float4*)(Bb + (long)(n0 + row) * ldb + (k0 + kc));
            Bs[kc + 0][row] = g.x; Bs[kc + 1][row] = g.y;
            Bs[kc + 2][row] = g.z; Bs[kc + 3][row] = g.w;
        }
        __syncthreads();
        #pragma unroll
        for (int kk = 0; kk < TK; ++kk) {
            const float4 av = *(const float4*)&As[kk][tm << 2];
            const float4 bv = *(const float4*)&Bs[kk][tn << 2];
            const float a[4] = {av.x, av.y, av.z, av.w};
            const float b[4] = {bv.x, bv.y, bv.z, bv.w};
            #pragma unroll
            for (int i = 0; i < 4; ++i)
                #pragma unroll
                for (int j = 0; j < 4; ++j)
                    acc[i][j] = fmaf(a[i], b[j], acc[i][j]);
        }
        __syncthreads();
    }
    #pragma unroll
    for (int i = 0; i < 4; ++i) {
        float4 o = make_float4(acc[i][0] * scale, acc[i][1] * scale,
                               acc[i][2] * scale, acc[i][3] * scale);
        *(float4*)(Cb + (long)(m0 + (tm << 2) + i) * ldc + n0 + (tn << 2)) = o;
    }
}

__global__ __launch_bounds__(256) void gemm_nn_k(
    const float* __restrict__ A, int lda, long sA,
    const float* __restrict__ B, int ldb, long sB,
    float* __restrict__ C, int ldc, long sC, int K)
{
    __shared__ float As[TK][TM + PAD];
    __shared__ float Bs[TK][TN + PAD];
    const float* Ab = A + (long)blockIdx.z * sA;
    const float* Bb = B + (long)blockIdx.z * sB;
    float* Cb = C + (long)blockIdx.z * sC;
    const int m0 = blockIdx.y * TM, n0 = blockIdx.x * TN;
    const int tid = threadIdx.x;
    const int tn = tid & 15, tm = tid >> 4;
    float acc[4][4] = {};
    for (int k0 = 0; k0 < K; k0 += TK) {
        #pragma unroll
        for (int c = tid; c < (TM * TK) / 4; c += 256) {
            const int row = c >> 3, kc = (c & 7) << 2;
            const float4 g = *(const float4*)(Ab + (long)(m0 + row) * lda + (k0 + kc));
            As[kc + 0][row] = g.x; As[kc + 1][row] = g.y;
            As[kc + 2][row] = g.z; As[kc + 3][row] = g.w;
        }
        #pragma unroll
        for (int c = tid; c < (TK * TN) / 4; c += 256) {
            const int krow = c >> 4, nc = (c & 15) << 2;
            *(float4*)&Bs[krow][nc] =
                *(const float4*)(Bb + (long)(k0 + krow) * ldb + n0 + nc);
        }
        __syncthreads();
        #pragma unroll
        for (int kk = 0; kk < TK; ++kk) {
            const float4 av = *(const float4*)&As[kk][tm << 2];
            const float4 bv = *(const float4*)&Bs[kk][tn << 2];
            const float a[4] = {av.x, av.y, av.z, av.w};
            const float b[4] = {bv.x, bv.y, bv.z, bv.w};
            #pragma unroll
            for (int i = 0; i < 4; ++i)
                #pragma unroll
                for (int j = 0; j < 4; ++j)
                    acc[i][j] = fmaf(a[i], b[j], acc[i][j]);
        }
        __syncthreads();
    }
    #pragma unroll
    for (int i = 0; i < 4; ++i) {
        float4 o = make_float4(acc[i][0], acc[i][1], acc[i][2], acc[i][3]);
        *(float4*)(Cb + (long)(m0 + (tm << 2) + i) * ldc + n0 + (tn << 2)) = o;
    }
}

__global__ __launch_bounds__(256) void gemm_cat_k(
    const float* __restrict__ Qh, const float* __restrict__ R,
    const float* __restrict__ W, const float* __restrict__ bias,
    float* __restrict__ C)
{
    __shared__ float As[TK][TM + PAD];
    __shared__ float Bs[TK][TN + PAD];
    const float* Qb = Qh + (long)blockIdx.z * LQ * DD;
    const float* Rb = R + (long)blockIdx.z * LQ * DD;
    float* Cb = C + (long)blockIdx.z * LQ * DD;
    const int m0 = blockIdx.y * TM, n0 = blockIdx.x * TN;
    const int tid = threadIdx.x;
    const int tn = tid & 15, tm = tid >> 4;
    float acc[4][4] = {};
    for (int k0 = 0; k0 < 2 * DD; k0 += TK) {
        const float* src = (k0 < DD) ? Qb : Rb;
        const int kb = (k0 < DD) ? k0 : k0 - DD;
        #pragma unroll
        for (int c = tid; c < (TM * TK) / 4; c += 256) {
            const int row = c >> 3, kc = (c & 7) << 2;
            const float4 g = *(const float4*)(src + (long)(m0 + row) * DD + (kb + kc));
            As[kc + 0][row] = g.x; As[kc + 1][row] = g.y;
            As[kc + 2][row] = g.z; As[kc + 3][row] = g.w;
        }
        #pragma unroll
        for (int c = tid; c < (TN * TK) / 4; c += 256) {
            const int row = c >> 3, kc = (c & 7) << 2;
            const float4 g = *(const float4*)(W + (long)(n0 + row) * (2 * DD) + (k0 + kc));
            Bs[kc + 0][row] = g.x; Bs[kc + 1][row] = g.y;
            Bs[kc + 2][row] = g.z; Bs[kc + 3][row] = g.w;
        }
        __syncthreads();
        #pragma unroll
        for (int kk = 0; kk < TK; ++kk) {
            const float4 av = *(const float4*)&As[kk][tm << 2];
            const float4 bv = *(const float4*)&Bs[kk][tn << 2];
            const float a[4] = {av.x, av.y, av.z, av.w};
            const float b[4] = {bv.x, bv.y, bv.z, bv.w};
            #pragma unroll
            for (int i = 0; i < 4; ++i)
                #pragma unroll
                for (int j = 0; j < 4; ++j)
                    acc[i][j] = fmaf(a[i], b[j], acc[i][j]);
        }
        __syncthreads();
    }
    #pragma unroll
    for (int i = 0; i < 4; ++i) {
        float4 o;
        o.x = tanhf(acc[i][0] + bias[n0 + (tn << 2) + 0]);
        o.y = tanhf(acc[i][1] + bias[n0 + (tn << 2) + 1]);
        o.z = tanhf(acc[i][2] + bias[n0 + (tn << 2) + 2]);
        o.w = tanhf(acc[i][3] + bias[n0 + (tn << 2) + 3]);
        *(float4*)(Cb + (long)(m0 + (tm << 2) + i) * DD + n0 + (tn << 2)) = o;
    }
}

__global__ __launch_bounds__(256) void softmax_rows(float* __restrict__ S) {
    __shared__ float red[8];
    float* p = S + (size_t)blockIdx.x * LKK;
    const int tid = threadIdx.x;
    float4 v0 = ((const float4*)p)[tid];
    float4 v1 = ((const float4*)p)[tid + 256];
    float m = fmaxf(fmaxf(fmaxf(v0.x, v0.y), fmaxf(v0.z, v0.w)),
                    fmaxf(fmaxf(v1.x, v1.y), fmaxf(v1.z, v1.w)));
    #pragma unroll
    for (int off = 32; off > 0; off >>= 1) m = fmaxf(m, __shfl_down(m, off));
    if ((tid & 63) == 0) red[tid >> 6] = m;
    __syncthreads();
    m = fmaxf(fmaxf(red[0], red[1]), fmaxf(red[2], red[3]));
    v0.x = expf(v0.x - m); v0.y = expf(v0.y - m);
    v0.z = expf(v0.z - m); v0.w = expf(v0.w - m);
    v1.x = expf(v1.x - m); v1.y = expf(v1.y - m);
    v1.z = expf(v1.z - m); v1.w = expf(v1.w - m);
    float s = v0.x + v0.y + v0.z + v0.w + v1.x + v1.y + v1.z + v1.w;
    #pragma unroll
    for (int off = 32; off > 0; off >>= 1) s += __shfl_down(s, off);
    if ((tid & 63) == 0) red[4 + (tid >> 6)] = s;
    __syncthreads();
    s = red[4] + red[5] + red[6] + red[7];
    const float inv = 1.0f / s;
    v0.x *= inv; v0.y *= inv; v0.z *= inv; v0.w *= inv;
    v1.x *= inv; v1.y *= inv; v1.z *= inv; v1.w *= inv;
    ((float4*)p)[tid] = v0;
    ((float4*)p)[tid + 256] = v1;
}

// ===========================================================================
extern "C" void kernel_launch(void* const* d_in, const int* in_sizes, int n_in,
                              void* d_out, int out_size, void* d_ws, size_t ws_size,
                              hipStream_t stream) {
    const float* Q    = (const float*)d_in[0];
    const float* Km   = (const float*)d_in[1];
    const float* V    = (const float*)d_in[2];
    const float* W    = (const float*)d_in[3];
    const float* bias = (const float*)d_in[4];
    const float scale = 0.03125f;  // 1/sqrt(1024)
    dim3 blk(256);

    const size_t NEED = 155189248ULL;  // Kh 64M + Vt 64M + Wh 4M + Rh 16M
    if (ws_size >= NEED) {
        char* ws = (char*)d_ws;
        _Float16* Kh  = (_Float16*)ws;                    // [16,2048,1024]
        _Float16* Vt  = (_Float16*)(ws + 67108864);       // [16,1024,2048]
        _Float16* Wh  = (_Float16*)(ws + 134217728);      // [1024,2048]
        _Float16* Rh  = (_Float16*)(ws + 138412032);      // [16,512,1024]
        _Float16* attn2 = (_Float16*)ws;                  // alias Kh (dead at hop2 softmax)
        float* Fout = (float*)(ws + 33554432);            // alias Kh 2nd half

        _Float16* Qping = (_Float16*)d_out;               // d_out Q region, 1st half
        _Float16* Qpong = Qping + (size_t)NB * LQ * DD;   // 2nd half
        float* S = (float*)((char*)d_out + 33554432);     // d_out attn region (f32 scores)
        _Float16* Shtail = (_Float16*)S + 2048;           // f16 attn in row tails

        cvt_f32_to_f16<<<4096, blk, 0, stream>>>(Q, Qping, (long)NB * LQ * DD);
        cvt_f32_to_f16<<<16384, blk, 0, stream>>>(Km, Kh, (long)NB * LKK * DD);
        cvt_f32_to_f16<<<1024, blk, 0, stream>>>(W, Wh, (long)DD * 2 * DD);
        transpose_cvt_v<<<dim3(DD / 64, LKK / 64, NB), blk, 0, stream>>>(V, Vt);

        dim3 gS(LKK / 128, LQ / 128, NB);   // QK^T: 16 x 4 x 16
        dim3 gR(DD / 128, LQ / 128, NB);    // PV / cat: 8 x 4 x 16

        for (int h = 0; h < 3; ++h) {
            _Float16* qcur = (h == 1) ? Qpong : Qping;
            // ---- scores = Qh K^T * scale  (f32 into S)
            gemm_f16_nt<<<gS, blk, 0, stream>>>(
                qcur, (long)LQ * DD, DD, (const _Float16*)0, 0, 0, DD,
                Kh, (long)LKK * DD, DD, DD,
                0, scale, S, (long)LQ * LKK, LKK,
                (_Float16*)0, 0, 0, (const float*)0);
            // ---- softmax (f16 attn out; f32 in-place only on last hop)
            softmax_rows2<<<NB * LQ, blk, 0, stream>>>(
                S, (h == 2) ? attn2 : Shtail, (h == 2) ? 2048L : 4096L, (h == 2) ? 1 : 0);
            // ---- R = attn V   (f16 into Rh)
            gemm_f16_nt<<<gR, blk, 0, stream>>>(
                (h == 2) ? attn2 : Shtail,
                (h == 2) ? (long)LQ * 2048 : (long)LQ * 4096,
                (h == 2) ? 2048 : 4096,
                (const _Float16*)0, 0, 0, LKK,
                Vt, (long)DD * LKK, LKK, LKK,
                1, 1.0f, (float*)0, 0, 0,
                Rh, (long)LQ * DD, DD, (const float*)0);
            // ---- Qnext = tanh([Qh|R] W^T + b)
            _Float16* qn = (h == 0) ? Qpong : (h == 1) ? Qping : (_Float16*)0;
            float* fo = (h == 2) ? Fout : (float*)0;
            gemm_f16_nt<<<gR, blk, 0, stream>>>(
                qcur, (long)LQ * DD, DD,
                Rh, (long)LQ * DD, DD, DD,
                Wh, 0, 2 * DD, 2 * DD,
                2, 1.0f, fo, (long)LQ * DD, DD,
                qn, (long)LQ * DD, DD, bias);
        }
        hipMemcpyAsync(d_out, Fout, 33554432ULL, hipMemcpyDeviceToDevice, stream);
    } else {
        // -------- round-1 f32 fallback (proven; ws >= 67 MB) --------
        float* outQ = (float*)d_out;
        float* S    = outQ + (size_t)NB * LQ * DD;
        float* R    = (float*)d_ws;
        float* T    = R + (size_t)NB * LQ * DD;
        dim3 gS(LKK / TN, LQ / TM, NB);
        dim3 gR(DD / TN, LQ / TM, NB);
        for (int h = 0; h < 3; ++h) {
            const float* Qh = (h == 0) ? Q : (h == 1 ? (const float*)T : (const float*)outQ);
            float* cout = (h == 1) ? outQ : T;
            gemm_nt_k<<<gS, blk, 0, stream>>>(Qh, DD, (long)LQ * DD, Km, DD, (long)LKK * DD,
                                              S, LKK, (long)LQ * LKK, DD, scale);
            softmax_rows<<<NB * LQ, blk, 0, stream>>>(S);
            gemm_nn_k<<<gR, blk, 0, stream>>>(S, LKK, (long)LQ * LKK, V, DD, (long)LKK * DD,
                                              R, DD, (long)LQ * DD, LKK);
            gemm_cat_k<<<gR, blk, 0, stream>>>(Qh, R, W, bias, cout);
        }
        hipMemcpyAsync(outQ, T, (size_t)NB * LQ * DD * sizeof(float),
                       hipMemcpyDeviceToDevice, stream);
    }
}

// Round 3
// 618.851 us; speedup vs baseline: 7.1578x; 1.1154x over previous
//
#include <hip/hip_runtime.h>
#include <math.h>

#define NB 16
#define LQ 512
#define LKK 2048
#define DD 1024

typedef _Float16 half8 __attribute__((ext_vector_type(8)));
typedef _Float16 half4 __attribute__((ext_vector_type(4)));
typedef float f32x4 __attribute__((ext_vector_type(4)));

__device__ __forceinline__ void gl_lds16(const void* g, void* l) {
    __builtin_amdgcn_global_load_lds(
        (const __attribute__((address_space(1))) void*)g,
        (__attribute__((address_space(3))) void*)l, 16, 0, 0);
}

// ---------------------------------------------------------------------------
// f16 MFMA NT-GEMM: acc[m,n] = sum_k A[m,k] * B[n,k]  (128x128 tile, BK=64)
// A split lo/hi at ksplit (concat GEMM). global_load_lds(16B), XOR-swizzled.
// XCD-aware bijective block swizzle (requires nwg % 8 == 0 — all our grids).
// mode 0: P16 = exp(acc*scale), row partial sums -> partial[row*16+bx]
// mode 1: out16 = acc * (inv ? inv[row] : 1)
// mode 2: t = tanh(acc+bias[n]) -> out16 and/or out32
// mode 4: out32 = acc*scale (raw scores, hop 2)
// ---------------------------------------------------------------------------
__global__ __launch_bounds__(256) void gemm_f16_nt(
    const _Float16* __restrict__ Alo, long sAlo, int lda_lo,
    const _Float16* __restrict__ Ahi, long sAhi, int lda_hi,
    int ksplit,
    const _Float16* __restrict__ B, long sB, int ldb,
    int K, int mode, float scale,
    float* __restrict__ out32, long s32, int ldc32,
    _Float16* __restrict__ out16, long s16, int ldc16,
    const float* __restrict__ bias,
    float* __restrict__ partial, const float* __restrict__ inv)
{
    __shared__ _Float16 lsA[128 * 64];
    __shared__ _Float16 lsB[128 * 64];
    __shared__ float psum[128][2];
    const int tid = threadIdx.x;
    const int w = tid >> 6, l = tid & 63;
    const int wr = w >> 1, wc = w & 1;

    // T1: XCD-aware bijective swizzle of the flattened block id
    int id = blockIdx.x + gridDim.x * (blockIdx.y + gridDim.y * blockIdx.z);
    const int nwg = gridDim.x * gridDim.y * gridDim.z;
    id = (id & 7) * (nwg >> 3) + (id >> 3);
    const int bx = id % gridDim.x;
    const int t2 = id / gridDim.x;
    const int by = t2 % gridDim.y;
    const int z = t2 / gridDim.y;
    const int m0 = by * 128, n0 = bx * 128;

    const _Float16* Abase_lo = Alo + (size_t)z * sAlo + (size_t)m0 * lda_lo;
    const _Float16* Abase_hi = Ahi ? (Ahi + (size_t)z * sAhi + (size_t)m0 * lda_hi) : (const _Float16*)0;
    const _Float16* Bbase = B + (size_t)z * sB + (size_t)n0 * ldb;

    const int srow = l >> 3;                  // row within the 8-row chunk
    const int sswz = ((l & 7) ^ srow) << 3;   // swizzled f16-element slot offset

    f32x4 acc[4][4] = {};

    for (int k0 = 0; k0 < K; k0 += 64) {
        const _Float16* Ap; int kloc, ldaA;
        if (k0 < ksplit) { Ap = Abase_lo; kloc = k0;          ldaA = lda_lo; }
        else             { Ap = Abase_hi; kloc = k0 - ksplit; ldaA = lda_hi; }
        #pragma unroll
        for (int i = 0; i < 4; ++i) {
            const int c = w * 4 + i;
            const int row = c * 8 + srow;
            gl_lds16(Ap + (size_t)row * ldaA + kloc + sswz, &lsA[c * 512]);
        }
        #pragma unroll
        for (int i = 0; i < 4; ++i) {
            const int c = w * 4 + i;
            const int row = c * 8 + srow;
            gl_lds16(Bbase + (size_t)row * ldb + k0 + sswz, &lsB[c * 512]);
        }
        __syncthreads();

        half8 af[4][2], bf[4][2];
        const char* lA = (const char*)lsA;
        const char* lB = (const char*)lsB;
        const int rs = (l & 7) << 4;        // row-XOR bits (row&7)<<4
        const int cb = (l >> 4) << 4;       // 16B slot within 32-k half
        #pragma unroll
        for (int i = 0; i < 4; ++i) {
            const int rowa = wr * 64 + i * 16 + (l & 15);
            const int rowb = wc * 64 + i * 16 + (l & 15);
            #pragma unroll
            for (int kk = 0; kk < 2; ++kk) {
                af[i][kk] = *(const half8*)(lA + rowa * 128 + ((kk * 64 + cb) ^ rs));
                bf[i][kk] = *(const half8*)(lB + rowb * 128 + ((kk * 64 + cb) ^ rs));
            }
        }
        #pragma unroll
        for (int kk = 0; kk < 2; ++kk)
            #pragma unroll
            for (int i = 0; i < 4; ++i)
                #pragma unroll
                for (int j = 0; j < 4; ++j)
                    acc[i][j] = __builtin_amdgcn_mfma_f32_16x16x32_f16(
                        af[i][kk], bf[j][kk], acc[i][j], 0, 0, 0);
        __syncthreads();
    }

    const int lr = (l >> 4) * 4;
    const int lc = l & 15;
    if (mode == 0) {
        _Float16* Cb = out16 + (size_t)z * s16;
        float rsum[4][4];
        #pragma unroll
        for (int i = 0; i < 4; ++i)
            #pragma unroll
            for (int r = 0; r < 4; ++r) rsum[i][r] = 0.0f;
        #pragma unroll
        for (int i = 0; i < 4; ++i)
            #pragma unroll
            for (int j = 0; j < 4; ++j) {
                const int n = n0 + wc * 64 + j * 16 + lc;
                #pragma unroll
                for (int r = 0; r < 4; ++r) {
                    const int m = m0 + wr * 64 + i * 16 + lr + r;
                    const float e = __expf(acc[i][j][r] * scale);
                    Cb[(size_t)m * ldc16 + n] = (_Float16)e;
                    rsum[i][r] += e;
                }
            }
        #pragma unroll
        for (int i = 0; i < 4; ++i)
            #pragma unroll
            for (int r = 0; r < 4; ++r) {
                float s = rsum[i][r];
                s += __shfl_xor(s, 1);
                s += __shfl_xor(s, 2);
                s += __shfl_xor(s, 4);
                s += __shfl_xor(s, 8);
                rsum[i][r] = s;
            }
        if (lc == 0) {
            #pragma unroll
            for (int i = 0; i < 4; ++i)
                #pragma unroll
                for (int r = 0; r < 4; ++r)
                    psum[wr * 64 + i * 16 + lr + r][wc] = rsum[i][r];
        }
        __syncthreads();
        if (tid < 128)
            partial[((size_t)z * LQ + m0 + tid) * 16 + bx] = psum[tid][0] + psum[tid][1];
    } else if (mode == 1) {
        _Float16* Cb = out16 + (size_t)z * s16;
        float iv[4][4];
        #pragma unroll
        for (int i = 0; i < 4; ++i)
            #pragma unroll
            for (int r = 0; r < 4; ++r)
                iv[i][r] = inv ? inv[(size_t)z * LQ + m0 + wr * 64 + i * 16 + lr + r] : 1.0f;
        #pragma unroll
        for (int i = 0; i < 4; ++i)
            #pragma unroll
            for (int j = 0; j < 4; ++j) {
                const int n = n0 + wc * 64 + j * 16 + lc;
                #pragma unroll
                for (int r = 0; r < 4; ++r) {
                    const int m = m0 + wr * 64 + i * 16 + lr + r;
                    Cb[(size_t)m * ldc16 + n] = (_Float16)(acc[i][j][r] * iv[i][r]);
                }
            }
    } else if (mode == 4) {
        float* Cb = out32 + (size_t)z * s32;
        #pragma unroll
        for (int i = 0; i < 4; ++i)
            #pragma unroll
            for (int j = 0; j < 4; ++j) {
                const int n = n0 + wc * 64 + j * 16 + lc;
                #pragma unroll
                for (int r = 0; r < 4; ++r) {
                    const int m = m0 + wr * 64 + i * 16 + lr + r;
                    Cb[(size_t)m * ldc32 + n] = acc[i][j][r] * scale;
                }
            }
    } else {  // mode 2: tanh epilogue
        float bv[4];
        #pragma unroll
        for (int j = 0; j < 4; ++j)
            bv[j] = bias[n0 + wc * 64 + j * 16 + lc];
        #pragma unroll
        for (int i = 0; i < 4; ++i)
            #pragma unroll
            for (int j = 0; j < 4; ++j) {
                const int n = n0 + wc * 64 + j * 16 + lc;
                #pragma unroll
                for (int r = 0; r < 4; ++r) {
                    const int m = m0 + wr * 64 + i * 16 + lr + r;
                    const float t = tanhf(acc[i][j][r] + bv[j]);
                    if (out16) out16[(size_t)z * s16 + (size_t)m * ldc16 + n] = (_Float16)t;
                    if (out32) out32[(size_t)z * s32 + (size_t)m * ldc32 + n] = t;
                }
            }
    }
}

// inv[row] = 1 / sum_{cb<16} partial[row*16+cb]
__global__ __launch_bounds__(256) void make_inv(
    const float* __restrict__ partial, float* __restrict__ inv)
{
    const int row = blockIdx.x * 256 + threadIdx.x;
    const float4 a = *(const float4*)(partial + (size_t)row * 16);
    const float4 b = *(const float4*)(partial + (size_t)row * 16 + 4);
    const float4 c = *(const float4*)(partial + (size_t)row * 16 + 8);
    const float4 d = *(const float4*)(partial + (size_t)row * 16 + 12);
    const float s = (a.x + a.y + a.z + a.w) + (b.x + b.y + b.z + b.w)
                  + (c.x + c.y + c.z + c.w) + (d.x + d.y + d.z + d.w);
    inv[row] = 1.0f / s;
}

// row softmax over 2048 f32 (hop 2): writes f16 attn + normalized f32 in place
__global__ __launch_bounds__(256) void softmax_rows2(
    float* __restrict__ S, _Float16* __restrict__ f16out,
    long f16stride, int write_f32)
{
    __shared__ float red[8];
    const long row = blockIdx.x;
    float* p = S + row * LKK;
    const int tid = threadIdx.x;
    float4 v0 = ((const float4*)p)[tid];
    float4 v1 = ((const float4*)p)[tid + 256];
    float m = fmaxf(fmaxf(fmaxf(v0.x, v0.y), fmaxf(v0.z, v0.w)),
                    fmaxf(fmaxf(v1.x, v1.y), fmaxf(v1.z, v1.w)));
    #pragma unroll
    for (int off = 32; off > 0; off >>= 1) m = fmaxf(m, __shfl_down(m, off));
    if ((tid & 63) == 0) red[tid >> 6] = m;
    __syncthreads();
    m = fmaxf(fmaxf(red[0], red[1]), fmaxf(red[2], red[3]));
    v0.x = expf(v0.x - m); v0.y = expf(v0.y - m);
    v0.z = expf(v0.z - m); v0.w = expf(v0.w - m);
    v1.x = expf(v1.x - m); v1.y = expf(v1.y - m);
    v1.z = expf(v1.z - m); v1.w = expf(v1.w - m);
    float s = v0.x + v0.y + v0.z + v0.w + v1.x + v1.y + v1.z + v1.w;
    #pragma unroll
    for (int off = 32; off > 0; off >>= 1) s += __shfl_down(s, off);
    if ((tid & 63) == 0) red[4 + (tid >> 6)] = s;
    __syncthreads();
    s = red[4] + red[5] + red[6] + red[7];
    const float inv = 1.0f / s;
    v0.x *= inv; v0.y *= inv; v0.z *= inv; v0.w *= inv;
    v1.x *= inv; v1.y *= inv; v1.z *= inv; v1.w *= inv;
    if (write_f32) {
        ((float4*)p)[tid] = v0;
        ((float4*)p)[tid + 256] = v1;
    }
    _Float16* q = f16out + row * f16stride;
    half4 h0 = { (_Float16)v0.x, (_Float16)v0.y, (_Float16)v0.z, (_Float16)v0.w };
    half4 h1 = { (_Float16)v1.x, (_Float16)v1.y, (_Float16)v1.z, (_Float16)v1.w };
    *(half4*)(q + tid * 4) = h0;
    *(half4*)(q + 1024 + tid * 4) = h1;
}

__global__ __launch_bounds__(256) void cvt_f32_to_f16(
    const float* __restrict__ in, _Float16* __restrict__ out, long n)
{
    const long i = ((long)blockIdx.x * 256 + threadIdx.x) * 8;
    if (i + 8 > n) return;
    float4 a = *(const float4*)(in + i);
    float4 b = *(const float4*)(in + i + 4);
    half8 h = { (_Float16)a.x, (_Float16)a.y, (_Float16)a.z, (_Float16)a.w,
                (_Float16)b.x, (_Float16)b.y, (_Float16)b.z, (_Float16)b.w };
    *(half8*)(out + i) = h;
}

// V [B, Lk, D] f32 -> Vt [B, D, Lk] f16, 64x64 tiles via LDS
__global__ __launch_bounds__(256) void transpose_cvt_v(
    const float* __restrict__ V, _Float16* __restrict__ Vt)
{
    __shared__ _Float16 t[64][80];
    const int z = blockIdx.z;
    const int k0 = blockIdx.y * 64, d0 = blockIdx.x * 64;
    const float* Vb = V + (size_t)z * LKK * DD;
    _Float16* Vtb = Vt + (size_t)z * DD * LKK;
    const int r = threadIdx.x >> 2;
    const int c0 = (threadIdx.x & 3) * 16;
    #pragma unroll
    for (int j = 0; j < 4; ++j) {
        float4 v = *(const float4*)(Vb + (size_t)(k0 + r) * DD + d0 + c0 + j * 4);
        t[c0 + j * 4 + 0][r] = (_Float16)v.x;
        t[c0 + j * 4 + 1][r] = (_Float16)v.y;
        t[c0 + j * 4 + 2][r] = (_Float16)v.z;
        t[c0 + j * 4 + 3][r] = (_Float16)v.w;
    }
    __syncthreads();
    #pragma unroll
    for (int j = 0; j < 2; ++j) {
        half8 h = *(const half8*)&t[r][c0 + j * 8];
        *(half8*)(Vtb + (size_t)(d0 + r) * LKK + k0 + c0 + j * 8) = h;
    }
}

// ======================= round-1 f32 fallback kernels =======================
constexpr int TM = 64, TN = 64, TK = 32;
constexpr int PAD = 4;

__global__ __launch_bounds__(256) void gemm_nt_k(
    const float* __restrict__ A, int lda, long sA,
    const float* __restrict__ Bt, int ldb, long sB,
    float* __restrict__ C, int ldc, long sC, int K, float scale)
{
    __shared__ float As[TK][TM + PAD];
    __shared__ float Bs[TK][TN + PAD];
    const float* Ab = A + (long)blockIdx.z * sA;
    const float* Bb = Bt + (long)blockIdx.z * sB;
    float* Cb = C + (long)blockIdx.z * sC;
    const int m0 = blockIdx.y * TM, n0 = blockIdx.x * TN;
    const int tid = threadIdx.x;
    const int tn = tid & 15, tm = tid >> 4;
    float acc[4][4] = {};
    for (int k0 = 0; k0 < K; k0 += TK) {
        #pragma unroll
        for (int c = tid; c < (TM * TK) / 4; c += 256) {
            const int row = c >> 3, kc = (c & 7) << 2;
            const float4 g = *(const float4*)(Ab + (long)(m0 + row) * lda + (k0 + kc));
            As[kc + 0][row] = g.x; As[kc + 1][row] = g.y;
            As[kc + 2][row] = g.z; As[kc + 3][row] = g.w;
        }
        #pragma unroll
        for (int c = tid; c < (TN * TK) / 4; c += 256) {
            const int row = c >> 3, kc = (c & 7) << 2;
            const float4 g = *(const float4*)(Bb + (long)(n0 + row) * ldb + (k0 + kc));
            Bs[kc + 0][row] = g.x; Bs[kc + 1][row] = g.y;
            Bs[kc + 2][row] = g.z; Bs[kc + 3][row] = g.w;
        }
        __syncthreads();
        #pragma unroll
        for (int kk = 0; kk < TK; ++kk) {
            const float4 av = *(const float4*)&As[kk][tm << 2];
            const float4 bv = *(const float4*)&Bs[kk][tn << 2];
            const float a[4] = {av.x, av.y, av.z, av.w};
            const float b[4] = {bv.x, bv.y, bv.z, bv.w};
            #pragma unroll
            for (int i = 0; i < 4; ++i)
                #pragma unroll
                for (int j = 0; j < 4; ++j)
                    acc[i][j] = fmaf(a[i], b[j], acc[i][j]);
        }
        __syncthreads();
    }
    #pragma unroll
    for (int i = 0; i < 4; ++i) {
        float4 o = make_float4(acc[i][0] * scale, acc[i][1] * scale,
                               acc[i][2] * scale, acc[i][3] * scale);
        *(float4*)(Cb + (long)(m0 + (tm << 2) + i) * ldc + n0 + (tn << 2)) = o;
    }
}

__global__ __launch_bounds__(256) void gemm_nn_k(
    const float* __restrict__ A, int lda, long sA,
    const float* __restrict__ B, int ldb, long sB,
    float* __restrict__ C, int ldc, long sC, int K)
{
    __shared__ float As[TK][TM + PAD];
    __shared__ float Bs[TK][TN + PAD];
    const float* Ab = A + (long)blockIdx.z * sA;
    const float* Bb = B + (long)blockIdx.z * sB;
    float* Cb = C + (long)blockIdx.z * sC;
    const int m0 = blockIdx.y * TM, n0 = blockIdx.x * TN;
    const int tid = threadIdx.x;
    const int tn = tid & 15, tm = tid >> 4;
    float acc[4][4] = {};
    for (int k0 = 0; k0 < K; k0 += TK) {
        #pragma unroll
        for (int c = tid; c < (TM * TK) / 4; c += 256) {
            const int row = c >> 3, kc = (c & 7) << 2;
            const float4 g = *(const float4*)(Ab + (long)(m0 + row) * lda + (k0 + kc));
            As[kc + 0][row] = g.x; As[kc + 1][row] = g.y;
            As[kc + 2][row] = g.z; As[kc + 3][row] = g.w;
        }
        #pragma unroll
        for (int c = tid; c < (TK * TN) / 4; c += 256) {
            const int krow = c >> 4, nc = (c & 15) << 2;
            *(float4*)&Bs[krow][nc] =
                *(const float4*)(Bb + (long)(k0 + krow) * ldb + n0 + nc);
        }
        __syncthreads();
        #pragma unroll
        for (int kk = 0; kk < TK; ++kk) {
            const float4 av = *(const float4*)&As[kk][tm << 2];
            const float4 bv = *(const float4*)&Bs[kk][tn << 2];
            const float a[4] = {av.x, av.y, av.z, av.w};
            const float b[4] = {bv.x, bv.y, bv.z, bv.w};
            #pragma unroll
            for (int i = 0; i < 4; ++i)
                #pragma unroll
                for (int j = 0; j < 4; ++j)
                    acc[i][j] = fmaf(a[i], b[j], acc[i][j]);
        }
        __syncthreads();
    }
    #pragma unroll
    for (int i = 0; i < 4; ++i) {
        float4 o = make_float4(acc[i][0], acc[i][1], acc[i][2], acc[i][3]);
        *(float4*)(Cb + (long)(m0 + (tm << 2) + i) * ldc + n0 + (tn << 2)) = o;
    }
}

__global__ __launch_bounds__(256) void gemm_cat_k(
    const float* __restrict__ Qh, const float* __restrict__ R,
    const float* __restrict__ W, const float* __restrict__ bias,
    float* __restrict__ C)
{
    __shared__ float As[TK][TM + PAD];
    __shared__ float Bs[TK][TN + PAD];
    const float* Qb = Qh + (long)blockIdx.z * LQ * DD;
    const float* Rb = R + (long)blockIdx.z * LQ * DD;
    float* Cb = C + (long)blockIdx.z * LQ * DD;
    const int m0 = blockIdx.y * TM, n0 = blockIdx.x * TN;
    const int tid = threadIdx.x;
    const int tn = tid & 15, tm = tid >> 4;
    float acc[4][4] = {};
    for (int k0 = 0; k0 < 2 * DD; k0 += TK) {
        const float* src = (k0 < DD) ? Qb : Rb;
        const int kb = (k0 < DD) ? k0 : k0 - DD;
        #pragma unroll
        for (int c = tid; c < (TM * TK) / 4; c += 256) {
            const int row = c >> 3, kc = (c & 7) << 2;
            const float4 g = *(const float4*)(src + (long)(m0 + row) * DD + (kb + kc));
            As[kc + 0][row] = g.x; As[kc + 1][row] = g.y;
            As[kc + 2][row] = g.z; As[kc + 3][row] = g.w;
        }
        #pragma unroll
        for (int c = tid; c < (TN * TK) / 4; c += 256) {
            const int row = c >> 3, kc = (c & 7) << 2;
            const float4 g = *(const float4*)(W + (long)(n0 + row) * (2 * DD) + (k0 + kc));
            Bs[kc + 0][row] = g.x; Bs[kc + 1][row] = g.y;
            Bs[kc + 2][row] = g.z; Bs[kc + 3][row] = g.w;
        }
        __syncthreads();
        #pragma unroll
        for (int kk = 0; kk < TK; ++kk) {
            const float4 av = *(const float4*)&As[kk][tm << 2];
            const float4 bv = *(const float4*)&Bs[kk][tn << 2];
            const float a[4] = {av.x, av.y, av.z, av.w};
            const float b[4] = {bv.x, bv.y, bv.z, bv.w};
            #pragma unroll
            for (int i = 0; i < 4; ++i)
                #pragma unroll
                for (int j = 0; j < 4; ++j)
                    acc[i][j] = fmaf(a[i], b[j], acc[i][j]);
        }
        __syncthreads();
    }
    #pragma unroll
    for (int i = 0; i < 4; ++i) {
        float4 o;
        o.x = tanhf(acc[i][0] + bias[n0 + (tn << 2) + 0]);
        o.y = tanhf(acc[i][1] + bias[n0 + (tn << 2) + 1]);
        o.z = tanhf(acc[i][2] + bias[n0 + (tn << 2) + 2]);
        o.w = tanhf(acc[i][3] + bias[n0 + (tn << 2) + 3]);
        *(float4*)(Cb + (long)(m0 + (tm << 2) + i) * DD + n0 + (tn << 2)) = o;
    }
}

__global__ __launch_bounds__(256) void softmax_rows(float* __restrict__ S) {
    __shared__ float red[8];
    float* p = S + (size_t)blockIdx.x * LKK;
    const int tid = threadIdx.x;
    float4 v0 = ((const float4*)p)[tid];
    float4 v1 = ((const float4*)p)[tid + 256];
    float m = fmaxf(fmaxf(fmaxf(v0.x, v0.y), fmaxf(v0.z, v0.w)),
                    fmaxf(fmaxf(v1.x, v1.y), fmaxf(v1.z, v1.w)));
    #pragma unroll
    for (int off = 32; off > 0; off >>= 1) m = fmaxf(m, __shfl_down(m, off));
    if ((tid & 63) == 0) red[tid >> 6] = m;
    __syncthreads();
    m = fmaxf(fmaxf(red[0], red[1]), fmaxf(red[2], red[3]));
    v0.x = expf(v0.x - m); v0.y = expf(v0.y - m);
    v0.z = expf(v0.z - m); v0.w = expf(v0.w - m);
    v1.x = expf(v1.x - m); v1.y = expf(v1.y - m);
    v1.z = expf(v1.z - m); v1.w = expf(v1.w - m);
    float s = v0.x + v0.y + v0.z + v0.w + v1.x + v1.y + v1.z + v1.w;
    #pragma unroll
    for (int off = 32; off > 0; off >>= 1) s += __shfl_down(s, off);
    if ((tid & 63) == 0) red[4 + (tid >> 6)] = s;
    __syncthreads();
    s = red[4] + red[5] + red[6] + red[7];
    const float inv = 1.0f / s;
    v0.x *= inv; v0.y *= inv; v0.z *= inv; v0.w *= inv;
    v1.x *= inv; v1.y *= inv; v1.z *= inv; v1.w *= inv;
    ((float4*)p)[tid] = v0;
    ((float4*)p)[tid + 256] = v1;
}

// ===========================================================================
extern "C" void kernel_launch(void* const* d_in, const int* in_sizes, int n_in,
                              void* d_out, int out_size, void* d_ws, size_t ws_size,
                              hipStream_t stream) {
    const float* Q    = (const float*)d_in[0];
    const float* Km   = (const float*)d_in[1];
    const float* V    = (const float*)d_in[2];
    const float* W    = (const float*)d_in[3];
    const float* bias = (const float*)d_in[4];
    const float scale = 0.03125f;  // 1/sqrt(1024)
    dim3 blk(256);

    const size_t NEED = 155189248ULL;  // Kh 64M + Vt 64M + Wh 4M + Rh 16M
    if (ws_size >= NEED) {
        char* ws = (char*)d_ws;
        _Float16* Kh  = (_Float16*)ws;                    // [16,2048,1024]
        _Float16* Vt  = (_Float16*)(ws + 67108864);       // [16,1024,2048]
        _Float16* Wh  = (_Float16*)(ws + 134217728);      // [1024,2048]
        _Float16* Rh  = (_Float16*)(ws + 138412032);      // [16,512,1024]
        _Float16* attn2 = (_Float16*)ws;                  // alias Kh (dead at hop2 softmax)
        float* Fout = (float*)(ws + 33554432);            // alias Kh 2nd half

        _Float16* Qping = (_Float16*)d_out;               // d_out Q region, 1st half
        _Float16* Qpong = Qping + (size_t)NB * LQ * DD;   // 2nd half
        float* S = (float*)((char*)d_out + 33554432);     // d_out attn region (hop2 f32 scores)
        _Float16* P = (_Float16*)S;                       // hops 0/1: f16 exp-scores (33.5 MB)
        float* partialB = (float*)((char*)d_out + 73400320);  // 8192x16 f32 (dead space hops 0/1)
        float* invB     = (float*)((char*)d_out + 73924608);  // 8192 f32

        cvt_f32_to_f16<<<4096, blk, 0, stream>>>(Q, Qping, (long)NB * LQ * DD);
        cvt_f32_to_f16<<<16384, blk, 0, stream>>>(Km, Kh, (long)NB * LKK * DD);
        cvt_f32_to_f16<<<1024, blk, 0, stream>>>(W, Wh, (long)DD * 2 * DD);
        transpose_cvt_v<<<dim3(DD / 64, LKK / 64, NB), blk, 0, stream>>>(V, Vt);

        dim3 gS(LKK / 128, LQ / 128, NB);   // QK^T: 16 x 4 x 16 = 1024 blocks
        dim3 gR(DD / 128, LQ / 128, NB);    // PV / cat: 8 x 4 x 16 = 512 blocks

        for (int h = 0; h < 3; ++h) {
            _Float16* qcur = (h == 1) ? Qpong : Qping;

            if (h < 3 - 1) {
                // ---- fused: P = exp(Qh K^T * scale), row partial sums
                gemm_f16_nt<<<gS, blk, 0, stream>>>(
                    qcur, (long)LQ * DD, DD, (const _Float16*)0, 0, 0, DD,
                    Kh, (long)LKK * DD, DD, DD,
                    0, scale, (float*)0, 0, 0,
                    P, (long)LQ * LKK, LKK, (const float*)0,
                    partialB, (const float*)0);
                make_inv<<<32, blk, 0, stream>>>(partialB, invB);
                // ---- R = (P V) * inv[row]
                gemm_f16_nt<<<gR, blk, 0, stream>>>(
                    P, (long)LQ * LKK, LKK,
                    (const _Float16*)0, 0, 0, LKK,
                    Vt, (long)DD * LKK, LKK, LKK,
                    1, 1.0f, (float*)0, 0, 0,
                    Rh, (long)LQ * DD, DD, (const float*)0,
                    (float*)0, invB);
            } else {
                // ---- hop 2: raw f32 scores, classic softmax (attn output path)
                gemm_f16_nt<<<gS, blk, 0, stream>>>(
                    qcur, (long)LQ * DD, DD, (const _Float16*)0, 0, 0, DD,
                    Kh, (long)LKK * DD, DD, DD,
                    4, scale, S, (long)LQ * LKK, LKK,
                    (_Float16*)0, 0, 0, (const float*)0,
                    (float*)0, (const float*)0);
                softmax_rows2<<<NB * LQ, blk, 0, stream>>>(S, attn2, 2048L, 1);
                gemm_f16_nt<<<gR, blk, 0, stream>>>(
                    attn2, (long)LQ * LKK, LKK,
                    (const _Float16*)0, 0, 0, LKK,
                    Vt, (long)DD * LKK, LKK, LKK,
                    1, 1.0f, (float*)0, 0, 0,
                    Rh, (long)LQ * DD, DD, (const float*)0,
                    (float*)0, (const float*)0);
            }
            // ---- Qnext = tanh([Qh|R] W^T + b)
            _Float16* qn = (h == 0) ? Qpong : (h == 1) ? Qping : (_Float16*)0;
            float* fo = (h == 2) ? Fout : (float*)0;
            gemm_f16_nt<<<gR, blk, 0, stream>>>(
                qcur, (long)LQ * DD, DD,
                Rh, (long)LQ * DD, DD, DD,
                Wh, 0, 2 * DD, 2 * DD,
                2, 1.0f, fo, (long)LQ * DD, DD,
                qn, (long)LQ * DD, DD, bias,
                (float*)0, (const float*)0);
        }
        hipMemcpyAsync(d_out, Fout, 33554432ULL, hipMemcpyDeviceToDevice, stream);
    } else {
        // -------- round-1 f32 fallback (proven; ws >= 67 MB) --------
        float* outQ = (float*)d_out;
        float* S    = outQ + (size_t)NB * LQ * DD;
        float* R    = (float*)d_ws;
        float* T    = R + (size_t)NB * LQ * DD;
        dim3 gS(LKK / TN, LQ / TM, NB);
        dim3 gR(DD / TN, LQ / TM, NB);
        for (int h = 0; h < 3; ++h) {
            const float* Qh = (h == 0) ? Q : (h == 1 ? (const float*)T : (const float*)outQ);
            float* cout = (h == 1) ? outQ : T;
            gemm_nt_k<<<gS, blk, 0, stream>>>(Qh, DD, (long)LQ * DD, Km, DD, (long)LKK * DD,
                                              S, LKK, (long)LQ * LKK, DD, scale);
            softmax_rows<<<NB * LQ, blk, 0, stream>>>(S);
            gemm_nn_k<<<gR, blk, 0, stream>>>(S, LKK, (long)LQ * LKK, V, DD, (long)LKK * DD,
                                              R, DD, (long)LQ * DD, LKK);
            gemm_cat_k<<<gR, blk, 0, stream>>>(Qh, R, W, bias, cout);
        }
        hipMemcpyAsync(outQ, T, (size_t)NB * LQ * DD * sizeof(float),
                       hipMemcpyDeviceToDevice, stream);
    }
}

// Round 4
// 596.264 us; speedup vs baseline: 7.4290x; 1.0379x over previous
//
#include <hip/hip_runtime.h>
#include <math.h>

#define NB 16
#define LQ 512
#define LKK 2048
#define DD 1024

typedef _Float16 half8 __attribute__((ext_vector_type(8)));
typedef _Float16 half4 __attribute__((ext_vector_type(4)));
typedef float f32x4 __attribute__((ext_vector_type(4)));

__device__ __forceinline__ void gl_lds16(const void* g, void* l) {
    __builtin_amdgcn_global_load_lds(
        (const __attribute__((address_space(1))) void*)g,
        (__attribute__((address_space(3))) void*)l, 16, 0, 0);
}

// ---------------------------------------------------------------------------
// f16 MFMA NT-GEMM: acc[m,n] = sum_k A[m,k] * B[n,k]  (128x128 tile, BK=64)
// A split lo/hi at ksplit (concat GEMM). global_load_lds(16B), XOR-swizzled.
// XCD-aware bijective block swizzle (requires nwg % 8 == 0 — all our grids).
// mode 0: P16 = exp(acc*scale), row partial sums -> partial[row*16+bx]
// mode 1: out16 = acc * inv(row); inv from inv[] or folded from partial[]
// mode 2: t = tanh(acc+bias[n]) -> out16 and/or out32
// mode 4: out32 = acc*scale (raw scores, R3-fallback hop 2)
// ---------------------------------------------------------------------------
__global__ __launch_bounds__(256) void gemm_f16_nt(
    const _Float16* __restrict__ Alo, long sAlo, int lda_lo,
    const _Float16* __restrict__ Ahi, long sAhi, int lda_hi,
    int ksplit,
    const _Float16* __restrict__ B, long sB, int ldb,
    int K, int mode, float scale,
    float* __restrict__ out32, long s32, int ldc32,
    _Float16* __restrict__ out16, long s16, int ldc16,
    const float* __restrict__ bias,
    float* __restrict__ partial, const float* __restrict__ inv)
{
    __shared__ _Float16 lsA[128 * 64];
    __shared__ _Float16 lsB[128 * 64];
    __shared__ float psum[128][2];
    const int tid = threadIdx.x;
    const int w = tid >> 6, l = tid & 63;
    const int wr = w >> 1, wc = w & 1;

    // T1: XCD-aware bijective swizzle of the flattened block id
    int id = blockIdx.x + gridDim.x * (blockIdx.y + gridDim.y * blockIdx.z);
    const int nwg = gridDim.x * gridDim.y * gridDim.z;
    id = (id & 7) * (nwg >> 3) + (id >> 3);
    const int bx = id % gridDim.x;
    const int t2 = id / gridDim.x;
    const int by = t2 % gridDim.y;
    const int z = t2 / gridDim.y;
    const int m0 = by * 128, n0 = bx * 128;

    const _Float16* Abase_lo = Alo + (size_t)z * sAlo + (size_t)m0 * lda_lo;
    const _Float16* Abase_hi = Ahi ? (Ahi + (size_t)z * sAhi + (size_t)m0 * lda_hi) : (const _Float16*)0;
    const _Float16* Bbase = B + (size_t)z * sB + (size_t)n0 * ldb;

    const int srow = l >> 3;                  // row within the 8-row chunk
    const int sswz = ((l & 7) ^ srow) << 3;   // swizzled f16-element slot offset

    f32x4 acc[4][4] = {};

    for (int k0 = 0; k0 < K; k0 += 64) {
        const _Float16* Ap; int kloc, ldaA;
        if (k0 < ksplit) { Ap = Abase_lo; kloc = k0;          ldaA = lda_lo; }
        else             { Ap = Abase_hi; kloc = k0 - ksplit; ldaA = lda_hi; }
        #pragma unroll
        for (int i = 0; i < 4; ++i) {
            const int c = w * 4 + i;
            const int row = c * 8 + srow;
            gl_lds16(Ap + (size_t)row * ldaA + kloc + sswz, &lsA[c * 512]);
        }
        #pragma unroll
        for (int i = 0; i < 4; ++i) {
            const int c = w * 4 + i;
            const int row = c * 8 + srow;
            gl_lds16(Bbase + (size_t)row * ldb + k0 + sswz, &lsB[c * 512]);
        }
        __syncthreads();

        half8 af[4][2], bf[4][2];
        const char* lA = (const char*)lsA;
        const char* lB = (const char*)lsB;
        const int rs = (l & 7) << 4;        // row-XOR bits (row&7)<<4
        const int cb = (l >> 4) << 4;       // 16B slot within 32-k half
        #pragma unroll
        for (int i = 0; i < 4; ++i) {
            const int rowa = wr * 64 + i * 16 + (l & 15);
            const int rowb = wc * 64 + i * 16 + (l & 15);
            #pragma unroll
            for (int kk = 0; kk < 2; ++kk) {
                af[i][kk] = *(const half8*)(lA + rowa * 128 + ((kk * 64 + cb) ^ rs));
                bf[i][kk] = *(const half8*)(lB + rowb * 128 + ((kk * 64 + cb) ^ rs));
            }
        }
        #pragma unroll
        for (int kk = 0; kk < 2; ++kk)
            #pragma unroll
            for (int i = 0; i < 4; ++i)
                #pragma unroll
                for (int j = 0; j < 4; ++j)
                    acc[i][j] = __builtin_amdgcn_mfma_f32_16x16x32_f16(
                        af[i][kk], bf[j][kk], acc[i][j], 0, 0, 0);
        __syncthreads();
    }

    const int lr = (l >> 4) * 4;
    const int lc = l & 15;
    if (mode == 0) {
        _Float16* Cb = out16 + (size_t)z * s16;
        float rsum[4][4];
        #pragma unroll
        for (int i = 0; i < 4; ++i)
            #pragma unroll
            for (int r = 0; r < 4; ++r) rsum[i][r] = 0.0f;
        #pragma unroll
        for (int i = 0; i < 4; ++i)
            #pragma unroll
            for (int j = 0; j < 4; ++j) {
                const int n = n0 + wc * 64 + j * 16 + lc;
                #pragma unroll
                for (int r = 0; r < 4; ++r) {
                    const int m = m0 + wr * 64 + i * 16 + lr + r;
                    const float e = __expf(acc[i][j][r] * scale);
                    Cb[(size_t)m * ldc16 + n] = (_Float16)e;
                    rsum[i][r] += e;
                }
            }
        #pragma unroll
        for (int i = 0; i < 4; ++i)
            #pragma unroll
            for (int r = 0; r < 4; ++r) {
                float s = rsum[i][r];
                s += __shfl_xor(s, 1);
                s += __shfl_xor(s, 2);
                s += __shfl_xor(s, 4);
                s += __shfl_xor(s, 8);
                rsum[i][r] = s;
            }
        if (lc == 0) {
            #pragma unroll
            for (int i = 0; i < 4; ++i)
                #pragma unroll
                for (int r = 0; r < 4; ++r)
                    psum[wr * 64 + i * 16 + lr + r][wc] = rsum[i][r];
        }
        __syncthreads();
        if (tid < 128)
            partial[((size_t)z * LQ + m0 + tid) * 16 + bx] = psum[tid][0] + psum[tid][1];
    } else if (mode == 1) {
        _Float16* Cb = out16 + (size_t)z * s16;
        float iv[4][4];
        if (partial) {
            // fold: inv(row) = 1 / sum_{c<16} partial[row*16+c]
            if (tid < 128) {
                const float* pp = partial + ((size_t)z * LQ + m0 + tid) * 16;
                float s = 0.0f;
                #pragma unroll
                for (int c = 0; c < 16; ++c) s += pp[c];
                psum[tid][0] = 1.0f / s;
            }
            __syncthreads();
            #pragma unroll
            for (int i = 0; i < 4; ++i)
                #pragma unroll
                for (int r = 0; r < 4; ++r)
                    iv[i][r] = psum[wr * 64 + i * 16 + lr + r][0];
        } else {
            #pragma unroll
            for (int i = 0; i < 4; ++i)
                #pragma unroll
                for (int r = 0; r < 4; ++r)
                    iv[i][r] = inv ? inv[(size_t)z * LQ + m0 + wr * 64 + i * 16 + lr + r] : 1.0f;
        }
        #pragma unroll
        for (int i = 0; i < 4; ++i)
            #pragma unroll
            for (int j = 0; j < 4; ++j) {
                const int n = n0 + wc * 64 + j * 16 + lc;
                #pragma unroll
                for (int r = 0; r < 4; ++r) {
                    const int m = m0 + wr * 64 + i * 16 + lr + r;
                    Cb[(size_t)m * ldc16 + n] = (_Float16)(acc[i][j][r] * iv[i][r]);
                }
            }
    } else if (mode == 4) {
        float* Cb = out32 + (size_t)z * s32;
        #pragma unroll
        for (int i = 0; i < 4; ++i)
            #pragma unroll
            for (int j = 0; j < 4; ++j) {
                const int n = n0 + wc * 64 + j * 16 + lc;
                #pragma unroll
                for (int r = 0; r < 4; ++r) {
                    const int m = m0 + wr * 64 + i * 16 + lr + r;
                    Cb[(size_t)m * ldc32 + n] = acc[i][j][r] * scale;
                }
            }
    } else {  // mode 2: tanh epilogue
        float bv[4];
        #pragma unroll
        for (int j = 0; j < 4; ++j)
            bv[j] = bias[n0 + wc * 64 + j * 16 + lc];
        #pragma unroll
        for (int i = 0; i < 4; ++i)
            #pragma unroll
            for (int j = 0; j < 4; ++j) {
                const int n = n0 + wc * 64 + j * 16 + lc;
                #pragma unroll
                for (int r = 0; r < 4; ++r) {
                    const int m = m0 + wr * 64 + i * 16 + lr + r;
                    const float t = tanhf(acc[i][j][r] + bv[j]);
                    if (out16) out16[(size_t)z * s16 + (size_t)m * ldc16 + n] = (_Float16)t;
                    if (out32) out32[(size_t)z * s32 + (size_t)m * ldc32 + n] = t;
                }
            }
    }
}

// one block per row: attn_f32[row,:] = P16[row,:] * (1/sum partial[row,:])
__global__ __launch_bounds__(256) void scale_attn(
    const _Float16* __restrict__ P, const float* __restrict__ partial,
    float* __restrict__ attn)
{
    __shared__ float sinv;
    const long row = blockIdx.x;
    const int tid = threadIdx.x;
    if (tid < 16) {
        float s = partial[row * 16 + tid];
        s += __shfl_xor(s, 1);
        s += __shfl_xor(s, 2);
        s += __shfl_xor(s, 4);
        s += __shfl_xor(s, 8);
        if (tid == 0) sinv = 1.0f / s;
    }
    __syncthreads();
    const float inv = sinv;
    const half8 h = *(const half8*)(P + row * 2048 + tid * 8);
    float* o = attn + row * 2048 + tid * 8;
    float4 a = make_float4((float)h[0] * inv, (float)h[1] * inv,
                           (float)h[2] * inv, (float)h[3] * inv);
    float4 b = make_float4((float)h[4] * inv, (float)h[5] * inv,
                           (float)h[6] * inv, (float)h[7] * inv);
    *(float4*)o = a;
    *(float4*)(o + 4) = b;
}

// inv[row] = 1 / sum_{cb<16} partial[row*16+cb]   (R3-fallback path)
__global__ __launch_bounds__(256) void make_inv(
    const float* __restrict__ partial, float* __restrict__ inv)
{
    const int row = blockIdx.x * 256 + threadIdx.x;
    const float4 a = *(const float4*)(partial + (size_t)row * 16);
    const float4 b = *(const float4*)(partial + (size_t)row * 16 + 4);
    const float4 c = *(const float4*)(partial + (size_t)row * 16 + 8);
    const float4 d = *(const float4*)(partial + (size_t)row * 16 + 12);
    const float s = (a.x + a.y + a.z + a.w) + (b.x + b.y + b.z + b.w)
                  + (c.x + c.y + c.z + c.w) + (d.x + d.y + d.z + d.w);
    inv[row] = 1.0f / s;
}

// row softmax over 2048 f32 (R3-fallback hop 2)
__global__ __launch_bounds__(256) void softmax_rows2(
    float* __restrict__ S, _Float16* __restrict__ f16out,
    long f16stride, int write_f32)
{
    __shared__ float red[8];
    const long row = blockIdx.x;
    float* p = S + row * LKK;
    const int tid = threadIdx.x;
    float4 v0 = ((const float4*)p)[tid];
    float4 v1 = ((const float4*)p)[tid + 256];
    float m = fmaxf(fmaxf(fmaxf(v0.x, v0.y), fmaxf(v0.z, v0.w)),
                    fmaxf(fmaxf(v1.x, v1.y), fmaxf(v1.z, v1.w)));
    #pragma unroll
    for (int off = 32; off > 0; off >>= 1) m = fmaxf(m, __shfl_down(m, off));
    if ((tid & 63) == 0) red[tid >> 6] = m;
    __syncthreads();
    m = fmaxf(fmaxf(red[0], red[1]), fmaxf(red[2], red[3]));
    v0.x = expf(v0.x - m); v0.y = expf(v0.y - m);
    v0.z = expf(v0.z - m); v0.w = expf(v0.w - m);
    v1.x = expf(v1.x - m); v1.y = expf(v1.y - m);
    v1.z = expf(v1.z - m); v1.w = expf(v1.w - m);
    float s = v0.x + v0.y + v0.z + v0.w + v1.x + v1.y + v1.z + v1.w;
    #pragma unroll
    for (int off = 32; off > 0; off >>= 1) s += __shfl_down(s, off);
    if ((tid & 63) == 0) red[4 + (tid >> 6)] = s;
    __syncthreads();
    s = red[4] + red[5] + red[6] + red[7];
    const float inv = 1.0f / s;
    v0.x *= inv; v0.y *= inv; v0.z *= inv; v0.w *= inv;
    v1.x *= inv; v1.y *= inv; v1.z *= inv; v1.w *= inv;
    if (write_f32) {
        ((float4*)p)[tid] = v0;
        ((float4*)p)[tid + 256] = v1;
    }
    _Float16* q = f16out + row * f16stride;
    half4 h0 = { (_Float16)v0.x, (_Float16)v0.y, (_Float16)v0.z, (_Float16)v0.w };
    half4 h1 = { (_Float16)v1.x, (_Float16)v1.y, (_Float16)v1.z, (_Float16)v1.w };
    *(half4*)(q + tid * 4) = h0;
    *(half4*)(q + 1024 + tid * 4) = h1;
}

__global__ __launch_bounds__(256) void cvt_f32_to_f16(
    const float* __restrict__ in, _Float16* __restrict__ out, long n)
{
    const long i = ((long)blockIdx.x * 256 + threadIdx.x) * 8;
    if (i + 8 > n) return;
    float4 a = *(const float4*)(in + i);
    float4 b = *(const float4*)(in + i + 4);
    half8 h = { (_Float16)a.x, (_Float16)a.y, (_Float16)a.z, (_Float16)a.w,
                (_Float16)b.x, (_Float16)b.y, (_Float16)b.z, (_Float16)b.w };
    *(half8*)(out + i) = h;
}

// V [B, Lk, D] f32 -> Vt [B, D, Lk] f16, 64x64 tiles via LDS
__global__ __launch_bounds__(256) void transpose_cvt_v(
    const float* __restrict__ V, _Float16* __restrict__ Vt)
{
    __shared__ _Float16 t[64][80];
    const int z = blockIdx.z;
    const int k0 = blockIdx.y * 64, d0 = blockIdx.x * 64;
    const float* Vb = V + (size_t)z * LKK * DD;
    _Float16* Vtb = Vt + (size_t)z * DD * LKK;
    const int r = threadIdx.x >> 2;
    const int c0 = (threadIdx.x & 3) * 16;
    #pragma unroll
    for (int j = 0; j < 4; ++j) {
        float4 v = *(const float4*)(Vb + (size_t)(k0 + r) * DD + d0 + c0 + j * 4);
        t[c0 + j * 4 + 0][r] = (_Float16)v.x;
        t[c0 + j * 4 + 1][r] = (_Float16)v.y;
        t[c0 + j * 4 + 2][r] = (_Float16)v.z;
        t[c0 + j * 4 + 3][r] = (_Float16)v.w;
    }
    __syncthreads();
    #pragma unroll
    for (int j = 0; j < 2; ++j) {
        half8 h = *(const half8*)&t[r][c0 + j * 8];
        *(half8*)(Vtb + (size_t)(d0 + r) * LKK + k0 + c0 + j * 8) = h;
    }
}

// ======================= round-1 f32 fallback kernels =======================
constexpr int TM = 64, TN = 64, TK = 32;
constexpr int PAD = 4;

__global__ __launch_bounds__(256) void gemm_nt_k(
    const float* __restrict__ A, int lda, long sA,
    const float* __restrict__ Bt, int ldb, long sB,
    float* __restrict__ C, int ldc, long sC, int K, float scale)
{
    __shared__ float As[TK][TM + PAD];
    __shared__ float Bs[TK][TN + PAD];
    const float* Ab = A + (long)blockIdx.z * sA;
    const float* Bb = Bt + (long)blockIdx.z * sB;
    float* Cb = C + (long)blockIdx.z * sC;
    const int m0 = blockIdx.y * TM, n0 = blockIdx.x * TN;
    const int tid = threadIdx.x;
    const int tn = tid & 15, tm = tid >> 4;
    float acc[4][4] = {};
    for (int k0 = 0; k0 < K; k0 += TK) {
        #pragma unroll
        for (int c = tid; c < (TM * TK) / 4; c += 256) {
            const int row = c >> 3, kc = (c & 7) << 2;
            const float4 g = *(const float4*)(Ab + (long)(m0 + row) * lda + (k0 + kc));
            As[kc + 0][row] = g.x; As[kc + 1][row] = g.y;
            As[kc + 2][row] = g.z; As[kc + 3][row] = g.w;
        }
        #pragma unroll
        for (int c = tid; c < (TN * TK) / 4; c += 256) {
            const int row = c >> 3, kc = (c & 7) << 2;
            const float4 g = *(const float4*)(Bb + (long)(n0 + row) * ldb + (k0 + kc));
            Bs[kc + 0][row] = g.x; Bs[kc + 1][row] = g.y;
            Bs[kc + 2][row] = g.z; Bs[kc + 3][row] = g.w;
        }
        __syncthreads();
        #pragma unroll
        for (int kk = 0; kk < TK; ++kk) {
            const float4 av = *(const float4*)&As[kk][tm << 2];
            const float4 bv = *(const float4*)&Bs[kk][tn << 2];
            const float a[4] = {av.x, av.y, av.z, av.w};
            const float b[4] = {bv.x, bv.y, bv.z, bv.w};
            #pragma unroll
            for (int i = 0; i < 4; ++i)
                #pragma unroll
                for (int j = 0; j < 4; ++j)
                    acc[i][j] = fmaf(a[i], b[j], acc[i][j]);
        }
        __syncthreads();
    }
    #pragma unroll
    for (int i = 0; i < 4; ++i) {
        float4 o = make_float4(acc[i][0] * scale, acc[i][1] * scale,
                               acc[i][2] * scale, acc[i][3] * scale);
        *(float4*)(Cb + (long)(m0 + (tm << 2) + i) * ldc + n0 + (tn << 2)) = o;
    }
}

__global__ __launch_bounds__(256) void gemm_nn_k(
    const float* __restrict__ A, int lda, long sA,
    const float* __restrict__ B, int ldb, long sB,
    float* __restrict__ C, int ldc, long sC, int K)
{
    __shared__ float As[TK][TM + PAD];
    __shared__ float Bs[TK][TN + PAD];
    const float* Ab = A + (long)blockIdx.z * sA;
    const float* Bb = B + (long)blockIdx.z * sB;
    float* Cb = C + (long)blockIdx.z * sC;
    const int m0 = blockIdx.y * TM, n0 = blockIdx.x * TN;
    const int tid = threadIdx.x;
    const int tn = tid & 15, tm = tid >> 4;
    float acc[4][4] = {};
    for (int k0 = 0; k0 < K; k0 += TK) {
        #pragma unroll
        for (int c = tid; c < (TM * TK) / 4; c += 256) {
            const int row = c >> 3, kc = (c & 7) << 2;
            const float4 g = *(const float4*)(Ab + (long)(m0 + row) * lda + (k0 + kc));
            As[kc + 0][row] = g.x; As[kc + 1][row] = g.y;
            As[kc + 2][row] = g.z; As[kc + 3][row] = g.w;
        }
        #pragma unroll
        for (int c = tid; c < (TK * TN) / 4; c += 256) {
            const int krow = c >> 4, nc = (c & 15) << 2;
            *(float4*)&Bs[krow][nc] =
                *(const float4*)(Bb + (long)(k0 + krow) * ldb + n0 + nc);
        }
        __syncthreads();
        #pragma unroll
        for (int kk = 0; kk < TK; ++kk) {
            const float4 av = *(const float4*)&As[kk][tm << 2];
            const float4 bv = *(const float4*)&Bs[kk][tn << 2];
            const float a[4] = {av.x, av.y, av.z, av.w};
            const float b[4] = {bv.x, bv.y, bv.z, bv.w};
            #pragma unroll
            for (int i = 0; i < 4; ++i)
                #pragma unroll
                for (int j = 0; j < 4; ++j)
                    acc[i][j] = fmaf(a[i], b[j], acc[i][j]);
        }
        __syncthreads();
    }
    #pragma unroll
    for (int i = 0; i < 4; ++i) {
        float4 o = make_float4(acc[i][0], acc[i][1], acc[i][2], acc[i][3]);
        *(float4*)(Cb + (long)(m0 + (tm << 2) + i) * ldc + n0 + (tn << 2)) = o;
    }
}

__global__ __launch_bounds__(256) void gemm_cat_k(
    const float* __restrict__ Qh, const float* __restrict__ R,
    const float* __restrict__ W, const float* __restrict__ bias,
    float* __restrict__ C)
{
    __shared__ float As[TK][TM + PAD];
    __shared__ float Bs[TK][TN + PAD];
    const float* Qb = Qh + (long)blockIdx.z * LQ * DD;
    const float* Rb = R + (long)blockIdx.z * LQ * DD;
    float* Cb = C + (long)blockIdx.z * LQ * DD;
    const int m0 = blockIdx.y * TM, n0 = blockIdx.x * TN;
    const int tid = threadIdx.x;
    const int tn = tid & 15, tm = tid >> 4;
    float acc[4][4] = {};
    for (int k0 = 0; k0 < 2 * DD; k0 += TK) {
        const float* src = (k0 < DD) ? Qb : Rb;
        const int kb = (k0 < DD) ? k0 : k0 - DD;
        #pragma unroll
        for (int c = tid; c < (TM * TK) / 4; c += 256) {
            const int row = c >> 3, kc = (c & 7) << 2;
            const float4 g = *(const float4*)(src + (long)(m0 + row) * DD + (kb + kc));
            As[kc + 0][row] = g.x; As[kc + 1][row] = g.y;
            As[kc + 2][row] = g.z; As[kc + 3][row] = g.w;
        }
        #pragma unroll
        for (int c = tid; c < (TN * TK) / 4; c += 256) {
            const int row = c >> 3, kc = (c & 7) << 2;
            const float4 g = *(const float4*)(W + (long)(n0 + row) * (2 * DD) + (k0 + kc));
            Bs[kc + 0][row] = g.x; Bs[kc + 1][row] = g.y;
            Bs[kc + 2][row] = g.z; Bs[kc + 3][row] = g.w;
        }
        __syncthreads();
        #pragma unroll
        for (int kk = 0; kk < TK; ++kk) {
            const float4 av = *(const float4*)&As[kk][tm << 2];
            const float4 bv = *(const float4*)&Bs[kk][tn << 2];
            const float a[4] = {av.x, av.y, av.z, av.w};
            const float b[4] = {bv.x, bv.y, bv.z, bv.w};
            #pragma unroll
            for (int i = 0; i < 4; ++i)
                #pragma unroll
                for (int j = 0; j < 4; ++j)
                    acc[i][j] = fmaf(a[i], b[j], acc[i][j]);
        }
        __syncthreads();
    }
    #pragma unroll
    for (int i = 0; i < 4; ++i) {
        float4 o;
        o.x = tanhf(acc[i][0] + bias[n0 + (tn << 2) + 0]);
        o.y = tanhf(acc[i][1] + bias[n0 + (tn << 2) + 1]);
        o.z = tanhf(acc[i][2] + bias[n0 + (tn << 2) + 2]);
        o.w = tanhf(acc[i][3] + bias[n0 + (tn << 2) + 3]);
        *(float4*)(Cb + (long)(m0 + (tm << 2) + i) * DD + n0 + (tn << 2)) = o;
    }
}

__global__ __launch_bounds__(256) void softmax_rows(float* __restrict__ S) {
    __shared__ float red[8];
    float* p = S + (size_t)blockIdx.x * LKK;
    const int tid = threadIdx.x;
    float4 v0 = ((const float4*)p)[tid];
    float4 v1 = ((const float4*)p)[tid + 256];
    float m = fmaxf(fmaxf(fmaxf(v0.x, v0.y), fmaxf(v0.z, v0.w)),
                    fmaxf(fmaxf(v1.x, v1.y), fmaxf(v1.z, v1.w)));
    #pragma unroll
    for (int off = 32; off > 0; off >>= 1) m = fmaxf(m, __shfl_down(m, off));
    if ((tid & 63) == 0) red[tid >> 6] = m;
    __syncthreads();
    m = fmaxf(fmaxf(red[0], red[1]), fmaxf(red[2], red[3]));
    v0.x = expf(v0.x - m); v0.y = expf(v0.y - m);
    v0.z = expf(v0.z - m); v0.w = expf(v0.w - m);
    v1.x = expf(v1.x - m); v1.y = expf(v1.y - m);
    v1.z = expf(v1.z - m); v1.w = expf(v1.w - m);
    float s = v0.x + v0.y + v0.z + v0.w + v1.x + v1.y + v1.z + v1.w;
    #pragma unroll
    for (int off = 32; off > 0; off >>= 1) s += __shfl_down(s, off);
    if ((tid & 63) == 0) red[4 + (tid >> 6)] = s;
    __syncthreads();
    s = red[4] + red[5] + red[6] + red[7];
    const float inv = 1.0f / s;
    v0.x *= inv; v0.y *= inv; v0.z *= inv; v0.w *= inv;
    v1.x *= inv; v1.y *= inv; v1.z *= inv; v1.w *= inv;
    ((float4*)p)[tid] = v0;
    ((float4*)p)[tid + 256] = v1;
}

// ===========================================================================
extern "C" void kernel_launch(void* const* d_in, const int* in_sizes, int n_in,
                              void* d_out, int out_size, void* d_ws, size_t ws_size,
                              hipStream_t stream) {
    const float* Q    = (const float*)d_in[0];
    const float* Km   = (const float*)d_in[1];
    const float* V    = (const float*)d_in[2];
    const float* W    = (const float*)d_in[3];
    const float* bias = (const float*)d_in[4];
    const float scale = 0.03125f;  // 1/sqrt(1024)
    dim3 blk(256);

    const size_t NEED_FULL = 189267968ULL;  // Kh+Vt+Wh+Rh+Qping+Qpong+partial
    const size_t NEED_R3   = 155189248ULL;  // Kh+Vt+Wh+Rh

    if (ws_size >= NEED_FULL) {
        char* ws = (char*)d_ws;
        _Float16* Kh     = (_Float16*)ws;                    // [16,2048,1024]
        _Float16* Vt     = (_Float16*)(ws + 67108864);       // [16,1024,2048]
        _Float16* Wh     = (_Float16*)(ws + 134217728);      // [1024,2048]
        _Float16* Rh     = (_Float16*)(ws + 138412032);      // [16,512,1024]
        _Float16* Qping  = (_Float16*)(ws + 155189248);      // [16,512,1024]
        _Float16* Qpong  = (_Float16*)(ws + 171966464);      // [16,512,1024]
        float*    partialB = (float*)(ws + 188743680);       // [8192,16]

        float*    outQ  = (float*)d_out;                     // final Q f32 [0,33.5M)
        _Float16* P2    = (_Float16*)d_out;                  // hop2 P f16, same region
        float*    attnF = (float*)((char*)d_out + 33554432); // attn f32 [33.5M,100.6M)
        _Float16* P01   = (_Float16*)attnF;                  // hops0/1 P f16 (scratch)

        cvt_f32_to_f16<<<4096, blk, 0, stream>>>(Q, Qping, (long)NB * LQ * DD);
        cvt_f32_to_f16<<<16384, blk, 0, stream>>>(Km, Kh, (long)NB * LKK * DD);
        cvt_f32_to_f16<<<1024, blk, 0, stream>>>(W, Wh, (long)DD * 2 * DD);
        transpose_cvt_v<<<dim3(DD / 64, LKK / 64, NB), blk, 0, stream>>>(V, Vt);

        dim3 gS(LKK / 128, LQ / 128, NB);   // QK^T: 16 x 4 x 16 = 1024 blocks
        dim3 gR(DD / 128, LQ / 128, NB);    // PV / cat: 8 x 4 x 16 = 512 blocks

        for (int h = 0; h < 3; ++h) {
            _Float16* qcur = (h == 1) ? Qpong : Qping;
            _Float16* P    = (h == 2) ? P2 : P01;

            // ---- fused: P = exp(Qh K^T * scale), row partial sums
            gemm_f16_nt<<<gS, blk, 0, stream>>>(
                qcur, (long)LQ * DD, DD, (const _Float16*)0, 0, 0, DD,
                Kh, (long)LKK * DD, DD, DD,
                0, scale, (float*)0, 0, 0,
                P, (long)LQ * LKK, LKK, (const float*)0,
                partialB, (const float*)0);
            if (h == 2)  // attn output: f32 = P * inv(row)
                scale_attn<<<NB * LQ, blk, 0, stream>>>(P2, partialB, attnF);
            // ---- R = (P V) * inv(row), inv folded from partials
            gemm_f16_nt<<<gR, blk, 0, stream>>>(
                P, (long)LQ * LKK, LKK,
                (const _Float16*)0, 0, 0, LKK,
                Vt, (long)DD * LKK, LKK, LKK,
                1, 1.0f, (float*)0, 0, 0,
                Rh, (long)LQ * DD, DD, (const float*)0,
                partialB, (const float*)0);
            // ---- Qnext = tanh([Qh|R] W^T + b)
            _Float16* qn = (h == 0) ? Qpong : (h == 1) ? Qping : (_Float16*)0;
            float* fo = (h == 2) ? outQ : (float*)0;
            gemm_f16_nt<<<gR, blk, 0, stream>>>(
                qcur, (long)LQ * DD, DD,
                Rh, (long)LQ * DD, DD, DD,
                Wh, 0, 2 * DD, 2 * DD,
                2, 1.0f, fo, (long)LQ * DD, DD,
                qn, (long)LQ * DD, DD, bias,
                (float*)0, (const float*)0);
        }
    } else if (ws_size >= NEED_R3) {
        // -------- proven R3 path --------
        char* ws = (char*)d_ws;
        _Float16* Kh  = (_Float16*)ws;
        _Float16* Vt  = (_Float16*)(ws + 67108864);
        _Float16* Wh  = (_Float16*)(ws + 134217728);
        _Float16* Rh  = (_Float16*)(ws + 138412032);
        _Float16* attn2 = (_Float16*)ws;                  // alias Kh (dead at hop2 softmax)
        float* Fout = (float*)(ws + 33554432);            // alias Kh 2nd half

        _Float16* Qping = (_Float16*)d_out;
        _Float16* Qpong = Qping + (size_t)NB * LQ * DD;
        float* S = (float*)((char*)d_out + 33554432);
        _Float16* P = (_Float16*)S;
        float* partialB = (float*)((char*)d_out + 73400320);
        float* invB     = (float*)((char*)d_out + 73924608);

        cvt_f32_to_f16<<<4096, blk, 0, stream>>>(Q, Qping, (long)NB * LQ * DD);
        cvt_f32_to_f16<<<16384, blk, 0, stream>>>(Km, Kh, (long)NB * LKK * DD);
        cvt_f32_to_f16<<<1024, blk, 0, stream>>>(W, Wh, (long)DD * 2 * DD);
        transpose_cvt_v<<<dim3(DD / 64, LKK / 64, NB), blk, 0, stream>>>(V, Vt);

        dim3 gS(LKK / 128, LQ / 128, NB);
        dim3 gR(DD / 128, LQ / 128, NB);

        for (int h = 0; h < 3; ++h) {
            _Float16* qcur = (h == 1) ? Qpong : Qping;
            if (h < 2) {
                gemm_f16_nt<<<gS, blk, 0, stream>>>(
                    qcur, (long)LQ * DD, DD, (const _Float16*)0, 0, 0, DD,
                    Kh, (long)LKK * DD, DD, DD,
                    0, scale, (float*)0, 0, 0,
                    P, (long)LQ * LKK, LKK, (const float*)0,
                    partialB, (const float*)0);
                make_inv<<<32, blk, 0, stream>>>(partialB, invB);
                gemm_f16_nt<<<gR, blk, 0, stream>>>(
                    P, (long)LQ * LKK, LKK,
                    (const _Float16*)0, 0, 0, LKK,
                    Vt, (long)DD * LKK, LKK, LKK,
                    1, 1.0f, (float*)0, 0, 0,
                    Rh, (long)LQ * DD, DD, (const float*)0,
                    (float*)0, invB);
            } else {
                gemm_f16_nt<<<gS, blk, 0, stream>>>(
                    qcur, (long)LQ * DD, DD, (const _Float16*)0, 0, 0, DD,
                    Kh, (long)LKK * DD, DD, DD,
                    4, scale, S, (long)LQ * LKK, LKK,
                    (_Float16*)0, 0, 0, (const float*)0,
                    (float*)0, (const float*)0);
                softmax_rows2<<<NB * LQ, blk, 0, stream>>>(S, attn2, 2048L, 1);
                gemm_f16_nt<<<gR, blk, 0, stream>>>(
                    attn2, (long)LQ * LKK, LKK,
                    (const _Float16*)0, 0, 0, LKK,
                    Vt, (long)DD * LKK, LKK, LKK,
                    1, 1.0f, (float*)0, 0, 0,
                    Rh, (long)LQ * DD, DD, (const float*)0,
                    (float*)0, (const float*)0);
            }
            _Float16* qn = (h == 0) ? Qpong : (h == 1) ? Qping : (_Float16*)0;
            float* fo = (h == 2) ? Fout : (float*)0;
            gemm_f16_nt<<<gR, blk, 0, stream>>>(
                qcur, (long)LQ * DD, DD,
                Rh, (long)LQ * DD, DD, DD,
                Wh, 0, 2 * DD, 2 * DD,
                2, 1.0f, fo, (long)LQ * DD, DD,
                qn, (long)LQ * DD, DD, bias,
                (float*)0, (const float*)0);
        }
        hipMemcpyAsync(d_out, Fout, 33554432ULL, hipMemcpyDeviceToDevice, stream);
    } else {
        // -------- round-1 f32 fallback --------
        float* outQ = (float*)d_out;
        float* S    = outQ + (size_t)NB * LQ * DD;
        float* R    = (float*)d_ws;
        float* T    = R + (size_t)NB * LQ * DD;
        dim3 gS(LKK / TN, LQ / TM, NB);
        dim3 gR(DD / TN, LQ / TM, NB);
        for (int h = 0; h < 3; ++h) {
            const float* Qh = (h == 0) ? Q : (h == 1 ? (const float*)T : (const float*)outQ);
            float* cout = (h == 1) ? outQ : T;
            gemm_nt_k<<<gS, blk, 0, stream>>>(Qh, DD, (long)LQ * DD, Km, DD, (long)LKK * DD,
                                              S, LKK, (long)LQ * LKK, DD, scale);
            softmax_rows<<<NB * LQ, blk, 0, stream>>>(S);
            gemm_nn_k<<<gR, blk, 0, stream>>>(S, LKK, (long)LQ * LKK, V, DD, (long)LKK * DD,
                                              R, DD, (long)LQ * DD, LKK);
            gemm_cat_k<<<gR, blk, 0, stream>>>(Qh, R, W, bias, cout);
        }
        hipMemcpyAsync(outQ, T, (size_t)NB * LQ * DD * sizeof(float),
                       hipMemcpyDeviceToDevice, stream);
    }
}

// Round 5
// 536.595 us; speedup vs baseline: 8.2551x; 1.1112x over previous
//
#include <hip/hip_runtime.h>
#include <math.h>

#define NB 16
#define LQ 512
#define LKK 2048
#define DD 1024

typedef _Float16 half8 __attribute__((ext_vector_type(8)));
typedef _Float16 half4 __attribute__((ext_vector_type(4)));
typedef float f32x4 __attribute__((ext_vector_type(4)));

__device__ __forceinline__ void gl_lds16(const void* g, void* l) {
    __builtin_amdgcn_global_load_lds(
        (const __attribute__((address_space(1))) void*)g,
        (__attribute__((address_space(3))) void*)l, 16, 0, 0);
}

// ===========================================================================
// 8-phase 256x256 NT-GEMM for QK^T (BK=64, 512 thr = 8 waves 2Mx4N, 128KB LDS,
// counted vmcnt, raw s_barrier, setprio around MFMA, T2 XOR swizzle).
// Epilogue: P16 = exp(acc*scale), 8-wide row partial sums.
// Requires K = 1024 (16 K-tiles -> 8 iterations of 2).
// ===========================================================================
__global__ __launch_bounds__(512, 2) void gemm_qk_256(
    const _Float16* __restrict__ A, long sA,     // [z] 512 x 1024, lda=DD
    const _Float16* __restrict__ B, long sB,     // [z] 2048 x 1024, ldb=DD
    _Float16* __restrict__ P, long sP,           // out f16 [z] 512 x 2048
    float* __restrict__ partial,                 // [z*LQ][8]
    float scale)
{
    __shared__ _Float16 lsA[2][256 * 64];
    __shared__ _Float16 lsB[2][256 * 64];
    const int tid = threadIdx.x;
    const int w = tid >> 6, l = tid & 63;
    const int wr = w >> 2, wc = w & 3;          // wave grid 2M x 4N
    const int lrg = l >> 4, lc = l & 15, lr = lrg << 2;

    // T1 bijective XCD swizzle (nwg = 256, %8 == 0)
    int id = blockIdx.x + gridDim.x * (blockIdx.y + gridDim.y * blockIdx.z);
    const int nwg = gridDim.x * gridDim.y * gridDim.z;
    id = (id & 7) * (nwg >> 3) + (id >> 3);
    const int bx = id % gridDim.x;              // 0..7
    const int t2 = id / gridDim.x;
    const int by = t2 % gridDim.y;              // 0..1
    const int z  = t2 / gridDim.y;
    const int m0 = by * 256, n0 = bx * 256;

    const _Float16* Ab = A + (size_t)z * sA + (size_t)m0 * DD;
    const _Float16* Bb = B + (size_t)z * sB + (size_t)n0 * DD;

    // staging lane geometry (identical to proven 128^2 kernel)
    const int srow = l >> 3;
    const int sk = ((l & 7) ^ srow) << 3;       // pre-swizzled source k-offset (f16)

    // stage one 128-row half-tile: 2 x gl_lds16 per thread (16KB total)
#define STG(dst, srcbase)                                                     \
    do {                                                                      \
        _Pragma("unroll")                                                     \
        for (int rr = 0; rr < 2; ++rr) {                                      \
            const int c = w + 8 * rr;                                         \
            gl_lds16((srcbase) + (size_t)(c * 8 + srow) * DD + sk,            \
                     (dst) + c * 512);                                        \
        }                                                                     \
    } while (0)

    half8 af[4][2], bf01[2][2], bf23[2][2];
    f32x4 acc[8][4] = {};
    const int rsb = (lc & 7) << 4;              // row-XOR swizzle bits

#define LDA(buf, mh)                                                          \
    do {                                                                      \
        const char* p_ = (const char*)lsA[buf];                               \
        _Pragma("unroll")                                                     \
        for (int ii = 0; ii < 4; ++ii) {                                      \
            const int row_ = wr * 128 + (mh) * 64 + ii * 16 + lc;             \
            _Pragma("unroll")                                                 \
            for (int kk = 0; kk < 2; ++kk)                                    \
                af[ii][kk] = *(const half8*)(p_ + row_ * 128 +                \
                             ((kk * 64 + (lrg << 4)) ^ rsb));                 \
        }                                                                     \
    } while (0)

#define LDB(buf, nh, bfr)                                                     \
    do {                                                                      \
        const char* p_ = (const char*)lsB[buf];                               \
        _Pragma("unroll")                                                     \
        for (int jj = 0; jj < 2; ++jj) {                                      \
            const int row_ = wc * 64 + ((nh) * 2 + jj) * 16 + lc;             \
            _Pragma("unroll")                                                 \
            for (int kk = 0; kk < 2; ++kk)                                    \
                bfr[jj][kk] = *(const half8*)(p_ + row_ * 128 +               \
                              ((kk * 64 + (lrg << 4)) ^ rsb));                \
        }                                                                     \
    } while (0)

#define MM(mh, nh, bfr)                                                       \
    do {                                                                      \
        __builtin_amdgcn_s_setprio(1);                                        \
        _Pragma("unroll")                                                     \
        for (int ii = 0; ii < 4; ++ii)                                        \
            _Pragma("unroll")                                                 \
            for (int jj = 0; jj < 2; ++jj)                                    \
                _Pragma("unroll")                                             \
                for (int kk = 0; kk < 2; ++kk)                                \
                    acc[(mh) * 4 + ii][(nh) * 2 + jj] =                       \
                        __builtin_amdgcn_mfma_f32_16x16x32_f16(               \
                            af[ii][kk], bfr[jj][kk],                          \
                            acc[(mh) * 4 + ii][(nh) * 2 + jj], 0, 0, 0);      \
        __builtin_amdgcn_s_setprio(0);                                        \
    } while (0)

#define BAR __builtin_amdgcn_s_barrier()
#define VMW(n) asm volatile("s_waitcnt vmcnt(" #n ")" ::: "memory")

    // prologue: tile0 (4 half-tiles) + tile1.A.lo
    STG(&lsA[0][0], Ab);
    STG(&lsA[0][128 * 64], Ab + (size_t)128 * DD);
    STG(&lsB[0][0], Bb);
    STG(&lsB[0][128 * 64], Bb + (size_t)128 * DD);
    STG(&lsA[1][0], Ab + 64);
    VMW(2);
    BAR;

    for (int i = 0; i < 7; ++i) {
        const int kt1 = (2 * i + 1) * 64, kt2 = kt1 + 64, kt3 = kt2 + 64;
        // P0: consume buf0 quad(m0,n01); stage t1.A.hi
        LDA(0, 0); LDB(0, 0, bf01);
        STG(&lsA[1][128 * 64], Ab + (size_t)128 * DD + kt1);
        BAR; MM(0, 0, bf01); BAR;
        // P1: stage t1.B.lo
        LDB(0, 1, bf23);
        STG(&lsB[1][0], Bb + kt1);
        BAR; MM(0, 1, bf23); BAR;
        // P2: stage t1.B.hi
        LDA(0, 1);
        STG(&lsB[1][128 * 64], Bb + (size_t)128 * DD + kt1);
        BAR; MM(1, 0, bf01); BAR;
        // P3: stage t2.A.lo (buf0 reads done); tile-boundary vmcnt
        STG(&lsA[0][0], Ab + kt2);
        BAR; MM(1, 1, bf23);
        VMW(2); BAR;
        // P4: consume buf1; stage t2.A.hi
        LDA(1, 0); LDB(1, 0, bf01);
        STG(&lsA[0][128 * 64], Ab + (size_t)128 * DD + kt2);
        BAR; MM(0, 0, bf01); BAR;
        // P5: stage t2.B.lo
        LDB(1, 1, bf23);
        STG(&lsB[0][0], Bb + kt2);
        BAR; MM(0, 1, bf23); BAR;
        // P6: stage t2.B.hi
        LDA(1, 1);
        STG(&lsB[0][128 * 64], Bb + (size_t)128 * DD + kt2);
        BAR; MM(1, 0, bf01); BAR;
        // P7: stage t3.A.lo (buf1 reads done); tile-boundary vmcnt
        STG(&lsA[1][0], Ab + kt3);
        BAR; MM(1, 1, bf23);
        VMW(2); BAR;
    }
    {   // tail iteration (tiles 14,15): no stages past tile 15
        const int kt1 = 15 * 64;
        LDA(0, 0); LDB(0, 0, bf01);
        STG(&lsA[1][128 * 64], Ab + (size_t)128 * DD + kt1);
        BAR; MM(0, 0, bf01); BAR;
        LDB(0, 1, bf23);
        STG(&lsB[1][0], Bb + kt1);
        BAR; MM(0, 1, bf23); BAR;
        LDA(0, 1);
        STG(&lsB[1][128 * 64], Bb + (size_t)128 * DD + kt1);
        BAR; MM(1, 0, bf01); BAR;
        BAR; MM(1, 1, bf23);
        VMW(0); BAR;
        LDA(1, 0); LDB(1, 0, bf01);
        BAR; MM(0, 0, bf01); BAR;
        LDB(1, 1, bf23);
        BAR; MM(0, 1, bf23); BAR;
        LDA(1, 1);
        BAR; MM(1, 0, bf01); BAR;
        BAR; MM(1, 1, bf23);
    }
    __syncthreads();

    // epilogue: exp + f16 P store + 8-wide row partial sums (psum overlays lsA)
    _Float16* Cb = P + (size_t)z * sP;
    float* psum = (float*)&lsA[0][0];           // [256][4]
    #pragma unroll
    for (int i = 0; i < 8; ++i) {
        float rsum[4] = {0.f, 0.f, 0.f, 0.f};
        #pragma unroll
        for (int j = 0; j < 4; ++j) {
            const int n = n0 + wc * 64 + j * 16 + lc;
            #pragma unroll
            for (int r = 0; r < 4; ++r) {
                const int m = m0 + wr * 128 + i * 16 + lr + r;
                const float e = __expf(acc[i][j][r] * scale);
                Cb[(size_t)m * LKK + n] = (_Float16)e;
                rsum[r] += e;
            }
        }
        #pragma unroll
        for (int r = 0; r < 4; ++r) {
            float s = rsum[r];
            s += __shfl_xor(s, 1);
            s += __shfl_xor(s, 2);
            s += __shfl_xor(s, 4);
            s += __shfl_xor(s, 8);
            if (lc == 0) psum[(wr * 128 + i * 16 + lr + r) * 4 + wc] = s;
        }
    }
    __syncthreads();
    if (tid < 256) {
        const float* pr = psum + tid * 4;
        partial[((size_t)z * LQ + m0 + tid) * 8 + bx] = pr[0] + pr[1] + pr[2] + pr[3];
    }
#undef STG
#undef LDA
#undef LDB
#undef MM
#undef BAR
#undef VMW
}

// ---------------------------------------------------------------------------
// f16 MFMA NT-GEMM: acc[m,n] = sum_k A[m,k] * B[n,k]  (128x128 tile, BK=64)
// mode 0: P16 = exp(acc*scale), row partial sums -> partial[row*16+bx]
// mode 1: out16 = acc * inv(row); inv from inv[] or folded from partial[] (npart wide)
// mode 2: t = tanh(acc+bias[n]) -> out16 and/or out32
// mode 4: out32 = acc*scale
// ---------------------------------------------------------------------------
__global__ __launch_bounds__(256) void gemm_f16_nt(
    const _Float16* __restrict__ Alo, long sAlo, int lda_lo,
    const _Float16* __restrict__ Ahi, long sAhi, int lda_hi,
    int ksplit,
    const _Float16* __restrict__ B, long sB, int ldb,
    int K, int mode, float scale,
    float* __restrict__ out32, long s32, int ldc32,
    _Float16* __restrict__ out16, long s16, int ldc16,
    const float* __restrict__ bias,
    float* __restrict__ partial, const float* __restrict__ inv, int npart)
{
    __shared__ _Float16 lsA[128 * 64];
    __shared__ _Float16 lsB[128 * 64];
    __shared__ float psum[128][2];
    const int tid = threadIdx.x;
    const int w = tid >> 6, l = tid & 63;
    const int wr = w >> 1, wc = w & 1;

    int id = blockIdx.x + gridDim.x * (blockIdx.y + gridDim.y * blockIdx.z);
    const int nwg = gridDim.x * gridDim.y * gridDim.z;
    id = (id & 7) * (nwg >> 3) + (id >> 3);
    const int bx = id % gridDim.x;
    const int t2 = id / gridDim.x;
    const int by = t2 % gridDim.y;
    const int z = t2 / gridDim.y;
    const int m0 = by * 128, n0 = bx * 128;

    const _Float16* Abase_lo = Alo + (size_t)z * sAlo + (size_t)m0 * lda_lo;
    const _Float16* Abase_hi = Ahi ? (Ahi + (size_t)z * sAhi + (size_t)m0 * lda_hi) : (const _Float16*)0;
    const _Float16* Bbase = B + (size_t)z * sB + (size_t)n0 * ldb;

    const int srow = l >> 3;
    const int sswz = ((l & 7) ^ srow) << 3;

    f32x4 acc[4][4] = {};

    for (int k0 = 0; k0 < K; k0 += 64) {
        const _Float16* Ap; int kloc, ldaA;
        if (k0 < ksplit) { Ap = Abase_lo; kloc = k0;          ldaA = lda_lo; }
        else             { Ap = Abase_hi; kloc = k0 - ksplit; ldaA = lda_hi; }
        #pragma unroll
        for (int i = 0; i < 4; ++i) {
            const int c = w * 4 + i;
            const int row = c * 8 + srow;
            gl_lds16(Ap + (size_t)row * ldaA + kloc + sswz, &lsA[c * 512]);
        }
        #pragma unroll
        for (int i = 0; i < 4; ++i) {
            const int c = w * 4 + i;
            const int row = c * 8 + srow;
            gl_lds16(Bbase + (size_t)row * ldb + k0 + sswz, &lsB[c * 512]);
        }
        __syncthreads();

        half8 af[4][2], bf[4][2];
        const char* lA = (const char*)lsA;
        const char* lB = (const char*)lsB;
        const int rs = (l & 7) << 4;
        const int cb = (l >> 4) << 4;
        #pragma unroll
        for (int i = 0; i < 4; ++i) {
            const int rowa = wr * 64 + i * 16 + (l & 15);
            const int rowb = wc * 64 + i * 16 + (l & 15);
            #pragma unroll
            for (int kk = 0; kk < 2; ++kk) {
                af[i][kk] = *(const half8*)(lA + rowa * 128 + ((kk * 64 + cb) ^ rs));
                bf[i][kk] = *(const half8*)(lB + rowb * 128 + ((kk * 64 + cb) ^ rs));
            }
        }
        #pragma unroll
        for (int kk = 0; kk < 2; ++kk)
            #pragma unroll
            for (int i = 0; i < 4; ++i)
                #pragma unroll
                for (int j = 0; j < 4; ++j)
                    acc[i][j] = __builtin_amdgcn_mfma_f32_16x16x32_f16(
                        af[i][kk], bf[j][kk], acc[i][j], 0, 0, 0);
        __syncthreads();
    }

    const int lr = (l >> 4) * 4;
    const int lc = l & 15;
    if (mode == 0) {
        _Float16* Cb = out16 + (size_t)z * s16;
        float rsum[4][4];
        #pragma unroll
        for (int i = 0; i < 4; ++i)
            #pragma unroll
            for (int r = 0; r < 4; ++r) rsum[i][r] = 0.0f;
        #pragma unroll
        for (int i = 0; i < 4; ++i)
            #pragma unroll
            for (int j = 0; j < 4; ++j) {
                const int n = n0 + wc * 64 + j * 16 + lc;
                #pragma unroll
                for (int r = 0; r < 4; ++r) {
                    const int m = m0 + wr * 64 + i * 16 + lr + r;
                    const float e = __expf(acc[i][j][r] * scale);
                    Cb[(size_t)m * ldc16 + n] = (_Float16)e;
                    rsum[i][r] += e;
                }
            }
        #pragma unroll
        for (int i = 0; i < 4; ++i)
            #pragma unroll
            for (int r = 0; r < 4; ++r) {
                float s = rsum[i][r];
                s += __shfl_xor(s, 1);
                s += __shfl_xor(s, 2);
                s += __shfl_xor(s, 4);
                s += __shfl_xor(s, 8);
                rsum[i][r] = s;
            }
        if (lc == 0) {
            #pragma unroll
            for (int i = 0; i < 4; ++i)
                #pragma unroll
                for (int r = 0; r < 4; ++r)
                    psum[wr * 64 + i * 16 + lr + r][wc] = rsum[i][r];
        }
        __syncthreads();
        if (tid < 128)
            partial[((size_t)z * LQ + m0 + tid) * npart + bx] = psum[tid][0] + psum[tid][1];
    } else if (mode == 1) {
        _Float16* Cb = out16 + (size_t)z * s16;
        float iv[4][4];
        if (partial) {
            if (tid < 128) {
                const float* pp = partial + ((size_t)z * LQ + m0 + tid) * npart;
                float s = 0.0f;
                for (int c = 0; c < npart; ++c) s += pp[c];
                psum[tid][0] = 1.0f / s;
            }
            __syncthreads();
            #pragma unroll
            for (int i = 0; i < 4; ++i)
                #pragma unroll
                for (int r = 0; r < 4; ++r)
                    iv[i][r] = psum[wr * 64 + i * 16 + lr + r][0];
        } else {
            #pragma unroll
            for (int i = 0; i < 4; ++i)
                #pragma unroll
                for (int r = 0; r < 4; ++r)
                    iv[i][r] = inv ? inv[(size_t)z * LQ + m0 + wr * 64 + i * 16 + lr + r] : 1.0f;
        }
        #pragma unroll
        for (int i = 0; i < 4; ++i)
            #pragma unroll
            for (int j = 0; j < 4; ++j) {
                const int n = n0 + wc * 64 + j * 16 + lc;
                #pragma unroll
                for (int r = 0; r < 4; ++r) {
                    const int m = m0 + wr * 64 + i * 16 + lr + r;
                    Cb[(size_t)m * ldc16 + n] = (_Float16)(acc[i][j][r] * iv[i][r]);
                }
            }
    } else if (mode == 4) {
        float* Cb = out32 + (size_t)z * s32;
        #pragma unroll
        for (int i = 0; i < 4; ++i)
            #pragma unroll
            for (int j = 0; j < 4; ++j) {
                const int n = n0 + wc * 64 + j * 16 + lc;
                #pragma unroll
                for (int r = 0; r < 4; ++r) {
                    const int m = m0 + wr * 64 + i * 16 + lr + r;
                    Cb[(size_t)m * ldc32 + n] = acc[i][j][r] * scale;
                }
            }
    } else {
        float bv[4];
        #pragma unroll
        for (int j = 0; j < 4; ++j)
            bv[j] = bias[n0 + wc * 64 + j * 16 + lc];
        #pragma unroll
        for (int i = 0; i < 4; ++i)
            #pragma unroll
            for (int j = 0; j < 4; ++j) {
                const int n = n0 + wc * 64 + j * 16 + lc;
                #pragma unroll
                for (int r = 0; r < 4; ++r) {
                    const int m = m0 + wr * 64 + i * 16 + lr + r;
                    const float t = tanhf(acc[i][j][r] + bv[j]);
                    if (out16) out16[(size_t)z * s16 + (size_t)m * ldc16 + n] = (_Float16)t;
                    if (out32) out32[(size_t)z * s32 + (size_t)m * ldc32 + n] = t;
                }
            }
    }
}

// one block per row: attn_f32[row,:] = P16[row,:] * (1/sum partial[row,0..npart))
__global__ __launch_bounds__(256) void scale_attn(
    const _Float16* __restrict__ P, const float* __restrict__ partial,
    float* __restrict__ attn, int npart)
{
    __shared__ float sinv;
    const long row = blockIdx.x;
    const int tid = threadIdx.x;
    if (tid < npart) {
        float s = partial[row * npart + tid];
        for (int off = npart >> 1; off > 0; off >>= 1) s += __shfl_xor(s, off);
        if (tid == 0) sinv = 1.0f / s;
    }
    __syncthreads();
    const float inv = sinv;
    const half8 h = *(const half8*)(P + row * 2048 + tid * 8);
    float* o = attn + row * 2048 + tid * 8;
    float4 a = make_float4((float)h[0] * inv, (float)h[1] * inv,
                           (float)h[2] * inv, (float)h[3] * inv);
    float4 b = make_float4((float)h[4] * inv, (float)h[5] * inv,
                           (float)h[6] * inv, (float)h[7] * inv);
    *(float4*)o = a;
    *(float4*)(o + 4) = b;
}

// inv[row] = 1 / sum_{cb<16} partial[row*16+cb]   (R3-fallback path)
__global__ __launch_bounds__(256) void make_inv(
    const float* __restrict__ partial, float* __restrict__ inv)
{
    const int row = blockIdx.x * 256 + threadIdx.x;
    const float4 a = *(const float4*)(partial + (size_t)row * 16);
    const float4 b = *(const float4*)(partial + (size_t)row * 16 + 4);
    const float4 c = *(const float4*)(partial + (size_t)row * 16 + 8);
    const float4 d = *(const float4*)(partial + (size_t)row * 16 + 12);
    const float s = (a.x + a.y + a.z + a.w) + (b.x + b.y + b.z + b.w)
                  + (c.x + c.y + c.z + c.w) + (d.x + d.y + d.z + d.w);
    inv[row] = 1.0f / s;
}

// row softmax over 2048 f32 (R3-fallback hop 2)
__global__ __launch_bounds__(256) void softmax_rows2(
    float* __restrict__ S, _Float16* __restrict__ f16out,
    long f16stride, int write_f32)
{
    __shared__ float red[8];
    const long row = blockIdx.x;
    float* p = S + row * LKK;
    const int tid = threadIdx.x;
    float4 v0 = ((const float4*)p)[tid];
    float4 v1 = ((const float4*)p)[tid + 256];
    float m = fmaxf(fmaxf(fmaxf(v0.x, v0.y), fmaxf(v0.z, v0.w)),
                    fmaxf(fmaxf(v1.x, v1.y), fmaxf(v1.z, v1.w)));
    #pragma unroll
    for (int off = 32; off > 0; off >>= 1) m = fmaxf(m, __shfl_down(m, off));
    if ((tid & 63) == 0) red[tid >> 6] = m;
    __syncthreads();
    m = fmaxf(fmaxf(red[0], red[1]), fmaxf(red[2], red[3]));
    v0.x = expf(v0.x - m); v0.y = expf(v0.y - m);
    v0.z = expf(v0.z - m); v0.w = expf(v0.w - m);
    v1.x = expf(v1.x - m); v1.y = expf(v1.y - m);
    v1.z = expf(v1.z - m); v1.w = expf(v1.w - m);
    float s = v0.x + v0.y + v0.z + v0.w + v1.x + v1.y + v1.z + v1.w;
    #pragma unroll
    for (int off = 32; off > 0; off >>= 1) s += __shfl_down(s, off);
    if ((tid & 63) == 0) red[4 + (tid >> 6)] = s;
    __syncthreads();
    s = red[4] + red[5] + red[6] + red[7];
    const float inv = 1.0f / s;
    v0.x *= inv; v0.y *= inv; v0.z *= inv; v0.w *= inv;
    v1.x *= inv; v1.y *= inv; v1.z *= inv; v1.w *= inv;
    if (write_f32) {
        ((float4*)p)[tid] = v0;
        ((float4*)p)[tid + 256] = v1;
    }
    _Float16* q = f16out + row * f16stride;
    half4 h0 = { (_Float16)v0.x, (_Float16)v0.y, (_Float16)v0.z, (_Float16)v0.w };
    half4 h1 = { (_Float16)v1.x, (_Float16)v1.y, (_Float16)v1.z, (_Float16)v1.w };
    *(half4*)(q + tid * 4) = h0;
    *(half4*)(q + 1024 + tid * 4) = h1;
}

__global__ __launch_bounds__(256) void cvt_f32_to_f16(
    const float* __restrict__ in, _Float16* __restrict__ out, long n)
{
    const long i = ((long)blockIdx.x * 256 + threadIdx.x) * 8;
    if (i + 8 > n) return;
    float4 a = *(const float4*)(in + i);
    float4 b = *(const float4*)(in + i + 4);
    half8 h = { (_Float16)a.x, (_Float16)a.y, (_Float16)a.z, (_Float16)a.w,
                (_Float16)b.x, (_Float16)b.y, (_Float16)b.z, (_Float16)b.w };
    *(half8*)(out + i) = h;
}

// V [B, Lk, D] f32 -> Vt [B, D, Lk] f16, 64x64 tiles via LDS
__global__ __launch_bounds__(256) void transpose_cvt_v(
    const float* __restrict__ V, _Float16* __restrict__ Vt)
{
    __shared__ _Float16 t[64][80];
    const int z = blockIdx.z;
    const int k0 = blockIdx.y * 64, d0 = blockIdx.x * 64;
    const float* Vb = V + (size_t)z * LKK * DD;
    _Float16* Vtb = Vt + (size_t)z * DD * LKK;
    const int r = threadIdx.x >> 2;
    const int c0 = (threadIdx.x & 3) * 16;
    #pragma unroll
    for (int j = 0; j < 4; ++j) {
        float4 v = *(const float4*)(Vb + (size_t)(k0 + r) * DD + d0 + c0 + j * 4);
        t[c0 + j * 4 + 0][r] = (_Float16)v.x;
        t[c0 + j * 4 + 1][r] = (_Float16)v.y;
        t[c0 + j * 4 + 2][r] = (_Float16)v.z;
        t[c0 + j * 4 + 3][r] = (_Float16)v.w;
    }
    __syncthreads();
    #pragma unroll
    for (int j = 0; j < 2; ++j) {
        half8 h = *(const half8*)&t[r][c0 + j * 8];
        *(half8*)(Vtb + (size_t)(d0 + r) * LKK + k0 + c0 + j * 8) = h;
    }
}

// ======================= round-1 f32 fallback kernels =======================
constexpr int TM = 64, TN = 64, TK = 32;
constexpr int PAD = 4;

__global__ __launch_bounds__(256) void gemm_nt_k(
    const float* __restrict__ A, int lda, long sA,
    const float* __restrict__ Bt, int ldb, long sB,
    float* __restrict__ C, int ldc, long sC, int K, float scale)
{
    __shared__ float As[TK][TM + PAD];
    __shared__ float Bs[TK][TN + PAD];
    const float* Ab = A + (long)blockIdx.z * sA;
    const float* Bb = Bt + (long)blockIdx.z * sB;
    float* Cb = C + (long)blockIdx.z * sC;
    const int m0 = blockIdx.y * TM, n0 = blockIdx.x * TN;
    const int tid = threadIdx.x;
    const int tn = tid & 15, tm = tid >> 4;
    float acc[4][4] = {};
    for (int k0 = 0; k0 < K; k0 += TK) {
        #pragma unroll
        for (int c = tid; c < (TM * TK) / 4; c += 256) {
            const int row = c >> 3, kc = (c & 7) << 2;
            const float4 g = *(const float4*)(Ab + (long)(m0 + row) * lda + (k0 + kc));
            As[kc + 0][row] = g.x; As[kc + 1][row] = g.y;
            As[kc + 2][row] = g.z; As[kc + 3][row] = g.w;
        }
        #pragma unroll
        for (int c = tid; c < (TN * TK) / 4; c += 256) {
            const int row = c >> 3, kc = (c & 7) << 2;
            const float4 g = *(const float4*)(Bb + (long)(n0 + row) * ldb + (k0 + kc));
            Bs[kc + 0][row] = g.x; Bs[kc + 1][row] = g.y;
            Bs[kc + 2][row] = g.z; Bs[kc + 3][row] = g.w;
        }
        __syncthreads();
        #pragma unroll
        for (int kk = 0; kk < TK; ++kk) {
            const float4 av = *(const float4*)&As[kk][tm << 2];
            const float4 bv = *(const float4*)&Bs[kk][tn << 2];
            const float a[4] = {av.x, av.y, av.z, av.w};
            const float b[4] = {bv.x, bv.y, bv.z, bv.w};
            #pragma unroll
            for (int i = 0; i < 4; ++i)
                #pragma unroll
                for (int j = 0; j < 4; ++j)
                    acc[i][j] = fmaf(a[i], b[j], acc[i][j]);
        }
        __syncthreads();
    }
    #pragma unroll
    for (int i = 0; i < 4; ++i) {
        float4 o = make_float4(acc[i][0] * scale, acc[i][1] * scale,
                               acc[i][2] * scale, acc[i][3] * scale);
        *(float4*)(Cb + (long)(m0 + (tm << 2) + i) * ldc + n0 + (tn << 2)) = o;
    }
}

__global__ __launch_bounds__(256) void gemm_nn_k(
    const float* __restrict__ A, int lda, long sA,
    const float* __restrict__ B, int ldb, long sB,
    float* __restrict__ C, int ldc, long sC, int K)
{
    __shared__ float As[TK][TM + PAD];
    __shared__ float Bs[TK][TN + PAD];
    const float* Ab = A + (long)blockIdx.z * sA;
    const float* Bb = B + (long)blockIdx.z * sB;
    float* Cb = C + (long)blockIdx.z * sC;
    const int m0 = blockIdx.y * TM, n0 = blockIdx.x * TN;
    const int tid = threadIdx.x;
    const int tn = tid & 15, tm = tid >> 4;
    float acc[4][4] = {};
    for (int k0 = 0; k0 < K; k0 += TK) {
        #pragma unroll
        for (int c = tid; c < (TM * TK) / 4; c += 256) {
            const int row = c >> 3, kc = (c & 7) << 2;
            const float4 g = *(const float4*)(Ab + (long)(m0 + row) * lda + (k0 + kc));
            As[kc + 0][row] = g.x; As[kc + 1][row] = g.y;
            As[kc + 2][row] = g.z; As[kc + 3][row] = g.w;
        }
        #pragma unroll
        for (int c = tid; c < (TK * TN) / 4; c += 256) {
            const int krow = c >> 4, nc = (c & 15) << 2;
            *(float4*)&Bs[krow][nc] =
                *(const float4*)(Bb + (long)(k0 + krow) * ldb + n0 + nc);
        }
        __syncthreads();
        #pragma unroll
        for (int kk = 0; kk < TK; ++kk) {
            const float4 av = *(const float4*)&As[kk][tm << 2];
            const float4 bv = *(const float4*)&Bs[kk][tn << 2];
            const float a[4] = {av.x, av.y, av.z, av.w};
            const float b[4] = {bv.x, bv.y, bv.z, bv.w};
            #pragma unroll
            for (int i = 0; i < 4; ++i)
                #pragma unroll
                for (int j = 0; j < 4; ++j)
                    acc[i][j] = fmaf(a[i], b[j], acc[i][j]);
        }
        __syncthreads();
    }
    #pragma unroll
    for (int i = 0; i < 4; ++i) {
        float4 o = make_float4(acc[i][0], acc[i][1], acc[i][2], acc[i][3]);
        *(float4*)(Cb + (long)(m0 + (tm << 2) + i) * ldc + n0 + (tn << 2)) = o;
    }
}

__global__ __launch_bounds__(256) void gemm_cat_k(
    const float* __restrict__ Qh, const float* __restrict__ R,
    const float* __restrict__ W, const float* __restrict__ bias,
    float* __restrict__ C)
{
    __shared__ float As[TK][TM + PAD];
    __shared__ float Bs[TK][TN + PAD];
    const float* Qb = Qh + (long)blockIdx.z * LQ * DD;
    const float* Rb = R + (long)blockIdx.z * LQ * DD;
    float* Cb = C + (long)blockIdx.z * LQ * DD;
    const int m0 = blockIdx.y * TM, n0 = blockIdx.x * TN;
    const int tid = threadIdx.x;
    const int tn = tid & 15, tm = tid >> 4;
    float acc[4][4] = {};
    for (int k0 = 0; k0 < 2 * DD; k0 += TK) {
        const float* src = (k0 < DD) ? Qb : Rb;
        const int kb = (k0 < DD) ? k0 : k0 - DD;
        #pragma unroll
        for (int c = tid; c < (TM * TK) / 4; c += 256) {
            const int row = c >> 3, kc = (c & 7) << 2;
            const float4 g = *(const float4*)(src + (long)(m0 + row) * DD + (kb + kc));
            As[kc + 0][row] = g.x; As[kc + 1][row] = g.y;
            As[kc + 2][row] = g.z; As[kc + 3][row] = g.w;
        }
        #pragma unroll
        for (int c = tid; c < (TN * TK) / 4; c += 256) {
            const int row = c >> 3, kc = (c & 7) << 2;
            const float4 g = *(const float4*)(W + (long)(n0 + row) * (2 * DD) + (k0 + kc));
            Bs[kc + 0][row] = g.x; Bs[kc + 1][row] = g.y;
            Bs[kc + 2][row] = g.z; Bs[kc + 3][row] = g.w;
        }
        __syncthreads();
        #pragma unroll
        for (int kk = 0; kk < TK; ++kk) {
            const float4 av = *(const float4*)&As[kk][tm << 2];
            const float4 bv = *(const float4*)&Bs[kk][tn << 2];
            const float a[4] = {av.x, av.y, av.z, av.w};
            const float b[4] = {bv.x, bv.y, bv.z, bv.w};
            #pragma unroll
            for (int i = 0; i < 4; ++i)
                #pragma unroll
                for (int j = 0; j < 4; ++j)
                    acc[i][j] = fmaf(a[i], b[j], acc[i][j]);
        }
        __syncthreads();
    }
    #pragma unroll
    for (int i = 0; i < 4; ++i) {
        float4 o;
        o.x = tanhf(acc[i][0] + bias[n0 + (tn << 2) + 0]);
        o.y = tanhf(acc[i][1] + bias[n0 + (tn << 2) + 1]);
        o.z = tanhf(acc[i][2] + bias[n0 + (tn << 2) + 2]);
        o.w = tanhf(acc[i][3] + bias[n0 + (tn << 2) + 3]);
        *(float4*)(Cb + (long)(m0 + (tm << 2) + i) * DD + n0 + (tn << 2)) = o;
    }
}

__global__ __launch_bounds__(256) void softmax_rows(float* __restrict__ S) {
    __shared__ float red[8];
    float* p = S + (size_t)blockIdx.x * LKK;
    const int tid = threadIdx.x;
    float4 v0 = ((const float4*)p)[tid];
    float4 v1 = ((const float4*)p)[tid + 256];
    float m = fmaxf(fmaxf(fmaxf(v0.x, v0.y), fmaxf(v0.z, v0.w)),
                    fmaxf(fmaxf(v1.x, v1.y), fmaxf(v1.z, v1.w)));
    #pragma unroll
    for (int off = 32; off > 0; off >>= 1) m = fmaxf(m, __shfl_down(m, off));
    if ((tid & 63) == 0) red[tid >> 6] = m;
    __syncthreads();
    m = fmaxf(fmaxf(red[0], red[1]), fmaxf(red[2], red[3]));
    v0.x = expf(v0.x - m); v0.y = expf(v0.y - m);
    v0.z = expf(v0.z - m); v0.w = expf(v0.w - m);
    v1.x = expf(v1.x - m); v1.y = expf(v1.y - m);
    v1.z = expf(v1.z - m); v1.w = expf(v1.w - m);
    float s = v0.x + v0.y + v0.z + v0.w + v1.x + v1.y + v1.z + v1.w;
    #pragma unroll
    for (int off = 32; off > 0; off >>= 1) s += __shfl_down(s, off);
    if ((tid & 63) == 0) red[4 + (tid >> 6)] = s;
    __syncthreads();
    s = red[4] + red[5] + red[6] + red[7];
    const float inv = 1.0f / s;
    v0.x *= inv; v0.y *= inv; v0.z *= inv; v0.w *= inv;
    v1.x *= inv; v1.y *= inv; v1.z *= inv; v1.w *= inv;
    ((float4*)p)[tid] = v0;
    ((float4*)p)[tid + 256] = v1;
}

// ===========================================================================
extern "C" void kernel_launch(void* const* d_in, const int* in_sizes, int n_in,
                              void* d_out, int out_size, void* d_ws, size_t ws_size,
                              hipStream_t stream) {
    const float* Q    = (const float*)d_in[0];
    const float* Km   = (const float*)d_in[1];
    const float* V    = (const float*)d_in[2];
    const float* W    = (const float*)d_in[3];
    const float* bias = (const float*)d_in[4];
    const float scale = 0.03125f;  // 1/sqrt(1024)
    dim3 blk(256);

    const size_t NEED_FULL = 189267968ULL;  // Kh+Vt+Wh+Rh+Qping+Qpong+partial
    const size_t NEED_R3   = 155189248ULL;  // Kh+Vt+Wh+Rh

    if (ws_size >= NEED_FULL) {
        char* ws = (char*)d_ws;
        _Float16* Kh     = (_Float16*)ws;                    // [16,2048,1024]
        _Float16* Vt     = (_Float16*)(ws + 67108864);       // [16,1024,2048]
        _Float16* Wh     = (_Float16*)(ws + 134217728);      // [1024,2048]
        _Float16* Rh     = (_Float16*)(ws + 138412032);      // [16,512,1024]
        _Float16* Qping  = (_Float16*)(ws + 155189248);      // [16,512,1024]
        _Float16* Qpong  = (_Float16*)(ws + 171966464);      // [16,512,1024]
        float*    partialB = (float*)(ws + 188743680);       // [8192,8] (alloc 16-wide)

        float*    outQ  = (float*)d_out;                     // final Q f32 [0,33.5M)
        _Float16* P2    = (_Float16*)d_out;                  // hop2 P f16, same region
        float*    attnF = (float*)((char*)d_out + 33554432); // attn f32 [33.5M,100.6M)
        _Float16* P01   = (_Float16*)attnF;                  // hops0/1 P f16 (scratch)

        cvt_f32_to_f16<<<4096, blk, 0, stream>>>(Q, Qping, (long)NB * LQ * DD);
        cvt_f32_to_f16<<<16384, blk, 0, stream>>>(Km, Kh, (long)NB * LKK * DD);
        cvt_f32_to_f16<<<1024, blk, 0, stream>>>(W, Wh, (long)DD * 2 * DD);
        transpose_cvt_v<<<dim3(DD / 64, LKK / 64, NB), blk, 0, stream>>>(V, Vt);

        dim3 gS2(LKK / 256, LQ / 256, NB);  // 8 x 2 x 16 = 256 blocks
        dim3 gR(DD / 128, LQ / 128, NB);    // PV / cat: 8 x 4 x 16 = 512 blocks

        for (int h = 0; h < 3; ++h) {
            _Float16* qcur = (h == 1) ? Qpong : Qping;
            _Float16* P    = (h == 2) ? P2 : P01;

            // ---- fused 8-phase 256^2: P = exp(Qh K^T * scale), 8-wide partials
            gemm_qk_256<<<gS2, dim3(512), 0, stream>>>(
                qcur, (long)LQ * DD, Kh, (long)LKK * DD,
                P, (long)LQ * LKK, partialB, scale);
            if (h == 2)  // attn output: f32 = P * inv(row)
                scale_attn<<<NB * LQ, blk, 0, stream>>>(P2, partialB, attnF, 8);
            // ---- R = (P V) * inv(row), inv folded from 8-wide partials
            gemm_f16_nt<<<gR, blk, 0, stream>>>(
                P, (long)LQ * LKK, LKK,
                (const _Float16*)0, 0, 0, LKK,
                Vt, (long)DD * LKK, LKK, LKK,
                1, 1.0f, (float*)0, 0, 0,
                Rh, (long)LQ * DD, DD, (const float*)0,
                partialB, (const float*)0, 8);
            // ---- Qnext = tanh([Qh|R] W^T + b)
            _Float16* qn = (h == 0) ? Qpong : (h == 1) ? Qping : (_Float16*)0;
            float* fo = (h == 2) ? outQ : (float*)0;
            gemm_f16_nt<<<gR, blk, 0, stream>>>(
                qcur, (long)LQ * DD, DD,
                Rh, (long)LQ * DD, DD, DD,
                Wh, 0, 2 * DD, 2 * DD,
                2, 1.0f, fo, (long)LQ * DD, DD,
                qn, (long)LQ * DD, DD, bias,
                (float*)0, (const float*)0, 0);
        }
    } else if (ws_size >= NEED_R3) {
        // -------- proven R3 path --------
        char* ws = (char*)d_ws;
        _Float16* Kh  = (_Float16*)ws;
        _Float16* Vt  = (_Float16*)(ws + 67108864);
        _Float16* Wh  = (_Float16*)(ws + 134217728);
        _Float16* Rh  = (_Float16*)(ws + 138412032);
        _Float16* attn2 = (_Float16*)ws;
        float* Fout = (float*)(ws + 33554432);

        _Float16* Qping = (_Float16*)d_out;
        _Float16* Qpong = Qping + (size_t)NB * LQ * DD;
        float* S = (float*)((char*)d_out + 33554432);
        _Float16* P = (_Float16*)S;
        float* partialB = (float*)((char*)d_out + 73400320);
        float* invB     = (float*)((char*)d_out + 73924608);

        cvt_f32_to_f16<<<4096, blk, 0, stream>>>(Q, Qping, (long)NB * LQ * DD);
        cvt_f32_to_f16<<<16384, blk, 0, stream>>>(Km, Kh, (long)NB * LKK * DD);
        cvt_f32_to_f16<<<1024, blk, 0, stream>>>(W, Wh, (long)DD * 2 * DD);
        transpose_cvt_v<<<dim3(DD / 64, LKK / 64, NB), blk, 0, stream>>>(V, Vt);

        dim3 gS(LKK / 128, LQ / 128, NB);
        dim3 gR(DD / 128, LQ / 128, NB);

        for (int h = 0; h < 3; ++h) {
            _Float16* qcur = (h == 1) ? Qpong : Qping;
            if (h < 2) {
                gemm_f16_nt<<<gS, blk, 0, stream>>>(
                    qcur, (long)LQ * DD, DD, (const _Float16*)0, 0, 0, DD,
                    Kh, (long)LKK * DD, DD, DD,
                    0, scale, (float*)0, 0, 0,
                    P, (long)LQ * LKK, LKK, (const float*)0,
                    partialB, (const float*)0, 16);
                make_inv<<<32, blk, 0, stream>>>(partialB, invB);
                gemm_f16_nt<<<gR, blk, 0, stream>>>(
                    P, (long)LQ * LKK, LKK,
                    (const _Float16*)0, 0, 0, LKK,
                    Vt, (long)DD * LKK, LKK, LKK,
                    1, 1.0f, (float*)0, 0, 0,
                    Rh, (long)LQ * DD, DD, (const float*)0,
                    (float*)0, invB, 0);
            } else {
                gemm_f16_nt<<<gS, blk, 0, stream>>>(
                    qcur, (long)LQ * DD, DD, (const _Float16*)0, 0, 0, DD,
                    Kh, (long)LKK * DD, DD, DD,
                    4, scale, S, (long)LQ * LKK, LKK,
                    (_Float16*)0, 0, 0, (const float*)0,
                    (float*)0, (const float*)0, 0);
                softmax_rows2<<<NB * LQ, blk, 0, stream>>>(S, attn2, 2048L, 1);
                gemm_f16_nt<<<gR, blk, 0, stream>>>(
                    attn2, (long)LQ * LKK, LKK,
                    (const _Float16*)0, 0, 0, LKK,
                    Vt, (long)DD * LKK, LKK, LKK,
                    1, 1.0f, (float*)0, 0, 0,
                    Rh, (long)LQ * DD, DD, (const float*)0,
                    (float*)0, (const float*)0, 0);
            }
            _Float16* qn = (h == 0) ? Qpong : (h == 1) ? Qping : (_Float16*)0;
            float* fo = (h == 2) ? Fout : (float*)0;
            gemm_f16_nt<<<gR, blk, 0, stream>>>(
                qcur, (long)LQ * DD, DD,
                Rh, (long)LQ * DD, DD, DD,
                Wh, 0, 2 * DD, 2 * DD,
                2, 1.0f, fo, (long)LQ * DD, DD,
                qn, (long)LQ * DD, DD, bias,
                (float*)0, (const float*)0, 0);
        }
        hipMemcpyAsync(d_out, Fout, 33554432ULL, hipMemcpyDeviceToDevice, stream);
    } else {
        // -------- round-1 f32 fallback --------
        float* outQ = (float*)d_out;
        float* S    = outQ + (size_t)NB * LQ * DD;
        float* R    = (float*)d_ws;
        float* T    = R + (size_t)NB * LQ * DD;
        dim3 gS(LKK / TN, LQ / TM, NB);
        dim3 gR(DD / TN, LQ / TM, NB);
        for (int h = 0; h < 3; ++h) {
            const float* Qh = (h == 0) ? Q : (h == 1 ? (const float*)T : (const float*)outQ);
            float* cout = (h == 1) ? outQ : T;
            gemm_nt_k<<<gS, blk, 0, stream>>>(Qh, DD, (long)LQ * DD, Km, DD, (long)LKK * DD,
                                              S, LKK, (long)LQ * LKK, DD, scale);
            softmax_rows<<<NB * LQ, blk, 0, stream>>>(S);
            gemm_nn_k<<<gR, blk, 0, stream>>>(S, LKK, (long)LQ * LKK, V, DD, (long)LKK * DD,
                                              R, DD, (long)LQ * DD, LKK);
            gemm_cat_k<<<gR, blk, 0, stream>>>(Qh, R, W, bias, cout);
        }
        hipMemcpyAsync(outQ, T, (size_t)NB * LQ * DD * sizeof(float),
                       hipMemcpyDeviceToDevice, stream);
    }
}

// Round 6
// 500.186 us; speedup vs baseline: 8.8559x; 1.0728x over previous
//
#include <hip/hip_runtime.h>
#include <math.h>

#define NB 16
#define LQ 512
#define LKK 2048
#define DD 1024

typedef _Float16 half8 __attribute__((ext_vector_type(8)));
typedef _Float16 half4 __attribute__((ext_vector_type(4)));
typedef float f32x4 __attribute__((ext_vector_type(4)));

__device__ __forceinline__ void gl_lds16(const void* g, void* l) {
    __builtin_amdgcn_global_load_lds(
        (const __attribute__((address_space(1))) void*)g,
        (__attribute__((address_space(3))) void*)l, 16, 0, 0);
}

// ===========================================================================
// 8-phase 256x256 NT-GEMM for QK^T (BK=64, 512 thr = 8 waves 2Mx4N, 128KB LDS,
// counted vmcnt, raw s_barrier, setprio around MFMA, T2 XOR swizzle).
// Epilogue: P16 = exp(acc*scale), 8-wide row partial sums.  [proven R5]
// ===========================================================================
__global__ __launch_bounds__(512, 2) void gemm_qk_256(
    const _Float16* __restrict__ A, long sA,     // [z] 512 x 1024, lda=DD
    const _Float16* __restrict__ B, long sB,     // [z] 2048 x 1024, ldb=DD
    _Float16* __restrict__ P, long sP,           // out f16 [z] 512 x 2048
    float* __restrict__ partial,                 // [z*LQ][8]
    float scale)
{
    __shared__ _Float16 lsA[2][256 * 64];
    __shared__ _Float16 lsB[2][256 * 64];
    const int tid = threadIdx.x;
    const int w = tid >> 6, l = tid & 63;
    const int wr = w >> 2, wc = w & 3;          // wave grid 2M x 4N
    const int lrg = l >> 4, lc = l & 15, lr = lrg << 2;

    int id = blockIdx.x + gridDim.x * (blockIdx.y + gridDim.y * blockIdx.z);
    const int nwg = gridDim.x * gridDim.y * gridDim.z;
    id = (id & 7) * (nwg >> 3) + (id >> 3);
    const int bx = id % gridDim.x;
    const int t2 = id / gridDim.x;
    const int by = t2 % gridDim.y;
    const int z  = t2 / gridDim.y;
    const int m0 = by * 256, n0 = bx * 256;

    const _Float16* Ab = A + (size_t)z * sA + (size_t)m0 * DD;
    const _Float16* Bb = B + (size_t)z * sB + (size_t)n0 * DD;

    const int srow = l >> 3;
    const int sk = ((l & 7) ^ srow) << 3;

#define STG(dst, srcbase)                                                     \
    do {                                                                      \
        _Pragma("unroll")                                                     \
        for (int rr = 0; rr < 2; ++rr) {                                      \
            const int c = w + 8 * rr;                                         \
            gl_lds16((srcbase) + (size_t)(c * 8 + srow) * DD + sk,            \
                     (dst) + c * 512);                                        \
        }                                                                     \
    } while (0)

    half8 af[4][2], bf01[2][2], bf23[2][2];
    f32x4 acc[8][4] = {};
    const int rsb = (lc & 7) << 4;

#define LDA(buf, mh)                                                          \
    do {                                                                      \
        const char* p_ = (const char*)lsA[buf];                               \
        _Pragma("unroll")                                                     \
        for (int ii = 0; ii < 4; ++ii) {                                      \
            const int row_ = wr * 128 + (mh) * 64 + ii * 16 + lc;             \
            _Pragma("unroll")                                                 \
            for (int kk = 0; kk < 2; ++kk)                                    \
                af[ii][kk] = *(const half8*)(p_ + row_ * 128 +                \
                             ((kk * 64 + (lrg << 4)) ^ rsb));                 \
        }                                                                     \
    } while (0)

#define LDB(buf, nh, bfr)                                                     \
    do {                                                                      \
        const char* p_ = (const char*)lsB[buf];                               \
        _Pragma("unroll")                                                     \
        for (int jj = 0; jj < 2; ++jj) {                                      \
            const int row_ = wc * 64 + ((nh) * 2 + jj) * 16 + lc;             \
            _Pragma("unroll")                                                 \
            for (int kk = 0; kk < 2; ++kk)                                    \
                bfr[jj][kk] = *(const half8*)(p_ + row_ * 128 +               \
                              ((kk * 64 + (lrg << 4)) ^ rsb));                \
        }                                                                     \
    } while (0)

#define MM(mh, nh, bfr)                                                       \
    do {                                                                      \
        __builtin_amdgcn_s_setprio(1);                                        \
        _Pragma("unroll")                                                     \
        for (int ii = 0; ii < 4; ++ii)                                        \
            _Pragma("unroll")                                                 \
            for (int jj = 0; jj < 2; ++jj)                                    \
                _Pragma("unroll")                                             \
                for (int kk = 0; kk < 2; ++kk)                                \
                    acc[(mh) * 4 + ii][(nh) * 2 + jj] =                       \
                        __builtin_amdgcn_mfma_f32_16x16x32_f16(               \
                            af[ii][kk], bfr[jj][kk],                          \
                            acc[(mh) * 4 + ii][(nh) * 2 + jj], 0, 0, 0);      \
        __builtin_amdgcn_s_setprio(0);                                        \
    } while (0)

#define BAR __builtin_amdgcn_s_barrier()
#define VMW(n) asm volatile("s_waitcnt vmcnt(" #n ")" ::: "memory")

    STG(&lsA[0][0], Ab);
    STG(&lsA[0][128 * 64], Ab + (size_t)128 * DD);
    STG(&lsB[0][0], Bb);
    STG(&lsB[0][128 * 64], Bb + (size_t)128 * DD);
    STG(&lsA[1][0], Ab + 64);
    VMW(2);
    BAR;

    for (int i = 0; i < 7; ++i) {
        const int kt1 = (2 * i + 1) * 64, kt2 = kt1 + 64, kt3 = kt2 + 64;
        LDA(0, 0); LDB(0, 0, bf01);
        STG(&lsA[1][128 * 64], Ab + (size_t)128 * DD + kt1);
        BAR; MM(0, 0, bf01); BAR;
        LDB(0, 1, bf23);
        STG(&lsB[1][0], Bb + kt1);
        BAR; MM(0, 1, bf23); BAR;
        LDA(0, 1);
        STG(&lsB[1][128 * 64], Bb + (size_t)128 * DD + kt1);
        BAR; MM(1, 0, bf01); BAR;
        STG(&lsA[0][0], Ab + kt2);
        BAR; MM(1, 1, bf23);
        VMW(2); BAR;
        LDA(1, 0); LDB(1, 0, bf01);
        STG(&lsA[0][128 * 64], Ab + (size_t)128 * DD + kt2);
        BAR; MM(0, 0, bf01); BAR;
        LDB(1, 1, bf23);
        STG(&lsB[0][0], Bb + kt2);
        BAR; MM(0, 1, bf23); BAR;
        LDA(1, 1);
        STG(&lsB[0][128 * 64], Bb + (size_t)128 * DD + kt2);
        BAR; MM(1, 0, bf01); BAR;
        STG(&lsA[1][0], Ab + kt3);
        BAR; MM(1, 1, bf23);
        VMW(2); BAR;
    }
    {
        const int kt1 = 15 * 64;
        LDA(0, 0); LDB(0, 0, bf01);
        STG(&lsA[1][128 * 64], Ab + (size_t)128 * DD + kt1);
        BAR; MM(0, 0, bf01); BAR;
        LDB(0, 1, bf23);
        STG(&lsB[1][0], Bb + kt1);
        BAR; MM(0, 1, bf23); BAR;
        LDA(0, 1);
        STG(&lsB[1][128 * 64], Bb + (size_t)128 * DD + kt1);
        BAR; MM(1, 0, bf01); BAR;
        BAR; MM(1, 1, bf23);
        VMW(0); BAR;
        LDA(1, 0); LDB(1, 0, bf01);
        BAR; MM(0, 0, bf01); BAR;
        LDB(1, 1, bf23);
        BAR; MM(0, 1, bf23); BAR;
        LDA(1, 1);
        BAR; MM(1, 0, bf01); BAR;
        BAR; MM(1, 1, bf23);
    }
    __syncthreads();

    _Float16* Cb = P + (size_t)z * sP;
    float* psum = (float*)&lsA[0][0];           // [256][4]
    #pragma unroll
    for (int i = 0; i < 8; ++i) {
        float rsum[4] = {0.f, 0.f, 0.f, 0.f};
        #pragma unroll
        for (int j = 0; j < 4; ++j) {
            const int n = n0 + wc * 64 + j * 16 + lc;
            #pragma unroll
            for (int r = 0; r < 4; ++r) {
                const int m = m0 + wr * 128 + i * 16 + lr + r;
                const float e = __expf(acc[i][j][r] * scale);
                Cb[(size_t)m * LKK + n] = (_Float16)e;
                rsum[r] += e;
            }
        }
        #pragma unroll
        for (int r = 0; r < 4; ++r) {
            float s = rsum[r];
            s += __shfl_xor(s, 1);
            s += __shfl_xor(s, 2);
            s += __shfl_xor(s, 4);
            s += __shfl_xor(s, 8);
            if (lc == 0) psum[(wr * 128 + i * 16 + lr + r) * 4 + wc] = s;
        }
    }
    __syncthreads();
    if (tid < 256) {
        const float* pr = psum + tid * 4;
        partial[((size_t)z * LQ + m0 + tid) * 8 + bx] = pr[0] + pr[1] + pr[2] + pr[3];
    }
#undef STG
#undef LDA
#undef LDB
#undef MM
}

// ===========================================================================
// 256x128 NT-GEMM for PV / cat (BK=64, 512 thr = 8 waves 2Mx4N, 3-buffer
// rolling schedule staging 2 K-tiles ahead, counted vmcnt(6), 144KB LDS).
// A split lo/hi at ksplit (cat). mode 1: out16 = acc * inv(row) folded from
// 8-wide partials. mode 2: t = tanh(acc + bias[n]) -> out16 and/or out32.
// ===========================================================================
__global__ __launch_bounds__(512, 2) void gemm_pc_256x128(
    const _Float16* __restrict__ Alo, long sAlo, int lda_lo,
    const _Float16* __restrict__ Ahi, long sAhi, int lda_hi,
    int ksplit,
    const _Float16* __restrict__ B, long sB, int ldb,
    int K, int mode,
    float* __restrict__ out32, long s32, int ldc32,
    _Float16* __restrict__ out16, long s16, int ldc16,
    const float* __restrict__ bias,
    const float* __restrict__ partial, int npart)
{
    __shared__ _Float16 ls[3][384 * 64];   // per buf: A 256x64 @0, B 128x64 @256*64
    const int tid = threadIdx.x;
    const int w = tid >> 6, l = tid & 63;
    const int wr = w >> 2, wc = w & 3;     // wave grid 2M x 4N (128 rows x 32 cols)
    const int lrg = l >> 4, lc = l & 15, lr = lrg << 2;

    int id = blockIdx.x + gridDim.x * (blockIdx.y + gridDim.y * blockIdx.z);
    const int nwg = gridDim.x * gridDim.y * gridDim.z;
    id = (id & 7) * (nwg >> 3) + (id >> 3);
    const int bx = id % gridDim.x;         // 0..7  (N blocks)
    const int t2_ = id / gridDim.x;
    const int by = t2_ % gridDim.y;        // 0..1  (M blocks)
    const int z  = t2_ / gridDim.y;
    const int m0 = by * 256, n0 = bx * 128;

    const _Float16* Abase_lo = Alo + (size_t)z * sAlo + (size_t)m0 * lda_lo;
    const _Float16* Abase_hi = Ahi ? (Ahi + (size_t)z * sAhi + (size_t)m0 * lda_hi) : (const _Float16*)0;
    const _Float16* Bbase = B + (size_t)z * sB + (size_t)n0 * ldb;

    const int srow = l >> 3;
    const int sk = ((l & 7) ^ srow) << 3;
    const int rsb = (lc & 7) << 4;

    half8 af[4][2], bf[2][2];
    f32x4 acc[8][2] = {};

    // stage full 256-row A tile of K-tile tt (4 gl_lds16/thread)
#define STGA(tt, dbuf)                                                        \
    do {                                                                      \
        const int kb_ = (tt) * 64;                                            \
        const _Float16* s_; int ld_;                                          \
        if (kb_ < ksplit) { s_ = Abase_lo + kb_;           ld_ = lda_lo; }    \
        else              { s_ = Abase_hi + (kb_ - ksplit); ld_ = lda_hi; }   \
        _Float16* d_ = &ls[dbuf][0];                                          \
        _Pragma("unroll")                                                     \
        for (int rr = 0; rr < 4; ++rr) {                                      \
            const int c = w + 8 * rr;                                         \
            gl_lds16(s_ + (size_t)(c * 8 + srow) * ld_ + sk, d_ + c * 512);   \
        }                                                                     \
    } while (0)

    // stage 128-row B tile of K-tile tt (2 gl_lds16/thread)
#define STGB(tt, dbuf)                                                        \
    do {                                                                      \
        const _Float16* s_ = Bbase + (tt) * 64;                               \
        _Float16* d_ = &ls[dbuf][256 * 64];                                   \
        _Pragma("unroll")                                                     \
        for (int rr = 0; rr < 2; ++rr) {                                      \
            const int c = w + 8 * rr;                                         \
            gl_lds16(s_ + (size_t)(c * 8 + srow) * ldb + sk, d_ + c * 512);   \
        }                                                                     \
    } while (0)

#define LDA2(buf, mh)                                                         \
    do {                                                                      \
        const char* p_ = (const char*)&ls[buf][0];                            \
        _Pragma("unroll")                                                     \
        for (int ii = 0; ii < 4; ++ii) {                                      \
            const int row_ = wr * 128 + (mh) * 64 + ii * 16 + lc;             \
            _Pragma("unroll")                                                 \
            for (int kk = 0; kk < 2; ++kk)                                    \
                af[ii][kk] = *(const half8*)(p_ + row_ * 128 +                \
                             ((kk * 64 + (lrg << 4)) ^ rsb));                 \
        }                                                                     \
    } while (0)

#define LDB2(buf)                                                             \
    do {                                                                      \
        const char* p_ = (const char*)&ls[buf][256 * 64];                     \
        _Pragma("unroll")                                                     \
        for (int jj = 0; jj < 2; ++jj) {                                      \
            const int row_ = wc * 32 + jj * 16 + lc;                          \
            _Pragma("unroll")                                                 \
            for (int kk = 0; kk < 2; ++kk)                                    \
                bf[jj][kk] = *(const half8*)(p_ + row_ * 128 +                \
                              ((kk * 64 + (lrg << 4)) ^ rsb));                \
        }                                                                     \
    } while (0)

#define MM2(mh)                                                               \
    do {                                                                      \
        __builtin_amdgcn_s_setprio(1);                                        \
        _Pragma("unroll")                                                     \
        for (int ii = 0; ii < 4; ++ii)                                        \
            _Pragma("unroll")                                                 \
            for (int jj = 0; jj < 2; ++jj)                                    \
                _Pragma("unroll")                                             \
                for (int kk = 0; kk < 2; ++kk)                                \
                    acc[(mh) * 4 + ii][jj] =                                  \
                        __builtin_amdgcn_mfma_f32_16x16x32_f16(               \
                            af[ii][kk], bf[jj][kk],                           \
                            acc[(mh) * 4 + ii][jj], 0, 0, 0);                 \
        __builtin_amdgcn_s_setprio(0);                                        \
    } while (0)

    const int NT = K >> 6;                 // 32 K-tiles
    // prologue: stage tiles 0,1 (buffers 0,1); 12 vmem instr in flight
    STGA(0, 0); STGB(0, 0);
    STGA(1, 1); STGB(1, 1);
    VMW(6);                                // tile0 complete (tile1 in flight)
    BAR;

    int b = 0, b2 = 2;
    for (int t = 0; t < NT; ++t) {
        const int tt = t + 2;
        const bool st = tt < NT;
        // P0
        LDA2(b, 0); LDB2(b);
        if (st) STGA(tt, b2);
        BAR; MM2(0); BAR;
        // P1
        LDA2(b, 1);
        if (st) STGB(tt, b2);
        BAR; MM2(1);
        if (t < NT - 2)       VMW(6);      // tile t+1's 6 stages complete
        else if (t == NT - 2) VMW(0);      // drain last tile's stages
        BAR;
        b = (b == 2) ? 0 : b + 1;
        b2 = (b2 == 2) ? 0 : b2 + 1;
    }
    __syncthreads();

    // epilogue
    if (mode == 1) {
        float* psum = (float*)&ls[0][0];   // [256] 1/rowsum
        if (tid < 256) {
            const float* pp = partial + ((size_t)z * LQ + m0 + tid) * npart;
            float s = 0.0f;
            for (int c = 0; c < npart; ++c) s += pp[c];
            psum[tid] = 1.0f / s;
        }
        __syncthreads();
        _Float16* Cb = out16 + (size_t)z * s16;
        #pragma unroll
        for (int i = 0; i < 8; ++i)
            #pragma unroll
            for (int j = 0; j < 2; ++j) {
                const int n = n0 + wc * 32 + j * 16 + lc;
                #pragma unroll
                for (int r = 0; r < 4; ++r) {
                    const int ml = wr * 128 + i * 16 + lr + r;
                    Cb[(size_t)(m0 + ml) * ldc16 + n] =
                        (_Float16)(acc[i][j][r] * psum[ml]);
                }
            }
    } else {
        float bv[2];
        #pragma unroll
        for (int j = 0; j < 2; ++j)
            bv[j] = bias[n0 + wc * 32 + j * 16 + lc];
        #pragma unroll
        for (int i = 0; i < 8; ++i)
            #pragma unroll
            for (int j = 0; j < 2; ++j) {
                const int n = n0 + wc * 32 + j * 16 + lc;
                #pragma unroll
                for (int r = 0; r < 4; ++r) {
                    const int m = m0 + wr * 128 + i * 16 + lr + r;
                    const float t = tanhf(acc[i][j][r] + bv[j]);
                    if (out16) out16[(size_t)z * s16 + (size_t)m * ldc16 + n] = (_Float16)t;
                    if (out32) out32[(size_t)z * s32 + (size_t)m * ldc32 + n] = t;
                }
            }
    }
#undef STGA
#undef STGB
#undef LDA2
#undef LDB2
#undef MM2
#undef BAR
#undef VMW
}

// ---------------------------------------------------------------------------
// f16 MFMA NT-GEMM 128x128 (R3-fallback path only)
// ---------------------------------------------------------------------------
__global__ __launch_bounds__(256) void gemm_f16_nt(
    const _Float16* __restrict__ Alo, long sAlo, int lda_lo,
    const _Float16* __restrict__ Ahi, long sAhi, int lda_hi,
    int ksplit,
    const _Float16* __restrict__ B, long sB, int ldb,
    int K, int mode, float scale,
    float* __restrict__ out32, long s32, int ldc32,
    _Float16* __restrict__ out16, long s16, int ldc16,
    const float* __restrict__ bias,
    float* __restrict__ partial, const float* __restrict__ inv, int npart)
{
    __shared__ _Float16 lsA[128 * 64];
    __shared__ _Float16 lsB[128 * 64];
    __shared__ float psum[128][2];
    const int tid = threadIdx.x;
    const int w = tid >> 6, l = tid & 63;
    const int wr = w >> 1, wc = w & 1;

    int id = blockIdx.x + gridDim.x * (blockIdx.y + gridDim.y * blockIdx.z);
    const int nwg = gridDim.x * gridDim.y * gridDim.z;
    id = (id & 7) * (nwg >> 3) + (id >> 3);
    const int bx = id % gridDim.x;
    const int t2 = id / gridDim.x;
    const int by = t2 % gridDim.y;
    const int z = t2 / gridDim.y;
    const int m0 = by * 128, n0 = bx * 128;

    const _Float16* Abase_lo = Alo + (size_t)z * sAlo + (size_t)m0 * lda_lo;
    const _Float16* Abase_hi = Ahi ? (Ahi + (size_t)z * sAhi + (size_t)m0 * lda_hi) : (const _Float16*)0;
    const _Float16* Bbase = B + (size_t)z * sB + (size_t)n0 * ldb;

    const int srow = l >> 3;
    const int sswz = ((l & 7) ^ srow) << 3;

    f32x4 acc[4][4] = {};

    for (int k0 = 0; k0 < K; k0 += 64) {
        const _Float16* Ap; int kloc, ldaA;
        if (k0 < ksplit) { Ap = Abase_lo; kloc = k0;          ldaA = lda_lo; }
        else             { Ap = Abase_hi; kloc = k0 - ksplit; ldaA = lda_hi; }
        #pragma unroll
        for (int i = 0; i < 4; ++i) {
            const int c = w * 4 + i;
            const int row = c * 8 + srow;
            gl_lds16(Ap + (size_t)row * ldaA + kloc + sswz, &lsA[c * 512]);
        }
        #pragma unroll
        for (int i = 0; i < 4; ++i) {
            const int c = w * 4 + i;
            const int row = c * 8 + srow;
            gl_lds16(Bbase + (size_t)row * ldb + k0 + sswz, &lsB[c * 512]);
        }
        __syncthreads();

        half8 af[4][2], bf[4][2];
        const char* lA = (const char*)lsA;
        const char* lB = (const char*)lsB;
        const int rs = (l & 7) << 4;
        const int cb = (l >> 4) << 4;
        #pragma unroll
        for (int i = 0; i < 4; ++i) {
            const int rowa = wr * 64 + i * 16 + (l & 15);
            const int rowb = wc * 64 + i * 16 + (l & 15);
            #pragma unroll
            for (int kk = 0; kk < 2; ++kk) {
                af[i][kk] = *(const half8*)(lA + rowa * 128 + ((kk * 64 + cb) ^ rs));
                bf[i][kk] = *(const half8*)(lB + rowb * 128 + ((kk * 64 + cb) ^ rs));
            }
        }
        #pragma unroll
        for (int kk = 0; kk < 2; ++kk)
            #pragma unroll
            for (int i = 0; i < 4; ++i)
                #pragma unroll
                for (int j = 0; j < 4; ++j)
                    acc[i][j] = __builtin_amdgcn_mfma_f32_16x16x32_f16(
                        af[i][kk], bf[j][kk], acc[i][j], 0, 0, 0);
        __syncthreads();
    }

    const int lr = (l >> 4) * 4;
    const int lc = l & 15;
    if (mode == 0) {
        _Float16* Cb = out16 + (size_t)z * s16;
        float rsum[4][4];
        #pragma unroll
        for (int i = 0; i < 4; ++i)
            #pragma unroll
            for (int r = 0; r < 4; ++r) rsum[i][r] = 0.0f;
        #pragma unroll
        for (int i = 0; i < 4; ++i)
            #pragma unroll
            for (int j = 0; j < 4; ++j) {
                const int n = n0 + wc * 64 + j * 16 + lc;
                #pragma unroll
                for (int r = 0; r < 4; ++r) {
                    const int m = m0 + wr * 64 + i * 16 + lr + r;
                    const float e = __expf(acc[i][j][r] * scale);
                    Cb[(size_t)m * ldc16 + n] = (_Float16)e;
                    rsum[i][r] += e;
                }
            }
        #pragma unroll
        for (int i = 0; i < 4; ++i)
            #pragma unroll
            for (int r = 0; r < 4; ++r) {
                float s = rsum[i][r];
                s += __shfl_xor(s, 1);
                s += __shfl_xor(s, 2);
                s += __shfl_xor(s, 4);
                s += __shfl_xor(s, 8);
                rsum[i][r] = s;
            }
        if (lc == 0) {
            #pragma unroll
            for (int i = 0; i < 4; ++i)
                #pragma unroll
                for (int r = 0; r < 4; ++r)
                    psum[wr * 64 + i * 16 + lr + r][wc] = rsum[i][r];
        }
        __syncthreads();
        if (tid < 128)
            partial[((size_t)z * LQ + m0 + tid) * npart + bx] = psum[tid][0] + psum[tid][1];
    } else if (mode == 1) {
        _Float16* Cb = out16 + (size_t)z * s16;
        float iv[4][4];
        if (partial) {
            if (tid < 128) {
                const float* pp = partial + ((size_t)z * LQ + m0 + tid) * npart;
                float s = 0.0f;
                for (int c = 0; c < npart; ++c) s += pp[c];
                psum[tid][0] = 1.0f / s;
            }
            __syncthreads();
            #pragma unroll
            for (int i = 0; i < 4; ++i)
                #pragma unroll
                for (int r = 0; r < 4; ++r)
                    iv[i][r] = psum[wr * 64 + i * 16 + lr + r][0];
        } else {
            #pragma unroll
            for (int i = 0; i < 4; ++i)
                #pragma unroll
                for (int r = 0; r < 4; ++r)
                    iv[i][r] = inv ? inv[(size_t)z * LQ + m0 + wr * 64 + i * 16 + lr + r] : 1.0f;
        }
        #pragma unroll
        for (int i = 0; i < 4; ++i)
            #pragma unroll
            for (int j = 0; j < 4; ++j) {
                const int n = n0 + wc * 64 + j * 16 + lc;
                #pragma unroll
                for (int r = 0; r < 4; ++r) {
                    const int m = m0 + wr * 64 + i * 16 + lr + r;
                    Cb[(size_t)m * ldc16 + n] = (_Float16)(acc[i][j][r] * iv[i][r]);
                }
            }
    } else if (mode == 4) {
        float* Cb = out32 + (size_t)z * s32;
        #pragma unroll
        for (int i = 0; i < 4; ++i)
            #pragma unroll
            for (int j = 0; j < 4; ++j) {
                const int n = n0 + wc * 64 + j * 16 + lc;
                #pragma unroll
                for (int r = 0; r < 4; ++r) {
                    const int m = m0 + wr * 64 + i * 16 + lr + r;
                    Cb[(size_t)m * ldc32 + n] = acc[i][j][r] * scale;
                }
            }
    } else {
        float bv[4];
        #pragma unroll
        for (int j = 0; j < 4; ++j)
            bv[j] = bias[n0 + wc * 64 + j * 16 + lc];
        #pragma unroll
        for (int i = 0; i < 4; ++i)
            #pragma unroll
            for (int j = 0; j < 4; ++j) {
                const int n = n0 + wc * 64 + j * 16 + lc;
                #pragma unroll
                for (int r = 0; r < 4; ++r) {
                    const int m = m0 + wr * 64 + i * 16 + lr + r;
                    const float t = tanhf(acc[i][j][r] + bv[j]);
                    if (out16) out16[(size_t)z * s16 + (size_t)m * ldc16 + n] = (_Float16)t;
                    if (out32) out32[(size_t)z * s32 + (size_t)m * ldc32 + n] = t;
                }
            }
    }
}

// one block per row: attn_f32[row,:] = P16[row,:] * (1/sum partial[row,0..npart))
__global__ __launch_bounds__(256) void scale_attn(
    const _Float16* __restrict__ P, const float* __restrict__ partial,
    float* __restrict__ attn, int npart)
{
    __shared__ float sinv;
    const long row = blockIdx.x;
    const int tid = threadIdx.x;
    if (tid < npart) {
        float s = partial[row * npart + tid];
        for (int off = npart >> 1; off > 0; off >>= 1) s += __shfl_xor(s, off);
        if (tid == 0) sinv = 1.0f / s;
    }
    __syncthreads();
    const float inv = sinv;
    const half8 h = *(const half8*)(P + row * 2048 + tid * 8);
    float* o = attn + row * 2048 + tid * 8;
    float4 a = make_float4((float)h[0] * inv, (float)h[1] * inv,
                           (float)h[2] * inv, (float)h[3] * inv);
    float4 b = make_float4((float)h[4] * inv, (float)h[5] * inv,
                           (float)h[6] * inv, (float)h[7] * inv);
    *(float4*)o = a;
    *(float4*)(o + 4) = b;
}

// inv[row] = 1 / sum_{cb<16} partial[row*16+cb]   (R3-fallback path)
__global__ __launch_bounds__(256) void make_inv(
    const float* __restrict__ partial, float* __restrict__ inv)
{
    const int row = blockIdx.x * 256 + threadIdx.x;
    const float4 a = *(const float4*)(partial + (size_t)row * 16);
    const float4 b = *(const float4*)(partial + (size_t)row * 16 + 4);
    const float4 c = *(const float4*)(partial + (size_t)row * 16 + 8);
    const float4 d = *(const float4*)(partial + (size_t)row * 16 + 12);
    const float s = (a.x + a.y + a.z + a.w) + (b.x + b.y + b.z + b.w)
                  + (c.x + c.y + c.z + c.w) + (d.x + d.y + d.z + d.w);
    inv[row] = 1.0f / s;
}

// row softmax over 2048 f32 (R3-fallback hop 2)
__global__ __launch_bounds__(256) void softmax_rows2(
    float* __restrict__ S, _Float16* __restrict__ f16out,
    long f16stride, int write_f32)
{
    __shared__ float red[8];
    const long row = blockIdx.x;
    float* p = S + row * LKK;
    const int tid = threadIdx.x;
    float4 v0 = ((const float4*)p)[tid];
    float4 v1 = ((const float4*)p)[tid + 256];
    float m = fmaxf(fmaxf(fmaxf(v0.x, v0.y), fmaxf(v0.z, v0.w)),
                    fmaxf(fmaxf(v1.x, v1.y), fmaxf(v1.z, v1.w)));
    #pragma unroll
    for (int off = 32; off > 0; off >>= 1) m = fmaxf(m, __shfl_down(m, off));
    if ((tid & 63) == 0) red[tid >> 6] = m;
    __syncthreads();
    m = fmaxf(fmaxf(red[0], red[1]), fmaxf(red[2], red[3]));
    v0.x = expf(v0.x - m); v0.y = expf(v0.y - m);
    v0.z = expf(v0.z - m); v0.w = expf(v0.w - m);
    v1.x = expf(v1.x - m); v1.y = expf(v1.y - m);
    v1.z = expf(v1.z - m); v1.w = expf(v1.w - m);
    float s = v0.x + v0.y + v0.z + v0.w + v1.x + v1.y + v1.z + v1.w;
    #pragma unroll
    for (int off = 32; off > 0; off >>= 1) s += __shfl_down(s, off);
    if ((tid & 63) == 0) red[4 + (tid >> 6)] = s;
    __syncthreads();
    s = red[4] + red[5] + red[6] + red[7];
    const float inv = 1.0f / s;
    v0.x *= inv; v0.y *= inv; v0.z *= inv; v0.w *= inv;
    v1.x *= inv; v1.y *= inv; v1.z *= inv; v1.w *= inv;
    if (write_f32) {
        ((float4*)p)[tid] = v0;
        ((float4*)p)[tid + 256] = v1;
    }
    _Float16* q = f16out + row * f16stride;
    half4 h0 = { (_Float16)v0.x, (_Float16)v0.y, (_Float16)v0.z, (_Float16)v0.w };
    half4 h1 = { (_Float16)v1.x, (_Float16)v1.y, (_Float16)v1.z, (_Float16)v1.w };
    *(half4*)(q + tid * 4) = h0;
    *(half4*)(q + 1024 + tid * 4) = h1;
}

__global__ __launch_bounds__(256) void cvt_f32_to_f16(
    const float* __restrict__ in, _Float16* __restrict__ out, long n)
{
    const long i = ((long)blockIdx.x * 256 + threadIdx.x) * 8;
    if (i + 8 > n) return;
    float4 a = *(const float4*)(in + i);
    float4 b = *(const float4*)(in + i + 4);
    half8 h = { (_Float16)a.x, (_Float16)a.y, (_Float16)a.z, (_Float16)a.w,
                (_Float16)b.x, (_Float16)b.y, (_Float16)b.z, (_Float16)b.w };
    *(half8*)(out + i) = h;
}

// V [B, Lk, D] f32 -> Vt [B, D, Lk] f16, 64x64 tiles via LDS
__global__ __launch_bounds__(256) void transpose_cvt_v(
    const float* __restrict__ V, _Float16* __restrict__ Vt)
{
    __shared__ _Float16 t[64][80];
    const int z = blockIdx.z;
    const int k0 = blockIdx.y * 64, d0 = blockIdx.x * 64;
    const float* Vb = V + (size_t)z * LKK * DD;
    _Float16* Vtb = Vt + (size_t)z * DD * LKK;
    const int r = threadIdx.x >> 2;
    const int c0 = (threadIdx.x & 3) * 16;
    #pragma unroll
    for (int j = 0; j < 4; ++j) {
        float4 v = *(const float4*)(Vb + (size_t)(k0 + r) * DD + d0 + c0 + j * 4);
        t[c0 + j * 4 + 0][r] = (_Float16)v.x;
        t[c0 + j * 4 + 1][r] = (_Float16)v.y;
        t[c0 + j * 4 + 2][r] = (_Float16)v.z;
        t[c0 + j * 4 + 3][r] = (_Float16)v.w;
    }
    __syncthreads();
    #pragma unroll
    for (int j = 0; j < 2; ++j) {
        half8 h = *(const half8*)&t[r][c0 + j * 8];
        *(half8*)(Vtb + (size_t)(d0 + r) * LKK + k0 + c0 + j * 8) = h;
    }
}

// ======================= round-1 f32 fallback kernels =======================
constexpr int TM = 64, TN = 64, TK = 32;
constexpr int PAD = 4;

__global__ __launch_bounds__(256) void gemm_nt_k(
    const float* __restrict__ A, int lda, long sA,
    const float* __restrict__ Bt, int ldb, long sB,
    float* __restrict__ C, int ldc, long sC, int K, float scale)
{
    __shared__ float As[TK][TM + PAD];
    __shared__ float Bs[TK][TN + PAD];
    const float* Ab = A + (long)blockIdx.z * sA;
    const float* Bb = Bt + (long)blockIdx.z * sB;
    float* Cb = C + (long)blockIdx.z * sC;
    const int m0 = blockIdx.y * TM, n0 = blockIdx.x * TN;
    const int tid = threadIdx.x;
    const int tn = tid & 15, tm = tid >> 4;
    float acc[4][4] = {};
    for (int k0 = 0; k0 < K; k0 += TK) {
        #pragma unroll
        for (int c = tid; c < (TM * TK) / 4; c += 256) {
            const int row = c >> 3, kc = (c & 7) << 2;
            const float4 g = *(const float4*)(Ab + (long)(m0 + row) * lda + (k0 + kc));
            As[kc + 0][row] = g.x; As[kc + 1][row] = g.y;
            As[kc + 2][row] = g.z; As[kc + 3][row] = g.w;
        }
        #pragma unroll
        for (int c = tid; c < (TN * TK) / 4; c += 256) {
            const int row = c >> 3, kc = (c & 7) << 2;
            const float4 g = *(const float4*)(Bb + (long)(n0 + row) * ldb + (k0 + kc));
            Bs[kc + 0][row] = g.x; Bs[kc + 1][row] = g.y;
            Bs[kc + 2][row] = g.z; Bs[kc + 3][row] = g.w;
        }
        __syncthreads();
        #pragma unroll
        for (int kk = 0; kk < TK; ++kk) {
            const float4 av = *(const float4*)&As[kk][tm << 2];
            const float4 bv = *(const float4*)&Bs[kk][tn << 2];
            const float a[4] = {av.x, av.y, av.z, av.w};
            const float b[4] = {bv.x, bv.y, bv.z, bv.w};
            #pragma unroll
            for (int i = 0; i < 4; ++i)
                #pragma unroll
                for (int j = 0; j < 4; ++j)
                    acc[i][j] = fmaf(a[i], b[j], acc[i][j]);
        }
        __syncthreads();
    }
    #pragma unroll
    for (int i = 0; i < 4; ++i) {
        float4 o = make_float4(acc[i][0] * scale, acc[i][1] * scale,
                               acc[i][2] * scale, acc[i][3] * scale);
        *(float4*)(Cb + (long)(m0 + (tm << 2) + i) * ldc + n0 + (tn << 2)) = o;
    }
}

__global__ __launch_bounds__(256) void gemm_nn_k(
    const float* __restrict__ A, int lda, long sA,
    const float* __restrict__ B, int ldb, long sB,
    float* __restrict__ C, int ldc, long sC, int K)
{
    __shared__ float As[TK][TM + PAD];
    __shared__ float Bs[TK][TN + PAD];
    const float* Ab = A + (long)blockIdx.z * sA;
    const float* Bb = B + (long)blockIdx.z * sB;
    float* Cb = C + (long)blockIdx.z * sC;
    const int m0 = blockIdx.y * TM, n0 = blockIdx.x * TN;
    const int tid = threadIdx.x;
    const int tn = tid & 15, tm = tid >> 4;
    float acc[4][4] = {};
    for (int k0 = 0; k0 < K; k0 += TK) {
        #pragma unroll
        for (int c = tid; c < (TM * TK) / 4; c += 256) {
            const int row = c >> 3, kc = (c & 7) << 2;
            const float4 g = *(const float4*)(Ab + (long)(m0 + row) * lda + (k0 + kc));
            As[kc + 0][row] = g.x; As[kc + 1][row] = g.y;
            As[kc + 2][row] = g.z; As[kc + 3][row] = g.w;
        }
        #pragma unroll
        for (int c = tid; c < (TK * TN) / 4; c += 256) {
            const int krow = c >> 4, nc = (c & 15) << 2;
            *(float4*)&Bs[krow][nc] =
                *(const float4*)(Bb + (long)(k0 + krow) * ldb + n0 + nc);
        }
        __syncthreads();
        #pragma unroll
        for (int kk = 0; kk < TK; ++kk) {
            const float4 av = *(const float4*)&As[kk][tm << 2];
            const float4 bv = *(const float4*)&Bs[kk][tn << 2];
            const float a[4] = {av.x, av.y, av.z, av.w};
            const float b[4] = {bv.x, bv.y, bv.z, bv.w};
            #pragma unroll
            for (int i = 0; i < 4; ++i)
                #pragma unroll
                for (int j = 0; j < 4; ++j)
                    acc[i][j] = fmaf(a[i], b[j], acc[i][j]);
        }
        __syncthreads();
    }
    #pragma unroll
    for (int i = 0; i < 4; ++i) {
        float4 o = make_float4(acc[i][0], acc[i][1], acc[i][2], acc[i][3]);
        *(float4*)(Cb + (long)(m0 + (tm << 2) + i) * ldc + n0 + (tn << 2)) = o;
    }
}

__global__ __launch_bounds__(256) void gemm_cat_k(
    const float* __restrict__ Qh, const float* __restrict__ R,
    const float* __restrict__ W, const float* __restrict__ bias,
    float* __restrict__ C)
{
    __shared__ float As[TK][TM + PAD];
    __shared__ float Bs[TK][TN + PAD];
    const float* Qb = Qh + (long)blockIdx.z * LQ * DD;
    const float* Rb = R + (long)blockIdx.z * LQ * DD;
    float* Cb = C + (long)blockIdx.z * LQ * DD;
    const int m0 = blockIdx.y * TM, n0 = blockIdx.x * TN;
    const int tid = threadIdx.x;
    const int tn = tid & 15, tm = tid >> 4;
    float acc[4][4] = {};
    for (int k0 = 0; k0 < 2 * DD; k0 += TK) {
        const float* src = (k0 < DD) ? Qb : Rb;
        const int kb = (k0 < DD) ? k0 : k0 - DD;
        #pragma unroll
        for (int c = tid; c < (TM * TK) / 4; c += 256) {
            const int row = c >> 3, kc = (c & 7) << 2;
            const float4 g = *(const float4*)(src + (long)(m0 + row) * DD + (kb + kc));
            As[kc + 0][row] = g.x; As[kc + 1][row] = g.y;
            As[kc + 2][row] = g.z; As[kc + 3][row] = g.w;
        }
        #pragma unroll
        for (int c = tid; c < (TN * TK) / 4; c += 256) {
            const int row = c >> 3, kc = (c & 7) << 2;
            const float4 g = *(const float4*)(W + (long)(n0 + row) * (2 * DD) + (k0 + kc));
            Bs[kc + 0][row] = g.x; Bs[kc + 1][row] = g.y;
            Bs[kc + 2][row] = g.z; Bs[kc + 3][row] = g.w;
        }
        __syncthreads();
        #pragma unroll
        for (int kk = 0; kk < TK; ++kk) {
            const float4 av = *(const float4*)&As[kk][tm << 2];
            const float4 bv = *(const float4*)&Bs[kk][tn << 2];
            const float a[4] = {av.x, av.y, av.z, av.w};
            const float b[4] = {bv.x, bv.y, bv.z, bv.w};
            #pragma unroll
            for (int i = 0; i < 4; ++i)
                #pragma unroll
                for (int j = 0; j < 4; ++j)
                    acc[i][j] = fmaf(a[i], b[j], acc[i][j]);
        }
        __syncthreads();
    }
    #pragma unroll
    for (int i = 0; i < 4; ++i) {
        float4 o;
        o.x = tanhf(acc[i][0] + bias[n0 + (tn << 2) + 0]);
        o.y = tanhf(acc[i][1] + bias[n0 + (tn << 2) + 1]);
        o.z = tanhf(acc[i][2] + bias[n0 + (tn << 2) + 2]);
        o.w = tanhf(acc[i][3] + bias[n0 + (tn << 2) + 3]);
        *(float4*)(Cb + (long)(m0 + (tm << 2) + i) * DD + n0 + (tn << 2)) = o;
    }
}

__global__ __launch_bounds__(256) void softmax_rows(float* __restrict__ S) {
    __shared__ float red[8];
    float* p = S + (size_t)blockIdx.x * LKK;
    const int tid = threadIdx.x;
    float4 v0 = ((const float4*)p)[tid];
    float4 v1 = ((const float4*)p)[tid + 256];
    float m = fmaxf(fmaxf(fmaxf(v0.x, v0.y), fmaxf(v0.z, v0.w)),
                    fmaxf(fmaxf(v1.x, v1.y), fmaxf(v1.z, v1.w)));
    #pragma unroll
    for (int off = 32; off > 0; off >>= 1) m = fmaxf(m, __shfl_down(m, off));
    if ((tid & 63) == 0) red[tid >> 6] = m;
    __syncthreads();
    m = fmaxf(fmaxf(red[0], red[1]), fmaxf(red[2], red[3]));
    v0.x = expf(v0.x - m); v0.y = expf(v0.y - m);
    v0.z = expf(v0.z - m); v0.w = expf(v0.w - m);
    v1.x = expf(v1.x - m); v1.y = expf(v1.y - m);
    v1.z = expf(v1.z - m); v1.w = expf(v1.w - m);
    float s = v0.x + v0.y + v0.z + v0.w + v1.x + v1.y + v1.z + v1.w;
    #pragma unroll
    for (int off = 32; off > 0; off >>= 1) s += __shfl_down(s, off);
    if ((tid & 63) == 0) red[4 + (tid >> 6)] = s;
    __syncthreads();
    s = red[4] + red[5] + red[6] + red[7];
    const float inv = 1.0f / s;
    v0.x *= inv; v0.y *= inv; v0.z *= inv; v0.w *= inv;
    v1.x *= inv; v1.y *= inv; v1.z *= inv; v1.w *= inv;
    ((float4*)p)[tid] = v0;
    ((float4*)p)[tid + 256] = v1;
}

// ===========================================================================
extern "C" void kernel_launch(void* const* d_in, const int* in_sizes, int n_in,
                              void* d_out, int out_size, void* d_ws, size_t ws_size,
                              hipStream_t stream) {
    const float* Q    = (const float*)d_in[0];
    const float* Km   = (const float*)d_in[1];
    const float* V    = (const float*)d_in[2];
    const float* W    = (const float*)d_in[3];
    const float* bias = (const float*)d_in[4];
    const float scale = 0.03125f;  // 1/sqrt(1024)
    dim3 blk(256);

    const size_t NEED_FULL = 189267968ULL;
    const size_t NEED_R3   = 155189248ULL;

    if (ws_size >= NEED_FULL) {
        char* ws = (char*)d_ws;
        _Float16* Kh     = (_Float16*)ws;                    // [16,2048,1024]
        _Float16* Vt     = (_Float16*)(ws + 67108864);       // [16,1024,2048]
        _Float16* Wh     = (_Float16*)(ws + 134217728);      // [1024,2048]
        _Float16* Rh     = (_Float16*)(ws + 138412032);      // [16,512,1024]
        _Float16* Qping  = (_Float16*)(ws + 155189248);      // [16,512,1024]
        _Float16* Qpong  = (_Float16*)(ws + 171966464);      // [16,512,1024]
        float*    partialB = (float*)(ws + 188743680);       // [8192,8]

        float*    outQ  = (float*)d_out;
        _Float16* P2    = (_Float16*)d_out;
        float*    attnF = (float*)((char*)d_out + 33554432);
        _Float16* P01   = (_Float16*)attnF;

        cvt_f32_to_f16<<<4096, blk, 0, stream>>>(Q, Qping, (long)NB * LQ * DD);
        cvt_f32_to_f16<<<16384, blk, 0, stream>>>(Km, Kh, (long)NB * LKK * DD);
        cvt_f32_to_f16<<<1024, blk, 0, stream>>>(W, Wh, (long)DD * 2 * DD);
        transpose_cvt_v<<<dim3(DD / 64, LKK / 64, NB), blk, 0, stream>>>(V, Vt);

        dim3 gS2(LKK / 256, LQ / 256, NB);  // 8 x 2 x 16 = 256 blocks
        dim3 gP(DD / 128, LQ / 256, NB);    // 8 x 2 x 16 = 256 blocks

        for (int h = 0; h < 3; ++h) {
            _Float16* qcur = (h == 1) ? Qpong : Qping;
            _Float16* P    = (h == 2) ? P2 : P01;

            // ---- fused 8-phase 256^2: P = exp(Qh K^T * scale), 8-wide partials
            gemm_qk_256<<<gS2, dim3(512), 0, stream>>>(
                qcur, (long)LQ * DD, Kh, (long)LKK * DD,
                P, (long)LQ * LKK, partialB, scale);
            if (h == 2)
                scale_attn<<<NB * LQ, blk, 0, stream>>>(P2, partialB, attnF, 8);
            // ---- R = (P V) * inv(row)  [256x128 3-buf pipeline]
            gemm_pc_256x128<<<gP, dim3(512), 0, stream>>>(
                P, (long)LQ * LKK, LKK,
                (const _Float16*)0, 0, 0, LKK * 16,   // ksplit > K: lo only
                Vt, (long)DD * LKK, LKK,
                LKK, 1,
                (float*)0, 0, 0,
                Rh, (long)LQ * DD, DD,
                (const float*)0, partialB, 8);
            // ---- Qnext = tanh([Qh|R] W^T + b)  [256x128 3-buf pipeline]
            _Float16* qn = (h == 0) ? Qpong : (h == 1) ? Qping : (_Float16*)0;
            float* fo = (h == 2) ? outQ : (float*)0;
            gemm_pc_256x128<<<gP, dim3(512), 0, stream>>>(
                qcur, (long)LQ * DD, DD,
                Rh, (long)LQ * DD, DD, DD,            // ksplit = 1024
                Wh, 0, 2 * DD,
                2 * DD, 2,
                fo, (long)LQ * DD, DD,
                qn, (long)LQ * DD, DD,
                bias, (const float*)0, 0);
        }
    } else if (ws_size >= NEED_R3) {
        // -------- proven R3 path --------
        char* ws = (char*)d_ws;
        _Float16* Kh  = (_Float16*)ws;
        _Float16* Vt  = (_Float16*)(ws + 67108864);
        _Float16* Wh  = (_Float16*)(ws + 134217728);
        _Float16* Rh  = (_Float16*)(ws + 138412032);
        _Float16* attn2 = (_Float16*)ws;
        float* Fout = (float*)(ws + 33554432);

        _Float16* Qping = (_Float16*)d_out;
        _Float16* Qpong = Qping + (size_t)NB * LQ * DD;
        float* S = (float*)((char*)d_out + 33554432);
        _Float16* P = (_Float16*)S;
        float* partialB = (float*)((char*)d_out + 73400320);
        float* invB     = (float*)((char*)d_out + 73924608);

        cvt_f32_to_f16<<<4096, blk, 0, stream>>>(Q, Qping, (long)NB * LQ * DD);
        cvt_f32_to_f16<<<16384, blk, 0, stream>>>(Km, Kh, (long)NB * LKK * DD);
        cvt_f32_to_f16<<<1024, blk, 0, stream>>>(W, Wh, (long)DD * 2 * DD);
        transpose_cvt_v<<<dim3(DD / 64, LKK / 64, NB), blk, 0, stream>>>(V, Vt);

        dim3 gS(LKK / 128, LQ / 128, NB);
        dim3 gR(DD / 128, LQ / 128, NB);

        for (int h = 0; h < 3; ++h) {
            _Float16* qcur = (h == 1) ? Qpong : Qping;
            if (h < 2) {
                gemm_f16_nt<<<gS, blk, 0, stream>>>(
                    qcur, (long)LQ * DD, DD, (const _Float16*)0, 0, 0, DD,
                    Kh, (long)LKK * DD, DD, DD,
                    0, scale, (float*)0, 0, 0,
                    P, (long)LQ * LKK, LKK, (const float*)0,
                    partialB, (const float*)0, 16);
                make_inv<<<32, blk, 0, stream>>>(partialB, invB);
                gemm_f16_nt<<<gR, blk, 0, stream>>>(
                    P, (long)LQ * LKK, LKK,
                    (const _Float16*)0, 0, 0, LKK,
                    Vt, (long)DD * LKK, LKK, LKK,
                    1, 1.0f, (float*)0, 0, 0,
                    Rh, (long)LQ * DD, DD, (const float*)0,
                    (float*)0, invB, 0);
            } else {
                gemm_f16_nt<<<gS, blk, 0, stream>>>(
                    qcur, (long)LQ * DD, DD, (const _Float16*)0, 0, 0, DD,
                    Kh, (long)LKK * DD, DD, DD,
                    4, scale, S, (long)LQ * LKK, LKK,
                    (_Float16*)0, 0, 0, (const float*)0,
                    (float*)0, (const float*)0, 0);
                softmax_rows2<<<NB * LQ, blk, 0, stream>>>(S, attn2, 2048L, 1);
                gemm_f16_nt<<<gR, blk, 0, stream>>>(
                    attn2, (long)LQ * LKK, LKK,
                    (const _Float16*)0, 0, 0, LKK,
                    Vt, (long)DD * LKK, LKK, LKK,
                    1, 1.0f, (float*)0, 0, 0,
                    Rh, (long)LQ * DD, DD, (const float*)0,
                    (float*)0, (const float*)0, 0);
            }
            _Float16* qn = (h == 0) ? Qpong : (h == 1) ? Qping : (_Float16*)0;
            float* fo = (h == 2) ? Fout : (float*)0;
            gemm_f16_nt<<<gR, blk, 0, stream>>>(
                qcur, (long)LQ * DD, DD,
                Rh, (long)LQ * DD, DD, DD,
                Wh, 0, 2 * DD, 2 * DD,
                2, 1.0f, fo, (long)LQ * DD, DD,
                qn, (long)LQ * DD, DD, bias,
                (float*)0, (const float*)0, 0);
        }
        hipMemcpyAsync(d_out, Fout, 33554432ULL, hipMemcpyDeviceToDevice, stream);
    } else {
        // -------- round-1 f32 fallback --------
        float* outQ = (float*)d_out;
        float* S    = outQ + (size_t)NB * LQ * DD;
        float* R    = (float*)d_ws;
        float* T    = R + (size_t)NB * LQ * DD;
        dim3 gS(LKK / TN, LQ / TM, NB);
        dim3 gR(DD / TN, LQ / TM, NB);
        for (int h = 0; h < 3; ++h) {
            const float* Qh = (h == 0) ? Q : (h == 1 ? (const float*)T : (const float*)outQ);
            float* cout = (h == 1) ? outQ : T;
            gemm_nt_k<<<gS, blk, 0, stream>>>(Qh, DD, (long)LQ * DD, Km, DD, (long)LKK * DD,
                                              S, LKK, (long)LQ * LKK, DD, scale);
            softmax_rows<<<NB * LQ, blk, 0, stream>>>(S);
            gemm_nn_k<<<gR, blk, 0, stream>>>(S, LKK, (long)LQ * LKK, V, DD, (long)LKK * DD,
                                              R, DD, (long)LQ * DD, LKK);
            gemm_cat_k<<<gR, blk, 0, stream>>>(Qh, R, W, bias, cout);
        }
        hipMemcpyAsync(outQ, T, (size_t)NB * LQ * DD * sizeof(float),
                       hipMemcpyDeviceToDevice, stream);
    }
}

// Round 7
// 494.573 us; speedup vs baseline: 8.9565x; 1.0113x over previous
//
#include <hip/hip_runtime.h>
#include <math.h>

#define NB 16
#define LQ 512
#define LKK 2048
#define DD 1024

typedef _Float16 half8 __attribute__((ext_vector_type(8)));
typedef _Float16 half4 __attribute__((ext_vector_type(4)));
typedef float f32x4 __attribute__((ext_vector_type(4)));

__device__ __forceinline__ void gl_lds16(const void* g, void* l) {
    __builtin_amdgcn_global_load_lds(
        (const __attribute__((address_space(1))) void*)g,
        (__attribute__((address_space(3))) void*)l, 16, 0, 0);
}

// ===========================================================================
// 8-phase 256x256 NT-GEMM for QK^T  [proven R5/R6 — unchanged]
// ===========================================================================
__global__ __launch_bounds__(512, 2) void gemm_qk_256(
    const _Float16* __restrict__ A, long sA,
    const _Float16* __restrict__ B, long sB,
    _Float16* __restrict__ P, long sP,
    float* __restrict__ partial,
    float scale)
{
    __shared__ _Float16 lsA[2][256 * 64];
    __shared__ _Float16 lsB[2][256 * 64];
    const int tid = threadIdx.x;
    const int w = tid >> 6, l = tid & 63;
    const int wr = w >> 2, wc = w & 3;
    const int lrg = l >> 4, lc = l & 15, lr = lrg << 2;

    int id = blockIdx.x + gridDim.x * (blockIdx.y + gridDim.y * blockIdx.z);
    const int nwg = gridDim.x * gridDim.y * gridDim.z;
    id = (id & 7) * (nwg >> 3) + (id >> 3);
    const int bx = id % gridDim.x;
    const int t2 = id / gridDim.x;
    const int by = t2 % gridDim.y;
    const int z  = t2 / gridDim.y;
    const int m0 = by * 256, n0 = bx * 256;

    const _Float16* Ab = A + (size_t)z * sA + (size_t)m0 * DD;
    const _Float16* Bb = B + (size_t)z * sB + (size_t)n0 * DD;

    const int srow = l >> 3;
    const int sk = ((l & 7) ^ srow) << 3;

#define STG(dst, srcbase)                                                     \
    do {                                                                      \
        _Pragma("unroll")                                                     \
        for (int rr = 0; rr < 2; ++rr) {                                      \
            const int c = w + 8 * rr;                                         \
            gl_lds16((srcbase) + (size_t)(c * 8 + srow) * DD + sk,            \
                     (dst) + c * 512);                                        \
        }                                                                     \
    } while (0)

    half8 af[4][2], bf01[2][2], bf23[2][2];
    f32x4 acc[8][4] = {};
    const int rsb = (lc & 7) << 4;

#define LDA(buf, mh)                                                          \
    do {                                                                      \
        const char* p_ = (const char*)lsA[buf];                               \
        _Pragma("unroll")                                                     \
        for (int ii = 0; ii < 4; ++ii) {                                      \
            const int row_ = wr * 128 + (mh) * 64 + ii * 16 + lc;             \
            _Pragma("unroll")                                                 \
            for (int kk = 0; kk < 2; ++kk)                                    \
                af[ii][kk] = *(const half8*)(p_ + row_ * 128 +                \
                             ((kk * 64 + (lrg << 4)) ^ rsb));                 \
        }                                                                     \
    } while (0)

#define LDB(buf, nh, bfr)                                                     \
    do {                                                                      \
        const char* p_ = (const char*)lsB[buf];                               \
        _Pragma("unroll")                                                     \
        for (int jj = 0; jj < 2; ++jj) {                                      \
            const int row_ = wc * 64 + ((nh) * 2 + jj) * 16 + lc;             \
            _Pragma("unroll")                                                 \
            for (int kk = 0; kk < 2; ++kk)                                    \
                bfr[jj][kk] = *(const half8*)(p_ + row_ * 128 +               \
                              ((kk * 64 + (lrg << 4)) ^ rsb));                \
        }                                                                     \
    } while (0)

#define MM(mh, nh, bfr)                                                       \
    do {                                                                      \
        __builtin_amdgcn_s_setprio(1);                                        \
        _Pragma("unroll")                                                     \
        for (int ii = 0; ii < 4; ++ii)                                        \
            _Pragma("unroll")                                                 \
            for (int jj = 0; jj < 2; ++jj)                                    \
                _Pragma("unroll")                                             \
                for (int kk = 0; kk < 2; ++kk)                                \
                    acc[(mh) * 4 + ii][(nh) * 2 + jj] =                       \
                        __builtin_amdgcn_mfma_f32_16x16x32_f16(               \
                            af[ii][kk], bfr[jj][kk],                          \
                            acc[(mh) * 4 + ii][(nh) * 2 + jj], 0, 0, 0);      \
        __builtin_amdgcn_s_setprio(0);                                        \
    } while (0)

#define BAR __builtin_amdgcn_s_barrier()
#define VMW(n) asm volatile("s_waitcnt vmcnt(" #n ")" ::: "memory")

    STG(&lsA[0][0], Ab);
    STG(&lsA[0][128 * 64], Ab + (size_t)128 * DD);
    STG(&lsB[0][0], Bb);
    STG(&lsB[0][128 * 64], Bb + (size_t)128 * DD);
    STG(&lsA[1][0], Ab + 64);
    VMW(2);
    BAR;

    for (int i = 0; i < 7; ++i) {
        const int kt1 = (2 * i + 1) * 64, kt2 = kt1 + 64, kt3 = kt2 + 64;
        LDA(0, 0); LDB(0, 0, bf01);
        STG(&lsA[1][128 * 64], Ab + (size_t)128 * DD + kt1);
        BAR; MM(0, 0, bf01); BAR;
        LDB(0, 1, bf23);
        STG(&lsB[1][0], Bb + kt1);
        BAR; MM(0, 1, bf23); BAR;
        LDA(0, 1);
        STG(&lsB[1][128 * 64], Bb + (size_t)128 * DD + kt1);
        BAR; MM(1, 0, bf01); BAR;
        STG(&lsA[0][0], Ab + kt2);
        BAR; MM(1, 1, bf23);
        VMW(2); BAR;
        LDA(1, 0); LDB(1, 0, bf01);
        STG(&lsA[0][128 * 64], Ab + (size_t)128 * DD + kt2);
        BAR; MM(0, 0, bf01); BAR;
        LDB(1, 1, bf23);
        STG(&lsB[0][0], Bb + kt2);
        BAR; MM(0, 1, bf23); BAR;
        LDA(1, 1);
        STG(&lsB[0][128 * 64], Bb + (size_t)128 * DD + kt2);
        BAR; MM(1, 0, bf01); BAR;
        STG(&lsA[1][0], Ab + kt3);
        BAR; MM(1, 1, bf23);
        VMW(2); BAR;
    }
    {
        const int kt1 = 15 * 64;
        LDA(0, 0); LDB(0, 0, bf01);
        STG(&lsA[1][128 * 64], Ab + (size_t)128 * DD + kt1);
        BAR; MM(0, 0, bf01); BAR;
        LDB(0, 1, bf23);
        STG(&lsB[1][0], Bb + kt1);
        BAR; MM(0, 1, bf23); BAR;
        LDA(0, 1);
        STG(&lsB[1][128 * 64], Bb + (size_t)128 * DD + kt1);
        BAR; MM(1, 0, bf01); BAR;
        BAR; MM(1, 1, bf23);
        VMW(0); BAR;
        LDA(1, 0); LDB(1, 0, bf01);
        BAR; MM(0, 0, bf01); BAR;
        LDB(1, 1, bf23);
        BAR; MM(0, 1, bf23); BAR;
        LDA(1, 1);
        BAR; MM(1, 0, bf01); BAR;
        BAR; MM(1, 1, bf23);
    }
    __syncthreads();

    _Float16* Cb = P + (size_t)z * sP;
    float* psum = (float*)&lsA[0][0];
    #pragma unroll
    for (int i = 0; i < 8; ++i) {
        float rsum[4] = {0.f, 0.f, 0.f, 0.f};
        #pragma unroll
        for (int j = 0; j < 4; ++j) {
            const int n = n0 + wc * 64 + j * 16 + lc;
            #pragma unroll
            for (int r = 0; r < 4; ++r) {
                const int m = m0 + wr * 128 + i * 16 + lr + r;
                const float e = __expf(acc[i][j][r] * scale);
                Cb[(size_t)m * LKK + n] = (_Float16)e;
                rsum[r] += e;
            }
        }
        #pragma unroll
        for (int r = 0; r < 4; ++r) {
            float s = rsum[r];
            s += __shfl_xor(s, 1);
            s += __shfl_xor(s, 2);
            s += __shfl_xor(s, 4);
            s += __shfl_xor(s, 8);
            if (lc == 0) psum[(wr * 128 + i * 16 + lr + r) * 4 + wc] = s;
        }
    }
    __syncthreads();
    if (tid < 256) {
        const float* pr = psum + tid * 4;
        partial[((size_t)z * LQ + m0 + tid) * 8 + bx] = pr[0] + pr[1] + pr[2] + pr[3];
    }
#undef STG
#undef LDA
#undef LDB
#undef MM
}

// ===========================================================================
// 256x128 NT-GEMM for PV / cat — R7: wave grid 4M x 2N (wave = 64x64 output;
// A-read amp x2, B-read amp x4 -> 128KB LDS-read/K-tile vs 160KB before).
// 3-buffer rolling schedule, counted vmcnt(6), 144KB LDS.
// ===========================================================================
__global__ __launch_bounds__(512, 2) void gemm_pc_256x128(
    const _Float16* __restrict__ Alo, long sAlo, int lda_lo,
    const _Float16* __restrict__ Ahi, long sAhi, int lda_hi,
    int ksplit,
    const _Float16* __restrict__ B, long sB, int ldb,
    int K, int mode,
    float* __restrict__ out32, long s32, int ldc32,
    _Float16* __restrict__ out16, long s16, int ldc16,
    const float* __restrict__ bias,
    const float* __restrict__ partial, int npart)
{
    __shared__ _Float16 ls[3][384 * 64];   // per buf: A 256x64 @0, B 128x64 @256*64
    const int tid = threadIdx.x;
    const int w = tid >> 6, l = tid & 63;
    const int wr = w >> 1, wc = w & 1;     // wave grid 4M x 2N (64 rows x 64 cols)
    const int lrg = l >> 4, lc = l & 15, lr = lrg << 2;

    int id = blockIdx.x + gridDim.x * (blockIdx.y + gridDim.y * blockIdx.z);
    const int nwg = gridDim.x * gridDim.y * gridDim.z;
    id = (id & 7) * (nwg >> 3) + (id >> 3);
    const int bx = id % gridDim.x;
    const int t2_ = id / gridDim.x;
    const int by = t2_ % gridDim.y;
    const int z  = t2_ / gridDim.y;
    const int m0 = by * 256, n0 = bx * 128;

    const _Float16* Abase_lo = Alo + (size_t)z * sAlo + (size_t)m0 * lda_lo;
    const _Float16* Abase_hi = Ahi ? (Ahi + (size_t)z * sAhi + (size_t)m0 * lda_hi) : (const _Float16*)0;
    const _Float16* Bbase = B + (size_t)z * sB + (size_t)n0 * ldb;

    const int srow = l >> 3;
    const int sk = ((l & 7) ^ srow) << 3;
    const int rsb = (lc & 7) << 4;

    half8 af[4][2], bf[2][2];
    f32x4 acc[4][4] = {};

#define STGA(tt, dbuf)                                                        \
    do {                                                                      \
        const int kb_ = (tt) * 64;                                            \
        const _Float16* s_; int ld_;                                          \
        if (kb_ < ksplit) { s_ = Abase_lo + kb_;           ld_ = lda_lo; }    \
        else              { s_ = Abase_hi + (kb_ - ksplit); ld_ = lda_hi; }   \
        _Float16* d_ = &ls[dbuf][0];                                          \
        _Pragma("unroll")                                                     \
        for (int rr = 0; rr < 4; ++rr) {                                      \
            const int c = w + 8 * rr;                                         \
            gl_lds16(s_ + (size_t)(c * 8 + srow) * ld_ + sk, d_ + c * 512);   \
        }                                                                     \
    } while (0)

#define STGB(tt, dbuf)                                                        \
    do {                                                                      \
        const _Float16* s_ = Bbase + (tt) * 64;                               \
        _Float16* d_ = &ls[dbuf][256 * 64];                                   \
        _Pragma("unroll")                                                     \
        for (int rr = 0; rr < 2; ++rr) {                                      \
            const int c = w + 8 * rr;                                         \
            gl_lds16(s_ + (size_t)(c * 8 + srow) * ldb + sk, d_ + c * 512);   \
        }                                                                     \
    } while (0)

    // A frags: wave's 64 rows (wr*64 .. +64), all 4 frags per K-tile
#define LDA2(buf)                                                             \
    do {                                                                      \
        const char* p_ = (const char*)&ls[buf][0];                            \
        _Pragma("unroll")                                                     \
        for (int ii = 0; ii < 4; ++ii) {                                      \
            const int row_ = wr * 64 + ii * 16 + lc;                          \
            _Pragma("unroll")                                                 \
            for (int kk = 0; kk < 2; ++kk)                                    \
                af[ii][kk] = *(const half8*)(p_ + row_ * 128 +                \
                             ((kk * 64 + (lrg << 4)) ^ rsb));                 \
        }                                                                     \
    } while (0)

    // B frags: wave's 64 n-rows (wc*64), half nh (2 frags)
#define LDB2(buf, nh)                                                         \
    do {                                                                      \
        const char* p_ = (const char*)&ls[buf][256 * 64];                     \
        _Pragma("unroll")                                                     \
        for (int jj = 0; jj < 2; ++jj) {                                      \
            const int row_ = wc * 64 + ((nh) * 2 + jj) * 16 + lc;             \
            _Pragma("unroll")                                                 \
            for (int kk = 0; kk < 2; ++kk)                                    \
                bf[jj][kk] = *(const half8*)(p_ + row_ * 128 +                \
                              ((kk * 64 + (lrg << 4)) ^ rsb));                \
        }                                                                     \
    } while (0)

#define MM2(nh)                                                               \
    do {                                                                      \
        __builtin_amdgcn_s_setprio(1);                                        \
        _Pragma("unroll")                                                     \
        for (int ii = 0; ii < 4; ++ii)                                        \
            _Pragma("unroll")                                                 \
            for (int jj = 0; jj < 2; ++jj)                                    \
                _Pragma("unroll")                                             \
                for (int kk = 0; kk < 2; ++kk)                                \
                    acc[ii][(nh) * 2 + jj] =                                  \
                        __builtin_amdgcn_mfma_f32_16x16x32_f16(               \
                            af[ii][kk], bf[jj][kk],                           \
                            acc[ii][(nh) * 2 + jj], 0, 0, 0);                 \
        __builtin_amdgcn_s_setprio(0);                                        \
    } while (0)

    const int NT = K >> 6;
    STGA(0, 0); STGB(0, 0);
    STGA(1, 1); STGB(1, 1);
    VMW(6);
    BAR;

    int b = 0, b2 = 2;
    for (int t = 0; t < NT; ++t) {
        const int tt = t + 2;
        const bool st = tt < NT;
        // P0: A frags + B half 0; stage A(t+2)
        LDA2(b); LDB2(b, 0);
        if (st) STGA(tt, b2);
        BAR; MM2(0); BAR;
        // P1: B half 1; stage B(t+2)
        LDB2(b, 1);
        if (st) STGB(tt, b2);
        BAR; MM2(1);
        if (t < NT - 2)       VMW(6);
        else if (t == NT - 2) VMW(0);
        BAR;
        b = (b == 2) ? 0 : b + 1;
        b2 = (b2 == 2) ? 0 : b2 + 1;
    }
    __syncthreads();

    if (mode == 1) {
        float* psum = (float*)&ls[0][0];   // [256] 1/rowsum
        if (tid < 256) {
            const float* pp = partial + ((size_t)z * LQ + m0 + tid) * npart;
            float s = 0.0f;
            for (int c = 0; c < npart; ++c) s += pp[c];
            psum[tid] = 1.0f / s;
        }
        __syncthreads();
        _Float16* Cb = out16 + (size_t)z * s16;
        #pragma unroll
        for (int i = 0; i < 4; ++i)
            #pragma unroll
            for (int j = 0; j < 4; ++j) {
                const int n = n0 + wc * 64 + j * 16 + lc;
                #pragma unroll
                for (int r = 0; r < 4; ++r) {
                    const int ml = wr * 64 + i * 16 + lr + r;
                    Cb[(size_t)(m0 + ml) * ldc16 + n] =
                        (_Float16)(acc[i][j][r] * psum[ml]);
                }
            }
    } else {
        float bv[4];
        #pragma unroll
        for (int j = 0; j < 4; ++j)
            bv[j] = bias[n0 + wc * 64 + j * 16 + lc];
        #pragma unroll
        for (int i = 0; i < 4; ++i)
            #pragma unroll
            for (int j = 0; j < 4; ++j) {
                const int n = n0 + wc * 64 + j * 16 + lc;
                #pragma unroll
                for (int r = 0; r < 4; ++r) {
                    const int m = m0 + wr * 64 + i * 16 + lr + r;
                    const float t = tanhf(acc[i][j][r] + bv[j]);
                    if (out16) out16[(size_t)z * s16 + (size_t)m * ldc16 + n] = (_Float16)t;
                    if (out32) out32[(size_t)z * s32 + (size_t)m * ldc32 + n] = t;
                }
            }
    }
#undef STGA
#undef STGB
#undef LDA2
#undef LDB2
#undef MM2
#undef BAR
#undef VMW
}

// ---------------------------------------------------------------------------
// f16 MFMA NT-GEMM 128x128 (R3-fallback path only)
// ---------------------------------------------------------------------------
__global__ __launch_bounds__(256) void gemm_f16_nt(
    const _Float16* __restrict__ Alo, long sAlo, int lda_lo,
    const _Float16* __restrict__ Ahi, long sAhi, int lda_hi,
    int ksplit,
    const _Float16* __restrict__ B, long sB, int ldb,
    int K, int mode, float scale,
    float* __restrict__ out32, long s32, int ldc32,
    _Float16* __restrict__ out16, long s16, int ldc16,
    const float* __restrict__ bias,
    float* __restrict__ partial, const float* __restrict__ inv, int npart)
{
    __shared__ _Float16 lsA[128 * 64];
    __shared__ _Float16 lsB[128 * 64];
    __shared__ float psum[128][2];
    const int tid = threadIdx.x;
    const int w = tid >> 6, l = tid & 63;
    const int wr = w >> 1, wc = w & 1;

    int id = blockIdx.x + gridDim.x * (blockIdx.y + gridDim.y * blockIdx.z);
    const int nwg = gridDim.x * gridDim.y * gridDim.z;
    id = (id & 7) * (nwg >> 3) + (id >> 3);
    const int bx = id % gridDim.x;
    const int t2 = id / gridDim.x;
    const int by = t2 % gridDim.y;
    const int z = t2 / gridDim.y;
    const int m0 = by * 128, n0 = bx * 128;

    const _Float16* Abase_lo = Alo + (size_t)z * sAlo + (size_t)m0 * lda_lo;
    const _Float16* Abase_hi = Ahi ? (Ahi + (size_t)z * sAhi + (size_t)m0 * lda_hi) : (const _Float16*)0;
    const _Float16* Bbase = B + (size_t)z * sB + (size_t)n0 * ldb;

    const int srow = l >> 3;
    const int sswz = ((l & 7) ^ srow) << 3;

    f32x4 acc[4][4] = {};

    for (int k0 = 0; k0 < K; k0 += 64) {
        const _Float16* Ap; int kloc, ldaA;
        if (k0 < ksplit) { Ap = Abase_lo; kloc = k0;          ldaA = lda_lo; }
        else             { Ap = Abase_hi; kloc = k0 - ksplit; ldaA = lda_hi; }
        #pragma unroll
        for (int i = 0; i < 4; ++i) {
            const int c = w * 4 + i;
            const int row = c * 8 + srow;
            gl_lds16(Ap + (size_t)row * ldaA + kloc + sswz, &lsA[c * 512]);
        }
        #pragma unroll
        for (int i = 0; i < 4; ++i) {
            const int c = w * 4 + i;
            const int row = c * 8 + srow;
            gl_lds16(Bbase + (size_t)row * ldb + k0 + sswz, &lsB[c * 512]);
        }
        __syncthreads();

        half8 af[4][2], bf[4][2];
        const char* lA = (const char*)lsA;
        const char* lB = (const char*)lsB;
        const int rs = (l & 7) << 4;
        const int cb = (l >> 4) << 4;
        #pragma unroll
        for (int i = 0; i < 4; ++i) {
            const int rowa = wr * 64 + i * 16 + (l & 15);
            const int rowb = wc * 64 + i * 16 + (l & 15);
            #pragma unroll
            for (int kk = 0; kk < 2; ++kk) {
                af[i][kk] = *(const half8*)(lA + rowa * 128 + ((kk * 64 + cb) ^ rs));
                bf[i][kk] = *(const half8*)(lB + rowb * 128 + ((kk * 64 + cb) ^ rs));
            }
        }
        #pragma unroll
        for (int kk = 0; kk < 2; ++kk)
            #pragma unroll
            for (int i = 0; i < 4; ++i)
                #pragma unroll
                for (int j = 0; j < 4; ++j)
                    acc[i][j] = __builtin_amdgcn_mfma_f32_16x16x32_f16(
                        af[i][kk], bf[j][kk], acc[i][j], 0, 0, 0);
        __syncthreads();
    }

    const int lr = (l >> 4) * 4;
    const int lc = l & 15;
    if (mode == 0) {
        _Float16* Cb = out16 + (size_t)z * s16;
        float rsum[4][4];
        #pragma unroll
        for (int i = 0; i < 4; ++i)
            #pragma unroll
            for (int r = 0; r < 4; ++r) rsum[i][r] = 0.0f;
        #pragma unroll
        for (int i = 0; i < 4; ++i)
            #pragma unroll
            for (int j = 0; j < 4; ++j) {
                const int n = n0 + wc * 64 + j * 16 + lc;
                #pragma unroll
                for (int r = 0; r < 4; ++r) {
                    const int m = m0 + wr * 64 + i * 16 + lr + r;
                    const float e = __expf(acc[i][j][r] * scale);
                    Cb[(size_t)m * ldc16 + n] = (_Float16)e;
                    rsum[i][r] += e;
                }
            }
        #pragma unroll
        for (int i = 0; i < 4; ++i)
            #pragma unroll
            for (int r = 0; r < 4; ++r) {
                float s = rsum[i][r];
                s += __shfl_xor(s, 1);
                s += __shfl_xor(s, 2);
                s += __shfl_xor(s, 4);
                s += __shfl_xor(s, 8);
                rsum[i][r] = s;
            }
        if (lc == 0) {
            #pragma unroll
            for (int i = 0; i < 4; ++i)
                #pragma unroll
                for (int r = 0; r < 4; ++r)
                    psum[wr * 64 + i * 16 + lr + r][wc] = rsum[i][r];
        }
        __syncthreads();
        if (tid < 128)
            partial[((size_t)z * LQ + m0 + tid) * npart + bx] = psum[tid][0] + psum[tid][1];
    } else if (mode == 1) {
        _Float16* Cb = out16 + (size_t)z * s16;
        float iv[4][4];
        if (partial) {
            if (tid < 128) {
                const float* pp = partial + ((size_t)z * LQ + m0 + tid) * npart;
                float s = 0.0f;
                for (int c = 0; c < npart; ++c) s += pp[c];
                psum[tid][0] = 1.0f / s;
            }
            __syncthreads();
            #pragma unroll
            for (int i = 0; i < 4; ++i)
                #pragma unroll
                for (int r = 0; r < 4; ++r)
                    iv[i][r] = psum[wr * 64 + i * 16 + lr + r][0];
        } else {
            #pragma unroll
            for (int i = 0; i < 4; ++i)
                #pragma unroll
                for (int r = 0; r < 4; ++r)
                    iv[i][r] = inv ? inv[(size_t)z * LQ + m0 + wr * 64 + i * 16 + lr + r] : 1.0f;
        }
        #pragma unroll
        for (int i = 0; i < 4; ++i)
            #pragma unroll
            for (int j = 0; j < 4; ++j) {
                const int n = n0 + wc * 64 + j * 16 + lc;
                #pragma unroll
                for (int r = 0; r < 4; ++r) {
                    const int m = m0 + wr * 64 + i * 16 + lr + r;
                    Cb[(size_t)m * ldc16 + n] = (_Float16)(acc[i][j][r] * iv[i][r]);
                }
            }
    } else if (mode == 4) {
        float* Cb = out32 + (size_t)z * s32;
        #pragma unroll
        for (int i = 0; i < 4; ++i)
            #pragma unroll
            for (int j = 0; j < 4; ++j) {
                const int n = n0 + wc * 64 + j * 16 + lc;
                #pragma unroll
                for (int r = 0; r < 4; ++r) {
                    const int m = m0 + wr * 64 + i * 16 + lr + r;
                    Cb[(size_t)m * ldc32 + n] = acc[i][j][r] * scale;
                }
            }
    } else {
        float bv[4];
        #pragma unroll
        for (int j = 0; j < 4; ++j)
            bv[j] = bias[n0 + wc * 64 + j * 16 + lc];
        #pragma unroll
        for (int i = 0; i < 4; ++i)
            #pragma unroll
            for (int j = 0; j < 4; ++j) {
                const int n = n0 + wc * 64 + j * 16 + lc;
                #pragma unroll
                for (int r = 0; r < 4; ++r) {
                    const int m = m0 + wr * 64 + i * 16 + lr + r;
                    const float t = tanhf(acc[i][j][r] + bv[j]);
                    if (out16) out16[(size_t)z * s16 + (size_t)m * ldc16 + n] = (_Float16)t;
                    if (out32) out32[(size_t)z * s32 + (size_t)m * ldc32 + n] = t;
                }
            }
    }
}

// one block per row: attn_f32[row,:] = P16[row,:] * (1/sum partial[row,0..npart))
__global__ __launch_bounds__(256) void scale_attn(
    const _Float16* __restrict__ P, const float* __restrict__ partial,
    float* __restrict__ attn, int npart)
{
    __shared__ float sinv;
    const long row = blockIdx.x;
    const int tid = threadIdx.x;
    if (tid < npart) {
        float s = partial[row * npart + tid];
        for (int off = npart >> 1; off > 0; off >>= 1) s += __shfl_xor(s, off);
        if (tid == 0) sinv = 1.0f / s;
    }
    __syncthreads();
    const float inv = sinv;
    const half8 h = *(const half8*)(P + row * 2048 + tid * 8);
    float* o = attn + row * 2048 + tid * 8;
    float4 a = make_float4((float)h[0] * inv, (float)h[1] * inv,
                           (float)h[2] * inv, (float)h[3] * inv);
    float4 b = make_float4((float)h[4] * inv, (float)h[5] * inv,
                           (float)h[6] * inv, (float)h[7] * inv);
    *(float4*)o = a;
    *(float4*)(o + 4) = b;
}

// inv[row] = 1 / sum_{cb<16} partial[row*16+cb]   (R3-fallback path)
__global__ __launch_bounds__(256) void make_inv(
    const float* __restrict__ partial, float* __restrict__ inv)
{
    const int row = blockIdx.x * 256 + threadIdx.x;
    const float4 a = *(const float4*)(partial + (size_t)row * 16);
    const float4 b = *(const float4*)(partial + (size_t)row * 16 + 4);
    const float4 c = *(const float4*)(partial + (size_t)row * 16 + 8);
    const float4 d = *(const float4*)(partial + (size_t)row * 16 + 12);
    const float s = (a.x + a.y + a.z + a.w) + (b.x + b.y + b.z + b.w)
                  + (c.x + c.y + c.z + c.w) + (d.x + d.y + d.z + d.w);
    inv[row] = 1.0f / s;
}

// row softmax over 2048 f32 (R3-fallback hop 2)
__global__ __launch_bounds__(256) void softmax_rows2(
    float* __restrict__ S, _Float16* __restrict__ f16out,
    long f16stride, int write_f32)
{
    __shared__ float red[8];
    const long row = blockIdx.x;
    float* p = S + row * LKK;
    const int tid = threadIdx.x;
    float4 v0 = ((const float4*)p)[tid];
    float4 v1 = ((const float4*)p)[tid + 256];
    float m = fmaxf(fmaxf(fmaxf(v0.x, v0.y), fmaxf(v0.z, v0.w)),
                    fmaxf(fmaxf(v1.x, v1.y), fmaxf(v1.z, v1.w)));
    #pragma unroll
    for (int off = 32; off > 0; off >>= 1) m = fmaxf(m, __shfl_down(m, off));
    if ((tid & 63) == 0) red[tid >> 6] = m;
    __syncthreads();
    m = fmaxf(fmaxf(red[0], red[1]), fmaxf(red[2], red[3]));
    v0.x = expf(v0.x - m); v0.y = expf(v0.y - m);
    v0.z = expf(v0.z - m); v0.w = expf(v0.w - m);
    v1.x = expf(v1.x - m); v1.y = expf(v1.y - m);
    v1.z = expf(v1.z - m); v1.w = expf(v1.w - m);
    float s = v0.x + v0.y + v0.z + v0.w + v1.x + v1.y + v1.z + v1.w;
    #pragma unroll
    for (int off = 32; off > 0; off >>= 1) s += __shfl_down(s, off);
    if ((tid & 63) == 0) red[4 + (tid >> 6)] = s;
    __syncthreads();
    s = red[4] + red[5] + red[6] + red[7];
    const float inv = 1.0f / s;
    v0.x *= inv; v0.y *= inv; v0.z *= inv; v0.w *= inv;
    v1.x *= inv; v1.y *= inv; v1.z *= inv; v1.w *= inv;
    if (write_f32) {
        ((float4*)p)[tid] = v0;
        ((float4*)p)[tid + 256] = v1;
    }
    _Float16* q = f16out + row * f16stride;
    half4 h0 = { (_Float16)v0.x, (_Float16)v0.y, (_Float16)v0.z, (_Float16)v0.w };
    half4 h1 = { (_Float16)v1.x, (_Float16)v1.y, (_Float16)v1.z, (_Float16)v1.w };
    *(half4*)(q + tid * 4) = h0;
    *(half4*)(q + 1024 + tid * 4) = h1;
}

// fused grid-stride f32->f16 convert for Q, K, W
__global__ __launch_bounds__(256) void cvt3(
    const float* __restrict__ Q, const float* __restrict__ K,
    const float* __restrict__ W,
    _Float16* __restrict__ Qh, _Float16* __restrict__ Kh,
    _Float16* __restrict__ Wh)
{
    const long nQ = (long)NB * LQ * DD;          // 8388608
    const long nK = (long)NB * LKK * DD;         // 33554432
    const long nW = (long)DD * 2 * DD;           // 2097152
    const long total = (nQ + nK + nW) >> 3;
    for (long c = (long)blockIdx.x * 256 + threadIdx.x; c < total;
         c += (long)gridDim.x * 256) {
        const long i = c << 3;
        const float* src; _Float16* dst; long off;
        if (i < nQ)           { src = Q; dst = Qh; off = i; }
        else if (i < nQ + nK) { src = K; dst = Kh; off = i - nQ; }
        else                  { src = W; dst = Wh; off = i - nQ - nK; }
        float4 a = *(const float4*)(src + off);
        float4 b = *(const float4*)(src + off + 4);
        half8 h = { (_Float16)a.x, (_Float16)a.y, (_Float16)a.z, (_Float16)a.w,
                    (_Float16)b.x, (_Float16)b.y, (_Float16)b.z, (_Float16)b.w };
        *(half8*)(dst + off) = h;
    }
}

__global__ __launch_bounds__(256) void cvt_f32_to_f16(
    const float* __restrict__ in, _Float16* __restrict__ out, long n)
{
    const long i = ((long)blockIdx.x * 256 + threadIdx.x) * 8;
    if (i + 8 > n) return;
    float4 a = *(const float4*)(in + i);
    float4 b = *(const float4*)(in + i + 4);
    half8 h = { (_Float16)a.x, (_Float16)a.y, (_Float16)a.z, (_Float16)a.w,
                (_Float16)b.x, (_Float16)b.y, (_Float16)b.z, (_Float16)b.w };
    *(half8*)(out + i) = h;
}

// V [B, Lk, D] f32 -> Vt [B, D, Lk] f16, 64x64 tiles via LDS
__global__ __launch_bounds__(256) void transpose_cvt_v(
    const float* __restrict__ V, _Float16* __restrict__ Vt)
{
    __shared__ _Float16 t[64][80];
    const int z = blockIdx.z;
    const int k0 = blockIdx.y * 64, d0 = blockIdx.x * 64;
    const float* Vb = V + (size_t)z * LKK * DD;
    _Float16* Vtb = Vt + (size_t)z * DD * LKK;
    const int r = threadIdx.x >> 2;
    const int c0 = (threadIdx.x & 3) * 16;
    #pragma unroll
    for (int j = 0; j < 4; ++j) {
        float4 v = *(const float4*)(Vb + (size_t)(k0 + r) * DD + d0 + c0 + j * 4);
        t[c0 + j * 4 + 0][r] = (_Float16)v.x;
        t[c0 + j * 4 + 1][r] = (_Float16)v.y;
        t[c0 + j * 4 + 2][r] = (_Float16)v.z;
        t[c0 + j * 4 + 3][r] = (_Float16)v.w;
    }
    __syncthreads();
    #pragma unroll
    for (int j = 0; j < 2; ++j) {
        half8 h = *(const half8*)&t[r][c0 + j * 8];
        *(half8*)(Vtb + (size_t)(d0 + r) * LKK + k0 + c0 + j * 8) = h;
    }
}

// ======================= round-1 f32 fallback kernels =======================
constexpr int TM = 64, TN = 64, TK = 32;
constexpr int PAD = 4;

__global__ __launch_bounds__(256) void gemm_nt_k(
    const float* __restrict__ A, int lda, long sA,
    const float* __restrict__ Bt, int ldb, long sB,
    float* __restrict__ C, int ldc, long sC, int K, float scale)
{
    __shared__ float As[TK][TM + PAD];
    __shared__ float Bs[TK][TN + PAD];
    const float* Ab = A + (long)blockIdx.z * sA;
    const float* Bb = Bt + (long)blockIdx.z * sB;
    float* Cb = C + (long)blockIdx.z * sC;
    const int m0 = blockIdx.y * TM, n0 = blockIdx.x * TN;
    const int tid = threadIdx.x;
    const int tn = tid & 15, tm = tid >> 4;
    float acc[4][4] = {};
    for (int k0 = 0; k0 < K; k0 += TK) {
        #pragma unroll
        for (int c = tid; c < (TM * TK) / 4; c += 256) {
            const int row = c >> 3, kc = (c & 7) << 2;
            const float4 g = *(const float4*)(Ab + (long)(m0 + row) * lda + (k0 + kc));
            As[kc + 0][row] = g.x; As[kc + 1][row] = g.y;
            As[kc + 2][row] = g.z; As[kc + 3][row] = g.w;
        }
        #pragma unroll
        for (int c = tid; c < (TN * TK) / 4; c += 256) {
            const int row = c >> 3, kc = (c & 7) << 2;
            const float4 g = *(const float4*)(Bb + (long)(n0 + row) * ldb + (k0 + kc));
            Bs[kc + 0][row] = g.x; Bs[kc + 1][row] = g.y;
            Bs[kc + 2][row] = g.z; Bs[kc + 3][row] = g.w;
        }
        __syncthreads();
        #pragma unroll
        for (int kk = 0; kk < TK; ++kk) {
            const float4 av = *(const float4*)&As[kk][tm << 2];
            const float4 bv = *(const float4*)&Bs[kk][tn << 2];
            const float a[4] = {av.x, av.y, av.z, av.w};
            const float b[4] = {bv.x, bv.y, bv.z, bv.w};
            #pragma unroll
            for (int i = 0; i < 4; ++i)
                #pragma unroll
                for (int j = 0; j < 4; ++j)
                    acc[i][j] = fmaf(a[i], b[j], acc[i][j]);
        }
        __syncthreads();
    }
    #pragma unroll
    for (int i = 0; i < 4; ++i) {
        float4 o = make_float4(acc[i][0] * scale, acc[i][1] * scale,
                               acc[i][2] * scale, acc[i][3] * scale);
        *(float4*)(Cb + (long)(m0 + (tm << 2) + i) * ldc + n0 + (tn << 2)) = o;
    }
}

__global__ __launch_bounds__(256) void gemm_nn_k(
    const float* __restrict__ A, int lda, long sA,
    const float* __restrict__ B, int ldb, long sB,
    float* __restrict__ C, int ldc, long sC, int K)
{
    __shared__ float As[TK][TM + PAD];
    __shared__ float Bs[TK][TN + PAD];
    const float* Ab = A + (long)blockIdx.z * sA;
    const float* Bb = B + (long)blockIdx.z * sB;
    float* Cb = C + (long)blockIdx.z * sC;
    const int m0 = blockIdx.y * TM, n0 = blockIdx.x * TN;
    const int tid = threadIdx.x;
    const int tn = tid & 15, tm = tid >> 4;
    float acc[4][4] = {};
    for (int k0 = 0; k0 < K; k0 += TK) {
        #pragma unroll
        for (int c = tid; c < (TM * TK) / 4; c += 256) {
            const int row = c >> 3, kc = (c & 7) << 2;
            const float4 g = *(const float4*)(Ab + (long)(m0 + row) * lda + (k0 + kc));
            As[kc + 0][row] = g.x; As[kc + 1][row] = g.y;
            As[kc + 2][row] = g.z; As[kc + 3][row] = g.w;
        }
        #pragma unroll
        for (int c = tid; c < (TK * TN) / 4; c += 256) {
            const int krow = c >> 4, nc = (c & 15) << 2;
            *(float4*)&Bs[krow][nc] =
                *(const float4*)(Bb + (long)(k0 + krow) * ldb + n0 + nc);
        }
        __syncthreads();
        #pragma unroll
        for (int kk = 0; kk < TK; ++kk) {
            const float4 av = *(const float4*)&As[kk][tm << 2];
            const float4 bv = *(const float4*)&Bs[kk][tn << 2];
            const float a[4] = {av.x, av.y, av.z, av.w};
            const float b[4] = {bv.x, bv.y, bv.z, bv.w};
            #pragma unroll
            for (int i = 0; i < 4; ++i)
                #pragma unroll
                for (int j = 0; j < 4; ++j)
                    acc[i][j] = fmaf(a[i], b[j], acc[i][j]);
        }
        __syncthreads();
    }
    #pragma unroll
    for (int i = 0; i < 4; ++i) {
        float4 o = make_float4(acc[i][0], acc[i][1], acc[i][2], acc[i][3]);
        *(float4*)(Cb + (long)(m0 + (tm << 2) + i) * ldc + n0 + (tn << 2)) = o;
    }
}

__global__ __launch_bounds__(256) void gemm_cat_k(
    const float* __restrict__ Qh, const float* __restrict__ R,
    const float* __restrict__ W, const float* __restrict__ bias,
    float* __restrict__ C)
{
    __shared__ float As[TK][TM + PAD];
    __shared__ float Bs[TK][TN + PAD];
    const float* Qb = Qh + (long)blockIdx.z * LQ * DD;
    const float* Rb = R + (long)blockIdx.z * LQ * DD;
    float* Cb = C + (long)blockIdx.z * LQ * DD;
    const int m0 = blockIdx.y * TM, n0 = blockIdx.x * TN;
    const int tid = threadIdx.x;
    const int tn = tid & 15, tm = tid >> 4;
    float acc[4][4] = {};
    for (int k0 = 0; k0 < 2 * DD; k0 += TK) {
        const float* src = (k0 < DD) ? Qb : Rb;
        const int kb = (k0 < DD) ? k0 : k0 - DD;
        #pragma unroll
        for (int c = tid; c < (TM * TK) / 4; c += 256) {
            const int row = c >> 3, kc = (c & 7) << 2;
            const float4 g = *(const float4*)(src + (long)(m0 + row) * DD + (kb + kc));
            As[kc + 0][row] = g.x; As[kc + 1][row] = g.y;
            As[kc + 2][row] = g.z; As[kc + 3][row] = g.w;
        }
        #pragma unroll
        for (int c = tid; c < (TN * TK) / 4; c += 256) {
            const int row = c >> 3, kc = (c & 7) << 2;
            const float4 g = *(const float4*)(W + (long)(n0 + row) * (2 * DD) + (k0 + kc));
            Bs[kc + 0][row] = g.x; Bs[kc + 1][row] = g.y;
            Bs[kc + 2][row] = g.z; Bs[kc + 3][row] = g.w;
        }
        __syncthreads();
        #pragma unroll
        for (int kk = 0; kk < TK; ++kk) {
            const float4 av = *(const float4*)&As[kk][tm << 2];
            const float4 bv = *(const float4*)&Bs[kk][tn << 2];
            const float a[4] = {av.x, av.y, av.z, av.w};
            const float b[4] = {bv.x, bv.y, bv.z, bv.w};
            #pragma unroll
            for (int i = 0; i < 4; ++i)
                #pragma unroll
                for (int j = 0; j < 4; ++j)
                    acc[i][j] = fmaf(a[i], b[j], acc[i][j]);
        }
        __syncthreads();
    }
    #pragma unroll
    for (int i = 0; i < 4; ++i) {
        float4 o;
        o.x = tanhf(acc[i][0] + bias[n0 + (tn << 2) + 0]);
        o.y = tanhf(acc[i][1] + bias[n0 + (tn << 2) + 1]);
        o.z = tanhf(acc[i][2] + bias[n0 + (tn << 2) + 2]);
        o.w = tanhf(acc[i][3] + bias[n0 + (tn << 2) + 3]);
        *(float4*)(Cb + (long)(m0 + (tm << 2) + i) * DD + n0 + (tn << 2)) = o;
    }
}

__global__ __launch_bounds__(256) void softmax_rows(float* __restrict__ S) {
    __shared__ float red[8];
    float* p = S + (size_t)blockIdx.x * LKK;
    const int tid = threadIdx.x;
    float4 v0 = ((const float4*)p)[tid];
    float4 v1 = ((const float4*)p)[tid + 256];
    float m = fmaxf(fmaxf(fmaxf(v0.x, v0.y), fmaxf(v0.z, v0.w)),
                    fmaxf(fmaxf(v1.x, v1.y), fmaxf(v1.z, v1.w)));
    #pragma unroll
    for (int off = 32; off > 0; off >>= 1) m = fmaxf(m, __shfl_down(m, off));
    if ((tid & 63) == 0) red[tid >> 6] = m;
    __syncthreads();
    m = fmaxf(fmaxf(red[0], red[1]), fmaxf(red[2], red[3]));
    v0.x = expf(v0.x - m); v0.y = expf(v0.y - m);
    v0.z = expf(v0.z - m); v0.w = expf(v0.w - m);
    v1.x = expf(v1.x - m); v1.y = expf(v1.y - m);
    v1.z = expf(v1.z - m); v1.w = expf(v1.w - m);
    float s = v0.x + v0.y + v0.z + v0.w + v1.x + v1.y + v1.z + v1.w;
    #pragma unroll
    for (int off = 32; off > 0; off >>= 1) s += __shfl_down(s, off);
    if ((tid & 63) == 0) red[4 + (tid >> 6)] = s;
    __syncthreads();
    s = red[4] + red[5] + red[6] + red[7];
    const float inv = 1.0f / s;
    v0.x *= inv; v0.y *= inv; v0.z *= inv; v0.w *= inv;
    v1.x *= inv; v1.y *= inv; v1.z *= inv; v1.w *= inv;
    ((float4*)p)[tid] = v0;
    ((float4*)p)[tid + 256] = v1;
}

// ===========================================================================
extern "C" void kernel_launch(void* const* d_in, const int* in_sizes, int n_in,
                              void* d_out, int out_size, void* d_ws, size_t ws_size,
                              hipStream_t stream) {
    const float* Q    = (const float*)d_in[0];
    const float* Km   = (const float*)d_in[1];
    const float* V    = (const float*)d_in[2];
    const float* W    = (const float*)d_in[3];
    const float* bias = (const float*)d_in[4];
    const float scale = 0.03125f;  // 1/sqrt(1024)
    dim3 blk(256);

    const size_t NEED_FULL = 189267968ULL;
    const size_t NEED_R3   = 155189248ULL;

    if (ws_size >= NEED_FULL) {
        char* ws = (char*)d_ws;
        _Float16* Kh     = (_Float16*)ws;                    // [16,2048,1024]
        _Float16* Vt     = (_Float16*)(ws + 67108864);       // [16,1024,2048]
        _Float16* Wh     = (_Float16*)(ws + 134217728);      // [1024,2048]
        _Float16* Rh     = (_Float16*)(ws + 138412032);      // [16,512,1024]
        _Float16* Qping  = (_Float16*)(ws + 155189248);      // [16,512,1024]
        _Float16* Qpong  = (_Float16*)(ws + 171966464);      // [16,512,1024]
        float*    partialB = (float*)(ws + 188743680);       // [8192,8]

        float*    outQ  = (float*)d_out;
        _Float16* P2    = (_Float16*)d_out;
        float*    attnF = (float*)((char*)d_out + 33554432);
        _Float16* P01   = (_Float16*)attnF;

        cvt3<<<2048, blk, 0, stream>>>(Q, Km, W, Qping, Kh, Wh);
        transpose_cvt_v<<<dim3(DD / 64, LKK / 64, NB), blk, 0, stream>>>(V, Vt);

        dim3 gS2(LKK / 256, LQ / 256, NB);  // 8 x 2 x 16 = 256 blocks
        dim3 gP(DD / 128, LQ / 256, NB);    // 8 x 2 x 16 = 256 blocks

        for (int h = 0; h < 3; ++h) {
            _Float16* qcur = (h == 1) ? Qpong : Qping;
            _Float16* P    = (h == 2) ? P2 : P01;

            // ---- fused 8-phase 256^2: P = exp(Qh K^T * scale), 8-wide partials
            gemm_qk_256<<<gS2, dim3(512), 0, stream>>>(
                qcur, (long)LQ * DD, Kh, (long)LKK * DD,
                P, (long)LQ * LKK, partialB, scale);
            if (h == 2)
                scale_attn<<<NB * LQ, blk, 0, stream>>>(P2, partialB, attnF, 8);
            // ---- R = (P V) * inv(row)  [256x128, 4Mx2N waves, 3-buf pipeline]
            gemm_pc_256x128<<<gP, dim3(512), 0, stream>>>(
                P, (long)LQ * LKK, LKK,
                (const _Float16*)0, 0, 0, LKK * 16,   // ksplit > K: lo only
                Vt, (long)DD * LKK, LKK,
                LKK, 1,
                (float*)0, 0, 0,
                Rh, (long)LQ * DD, DD,
                (const float*)0, partialB, 8);
            // ---- Qnext = tanh([Qh|R] W^T + b)
            _Float16* qn = (h == 0) ? Qpong : (h == 1) ? Qping : (_Float16*)0;
            float* fo = (h == 2) ? outQ : (float*)0;
            gemm_pc_256x128<<<gP, dim3(512), 0, stream>>>(
                qcur, (long)LQ * DD, DD,
                Rh, (long)LQ * DD, DD, DD,            // ksplit = 1024
                Wh, 0, 2 * DD,
                2 * DD, 2,
                fo, (long)LQ * DD, DD,
                qn, (long)LQ * DD, DD,
                bias, (const float*)0, 0);
        }
    } else if (ws_size >= NEED_R3) {
        // -------- proven R3 path --------
        char* ws = (char*)d_ws;
        _Float16* Kh  = (_Float16*)ws;
        _Float16* Vt  = (_Float16*)(ws + 67108864);
        _Float16* Wh  = (_Float16*)(ws + 134217728);
        _Float16* Rh  = (_Float16*)(ws + 138412032);
        _Float16* attn2 = (_Float16*)ws;
        float* Fout = (float*)(ws + 33554432);

        _Float16* Qping = (_Float16*)d_out;
        _Float16* Qpong = Qping + (size_t)NB * LQ * DD;
        float* S = (float*)((char*)d_out + 33554432);
        _Float16* P = (_Float16*)S;
        float* partialB = (float*)((char*)d_out + 73400320);
        float* invB     = (float*)((char*)d_out + 73924608);

        cvt_f32_to_f16<<<4096, blk, 0, stream>>>(Q, Qping, (long)NB * LQ * DD);
        cvt_f32_to_f16<<<16384, blk, 0, stream>>>(Km, Kh, (long)NB * LKK * DD);
        cvt_f32_to_f16<<<1024, blk, 0, stream>>>(W, Wh, (long)DD * 2 * DD);
        transpose_cvt_v<<<dim3(DD / 64, LKK / 64, NB), blk, 0, stream>>>(V, Vt);

        dim3 gS(LKK / 128, LQ / 128, NB);
        dim3 gR(DD / 128, LQ / 128, NB);

        for (int h = 0; h < 3; ++h) {
            _Float16* qcur = (h == 1) ? Qpong : Qping;
            if (h < 2) {
                gemm_f16_nt<<<gS, blk, 0, stream>>>(
                    qcur, (long)LQ * DD, DD, (const _Float16*)0, 0, 0, DD,
                    Kh, (long)LKK * DD, DD, DD,
                    0, scale, (float*)0, 0, 0,
                    P, (long)LQ * LKK, LKK, (const float*)0,
                    partialB, (const float*)0, 16);
                make_inv<<<32, blk, 0, stream>>>(partialB, invB);
                gemm_f16_nt<<<gR, blk, 0, stream>>>(
                    P, (long)LQ * LKK, LKK,
                    (const _Float16*)0, 0, 0, LKK,
                    Vt, (long)DD * LKK, LKK, LKK,
                    1, 1.0f, (float*)0, 0, 0,
                    Rh, (long)LQ * DD, DD, (const float*)0,
                    (float*)0, invB, 0);
            } else {
                gemm_f16_nt<<<gS, blk, 0, stream>>>(
                    qcur, (long)LQ * DD, DD, (const _Float16*)0, 0, 0, DD,
                    Kh, (long)LKK * DD, DD, DD,
                    4, scale, S, (long)LQ * LKK, LKK,
                    (_Float16*)0, 0, 0, (const float*)0,
                    (float*)0, (const float*)0, 0);
                softmax_rows2<<<NB * LQ, blk, 0, stream>>>(S, attn2, 2048L, 1);
                gemm_f16_nt<<<gR, blk, 0, stream>>>(
                    attn2, (long)LQ * LKK, LKK,
                    (const _Float16*)0, 0, 0, LKK,
                    Vt, (long)DD * LKK, LKK, LKK,
                    1, 1.0f, (float*)0, 0, 0,
                    Rh, (long)LQ * DD, DD, (const float*)0,
                    (float*)0, (const float*)0, 0);
            }
            _Float16* qn = (h == 0) ? Qpong : (h == 1) ? Qping : (_Float16*)0;
            float* fo = (h == 2) ? Fout : (float*)0;
            gemm_f16_nt<<<gR, blk, 0, stream>>>(
                qcur, (long)LQ * DD, DD,
                Rh, (long)LQ * DD, DD, DD,
                Wh, 0, 2 * DD, 2 * DD,
                2, 1.0f, fo, (long)LQ * DD, DD,
                qn, (long)LQ * DD, DD, bias,
                (float*)0, (const float*)0, 0);
        }
        hipMemcpyAsync(d_out, Fout, 33554432ULL, hipMemcpyDeviceToDevice, stream);
    } else {
        // -------- round-1 f32 fallback --------
        float* outQ = (float*)d_out;
        float* S    = outQ + (size_t)NB * LQ * DD;
        float* R    = (float*)d_ws;
        float* T    = R + (size_t)NB * LQ * DD;
        dim3 gS(LKK / TN, LQ / TM, NB);
        dim3 gR(DD / TN, LQ / TM, NB);
        for (int h = 0; h < 3; ++h) {
            const float* Qh = (h == 0) ? Q : (h == 1 ? (const float*)T : (const float*)outQ);
            float* cout = (h == 1) ? outQ : T;
            gemm_nt_k<<<gS, blk, 0, stream>>>(Qh, DD, (long)LQ * DD, Km, DD, (long)LKK * DD,
                                              S, LKK, (long)LQ * LKK, DD, scale);
            softmax_rows<<<NB * LQ, blk, 0, stream>>>(S);
            gemm_nn_k<<<gR, blk, 0, stream>>>(S, LKK, (long)LQ * LKK, V, DD, (long)LKK * DD,
                                              R, DD, (long)LQ * DD, LKK);
            gemm_cat_k<<<gR, blk, 0, stream>>>(Qh, R, W, bias, cout);
        }
        hipMemcpyAsync(outQ, T, (size_t)NB * LQ * DD * sizeof(float),
                       hipMemcpyDeviceToDevice, stream);
    }
}

// Round 8
// 492.437 us; speedup vs baseline: 8.9953x; 1.0043x over previous
//
#include <hip/hip_runtime.h>
#include <math.h>

#define NB 16
#define LQ 512
#define LKK 2048
#define DD 1024

typedef _Float16 half8 __attribute__((ext_vector_type(8)));
typedef _Float16 half4 __attribute__((ext_vector_type(4)));
typedef float f32x4 __attribute__((ext_vector_type(4)));

__device__ __forceinline__ void gl_lds16(const void* g, void* l) {
    __builtin_amdgcn_global_load_lds(
        (const __attribute__((address_space(1))) void*)g,
        (__attribute__((address_space(3))) void*)l, 16, 0, 0);
}

// ===========================================================================
// 8-phase 256x256 NT-GEMM for QK^T  [proven R5/R6 — unchanged]
// ===========================================================================
__global__ __launch_bounds__(512, 2) void gemm_qk_256(
    const _Float16* __restrict__ A, long sA,
    const _Float16* __restrict__ B, long sB,
    _Float16* __restrict__ P, long sP,
    float* __restrict__ partial,
    float scale)
{
    __shared__ _Float16 lsA[2][256 * 64];
    __shared__ _Float16 lsB[2][256 * 64];
    const int tid = threadIdx.x;
    const int w = tid >> 6, l = tid & 63;
    const int wr = w >> 2, wc = w & 3;
    const int lrg = l >> 4, lc = l & 15, lr = lrg << 2;

    int id = blockIdx.x + gridDim.x * (blockIdx.y + gridDim.y * blockIdx.z);
    const int nwg = gridDim.x * gridDim.y * gridDim.z;
    id = (id & 7) * (nwg >> 3) + (id >> 3);
    const int bx = id % gridDim.x;
    const int t2 = id / gridDim.x;
    const int by = t2 % gridDim.y;
    const int z  = t2 / gridDim.y;
    const int m0 = by * 256, n0 = bx * 256;

    const _Float16* Ab = A + (size_t)z * sA + (size_t)m0 * DD;
    const _Float16* Bb = B + (size_t)z * sB + (size_t)n0 * DD;

    const int srow = l >> 3;
    const int sk = ((l & 7) ^ srow) << 3;

#define STG(dst, srcbase)                                                     \
    do {                                                                      \
        _Pragma("unroll")                                                     \
        for (int rr = 0; rr < 2; ++rr) {                                      \
            const int c = w + 8 * rr;                                         \
            gl_lds16((srcbase) + (size_t)(c * 8 + srow) * DD + sk,            \
                     (dst) + c * 512);                                        \
        }                                                                     \
    } while (0)

    half8 af[4][2], bf01[2][2], bf23[2][2];
    f32x4 acc[8][4] = {};
    const int rsb = (lc & 7) << 4;

#define LDA(buf, mh)                                                          \
    do {                                                                      \
        const char* p_ = (const char*)lsA[buf];                               \
        _Pragma("unroll")                                                     \
        for (int ii = 0; ii < 4; ++ii) {                                      \
            const int row_ = wr * 128 + (mh) * 64 + ii * 16 + lc;             \
            _Pragma("unroll")                                                 \
            for (int kk = 0; kk < 2; ++kk)                                    \
                af[ii][kk] = *(const half8*)(p_ + row_ * 128 +                \
                             ((kk * 64 + (lrg << 4)) ^ rsb));                 \
        }                                                                     \
    } while (0)

#define LDB(buf, nh, bfr)                                                     \
    do {                                                                      \
        const char* p_ = (const char*)lsB[buf];                               \
        _Pragma("unroll")                                                     \
        for (int jj = 0; jj < 2; ++jj) {                                      \
            const int row_ = wc * 64 + ((nh) * 2 + jj) * 16 + lc;             \
            _Pragma("unroll")                                                 \
            for (int kk = 0; kk < 2; ++kk)                                    \
                bfr[jj][kk] = *(const half8*)(p_ + row_ * 128 +               \
                              ((kk * 64 + (lrg << 4)) ^ rsb));                \
        }                                                                     \
    } while (0)

#define MM(mh, nh, bfr)                                                       \
    do {                                                                      \
        __builtin_amdgcn_s_setprio(1);                                        \
        _Pragma("unroll")                                                     \
        for (int ii = 0; ii < 4; ++ii)                                        \
            _Pragma("unroll")                                                 \
            for (int jj = 0; jj < 2; ++jj)                                    \
                _Pragma("unroll")                                             \
                for (int kk = 0; kk < 2; ++kk)                                \
                    acc[(mh) * 4 + ii][(nh) * 2 + jj] =                       \
                        __builtin_amdgcn_mfma_f32_16x16x32_f16(               \
                            af[ii][kk], bfr[jj][kk],                          \
                            acc[(mh) * 4 + ii][(nh) * 2 + jj], 0, 0, 0);      \
        __builtin_amdgcn_s_setprio(0);                                        \
    } while (0)

#define BAR __builtin_amdgcn_s_barrier()
#define VMW(n) asm volatile("s_waitcnt vmcnt(" #n ")" ::: "memory")

    STG(&lsA[0][0], Ab);
    STG(&lsA[0][128 * 64], Ab + (size_t)128 * DD);
    STG(&lsB[0][0], Bb);
    STG(&lsB[0][128 * 64], Bb + (size_t)128 * DD);
    STG(&lsA[1][0], Ab + 64);
    VMW(2);
    BAR;

    for (int i = 0; i < 7; ++i) {
        const int kt1 = (2 * i + 1) * 64, kt2 = kt1 + 64, kt3 = kt2 + 64;
        LDA(0, 0); LDB(0, 0, bf01);
        STG(&lsA[1][128 * 64], Ab + (size_t)128 * DD + kt1);
        BAR; MM(0, 0, bf01); BAR;
        LDB(0, 1, bf23);
        STG(&lsB[1][0], Bb + kt1);
        BAR; MM(0, 1, bf23); BAR;
        LDA(0, 1);
        STG(&lsB[1][128 * 64], Bb + (size_t)128 * DD + kt1);
        BAR; MM(1, 0, bf01); BAR;
        STG(&lsA[0][0], Ab + kt2);
        BAR; MM(1, 1, bf23);
        VMW(2); BAR;
        LDA(1, 0); LDB(1, 0, bf01);
        STG(&lsA[0][128 * 64], Ab + (size_t)128 * DD + kt2);
        BAR; MM(0, 0, bf01); BAR;
        LDB(1, 1, bf23);
        STG(&lsB[0][0], Bb + kt2);
        BAR; MM(0, 1, bf23); BAR;
        LDA(1, 1);
        STG(&lsB[0][128 * 64], Bb + (size_t)128 * DD + kt2);
        BAR; MM(1, 0, bf01); BAR;
        STG(&lsA[1][0], Ab + kt3);
        BAR; MM(1, 1, bf23);
        VMW(2); BAR;
    }
    {
        const int kt1 = 15 * 64;
        LDA(0, 0); LDB(0, 0, bf01);
        STG(&lsA[1][128 * 64], Ab + (size_t)128 * DD + kt1);
        BAR; MM(0, 0, bf01); BAR;
        LDB(0, 1, bf23);
        STG(&lsB[1][0], Bb + kt1);
        BAR; MM(0, 1, bf23); BAR;
        LDA(0, 1);
        STG(&lsB[1][128 * 64], Bb + (size_t)128 * DD + kt1);
        BAR; MM(1, 0, bf01); BAR;
        BAR; MM(1, 1, bf23);
        VMW(0); BAR;
        LDA(1, 0); LDB(1, 0, bf01);
        BAR; MM(0, 0, bf01); BAR;
        LDB(1, 1, bf23);
        BAR; MM(0, 1, bf23); BAR;
        LDA(1, 1);
        BAR; MM(1, 0, bf01); BAR;
        BAR; MM(1, 1, bf23);
    }
    __syncthreads();

    _Float16* Cb = P + (size_t)z * sP;
    float* psum = (float*)&lsA[0][0];
    #pragma unroll
    for (int i = 0; i < 8; ++i) {
        float rsum[4] = {0.f, 0.f, 0.f, 0.f};
        #pragma unroll
        for (int j = 0; j < 4; ++j) {
            const int n = n0 + wc * 64 + j * 16 + lc;
            #pragma unroll
            for (int r = 0; r < 4; ++r) {
                const int m = m0 + wr * 128 + i * 16 + lr + r;
                const float e = __expf(acc[i][j][r] * scale);
                Cb[(size_t)m * LKK + n] = (_Float16)e;
                rsum[r] += e;
            }
        }
        #pragma unroll
        for (int r = 0; r < 4; ++r) {
            float s = rsum[r];
            s += __shfl_xor(s, 1);
            s += __shfl_xor(s, 2);
            s += __shfl_xor(s, 4);
            s += __shfl_xor(s, 8);
            if (lc == 0) psum[(wr * 128 + i * 16 + lr + r) * 4 + wc] = s;
        }
    }
    __syncthreads();
    if (tid < 256) {
        const float* pr = psum + tid * 4;
        partial[((size_t)z * LQ + m0 + tid) * 8 + bx] = pr[0] + pr[1] + pr[2] + pr[3];
    }
#undef STG
#undef LDA
#undef LDB
#undef MM
}

// ===========================================================================
// 256x128 NT-GEMM for PV / cat — 4M x 2N waves, 3-buffer rolling schedule,
// counted vmcnt(6), 144KB LDS.  [proven R7 — unchanged]
// ===========================================================================
__global__ __launch_bounds__(512, 2) void gemm_pc_256x128(
    const _Float16* __restrict__ Alo, long sAlo, int lda_lo,
    const _Float16* __restrict__ Ahi, long sAhi, int lda_hi,
    int ksplit,
    const _Float16* __restrict__ B, long sB, int ldb,
    int K, int mode,
    float* __restrict__ out32, long s32, int ldc32,
    _Float16* __restrict__ out16, long s16, int ldc16,
    const float* __restrict__ bias,
    const float* __restrict__ partial, int npart)
{
    __shared__ _Float16 ls[3][384 * 64];
    const int tid = threadIdx.x;
    const int w = tid >> 6, l = tid & 63;
    const int wr = w >> 1, wc = w & 1;     // 4M x 2N
    const int lrg = l >> 4, lc = l & 15, lr = lrg << 2;

    int id = blockIdx.x + gridDim.x * (blockIdx.y + gridDim.y * blockIdx.z);
    const int nwg = gridDim.x * gridDim.y * gridDim.z;
    id = (id & 7) * (nwg >> 3) + (id >> 3);
    const int bx = id % gridDim.x;
    const int t2_ = id / gridDim.x;
    const int by = t2_ % gridDim.y;
    const int z  = t2_ / gridDim.y;
    const int m0 = by * 256, n0 = bx * 128;

    const _Float16* Abase_lo = Alo + (size_t)z * sAlo + (size_t)m0 * lda_lo;
    const _Float16* Abase_hi = Ahi ? (Ahi + (size_t)z * sAhi + (size_t)m0 * lda_hi) : (const _Float16*)0;
    const _Float16* Bbase = B + (size_t)z * sB + (size_t)n0 * ldb;

    const int srow = l >> 3;
    const int sk = ((l & 7) ^ srow) << 3;
    const int rsb = (lc & 7) << 4;

    half8 af[4][2], bf[2][2];
    f32x4 acc[4][4] = {};

#define STGA(tt, dbuf)                                                        \
    do {                                                                      \
        const int kb_ = (tt) * 64;                                            \
        const _Float16* s_; int ld_;                                          \
        if (kb_ < ksplit) { s_ = Abase_lo + kb_;           ld_ = lda_lo; }    \
        else              { s_ = Abase_hi + (kb_ - ksplit); ld_ = lda_hi; }   \
        _Float16* d_ = &ls[dbuf][0];                                          \
        _Pragma("unroll")                                                     \
        for (int rr = 0; rr < 4; ++rr) {                                      \
            const int c = w + 8 * rr;                                         \
            gl_lds16(s_ + (size_t)(c * 8 + srow) * ld_ + sk, d_ + c * 512);   \
        }                                                                     \
    } while (0)

#define STGB(tt, dbuf)                                                        \
    do {                                                                      \
        const _Float16* s_ = Bbase + (tt) * 64;                               \
        _Float16* d_ = &ls[dbuf][256 * 64];                                   \
        _Pragma("unroll")                                                     \
        for (int rr = 0; rr < 2; ++rr) {                                      \
            const int c = w + 8 * rr;                                         \
            gl_lds16(s_ + (size_t)(c * 8 + srow) * ldb + sk, d_ + c * 512);   \
        }                                                                     \
    } while (0)

#define LDA2(buf)                                                             \
    do {                                                                      \
        const char* p_ = (const char*)&ls[buf][0];                            \
        _Pragma("unroll")                                                     \
        for (int ii = 0; ii < 4; ++ii) {                                      \
            const int row_ = wr * 64 + ii * 16 + lc;                          \
            _Pragma("unroll")                                                 \
            for (int kk = 0; kk < 2; ++kk)                                    \
                af[ii][kk] = *(const half8*)(p_ + row_ * 128 +                \
                             ((kk * 64 + (lrg << 4)) ^ rsb));                 \
        }                                                                     \
    } while (0)

#define LDB2(buf, nh)                                                         \
    do {                                                                      \
        const char* p_ = (const char*)&ls[buf][256 * 64];                     \
        _Pragma("unroll")                                                     \
        for (int jj = 0; jj < 2; ++jj) {                                      \
            const int row_ = wc * 64 + ((nh) * 2 + jj) * 16 + lc;             \
            _Pragma("unroll")                                                 \
            for (int kk = 0; kk < 2; ++kk)                                    \
                bf[jj][kk] = *(const half8*)(p_ + row_ * 128 +                \
                              ((kk * 64 + (lrg << 4)) ^ rsb));                \
        }                                                                     \
    } while (0)

#define MM2(nh)                                                               \
    do {                                                                      \
        __builtin_amdgcn_s_setprio(1);                                        \
        _Pragma("unroll")                                                     \
        for (int ii = 0; ii < 4; ++ii)                                        \
            _Pragma("unroll")                                                 \
            for (int jj = 0; jj < 2; ++jj)                                    \
                _Pragma("unroll")                                             \
                for (int kk = 0; kk < 2; ++kk)                                \
                    acc[ii][(nh) * 2 + jj] =                                  \
                        __builtin_amdgcn_mfma_f32_16x16x32_f16(               \
                            af[ii][kk], bf[jj][kk],                           \
                            acc[ii][(nh) * 2 + jj], 0, 0, 0);                 \
        __builtin_amdgcn_s_setprio(0);                                        \
    } while (0)

    const int NT = K >> 6;
    STGA(0, 0); STGB(0, 0);
    STGA(1, 1); STGB(1, 1);
    VMW(6);
    BAR;

    int b = 0, b2 = 2;
    for (int t = 0; t < NT; ++t) {
        const int tt = t + 2;
        const bool st = tt < NT;
        LDA2(b); LDB2(b, 0);
        if (st) STGA(tt, b2);
        BAR; MM2(0); BAR;
        LDB2(b, 1);
        if (st) STGB(tt, b2);
        BAR; MM2(1);
        if (t < NT - 2)       VMW(6);
        else if (t == NT - 2) VMW(0);
        BAR;
        b = (b == 2) ? 0 : b + 1;
        b2 = (b2 == 2) ? 0 : b2 + 1;
    }
    __syncthreads();

    if (mode == 1) {
        float* psum = (float*)&ls[0][0];
        if (tid < 256) {
            const float* pp = partial + ((size_t)z * LQ + m0 + tid) * npart;
            float s = 0.0f;
            for (int c = 0; c < npart; ++c) s += pp[c];
            psum[tid] = 1.0f / s;
        }
        __syncthreads();
        _Float16* Cb = out16 + (size_t)z * s16;
        #pragma unroll
        for (int i = 0; i < 4; ++i)
            #pragma unroll
            for (int j = 0; j < 4; ++j) {
                const int n = n0 + wc * 64 + j * 16 + lc;
                #pragma unroll
                for (int r = 0; r < 4; ++r) {
                    const int ml = wr * 64 + i * 16 + lr + r;
                    Cb[(size_t)(m0 + ml) * ldc16 + n] =
                        (_Float16)(acc[i][j][r] * psum[ml]);
                }
            }
    } else {
        float bv[4];
        #pragma unroll
        for (int j = 0; j < 4; ++j)
            bv[j] = bias[n0 + wc * 64 + j * 16 + lc];
        #pragma unroll
        for (int i = 0; i < 4; ++i)
            #pragma unroll
            for (int j = 0; j < 4; ++j) {
                const int n = n0 + wc * 64 + j * 16 + lc;
                #pragma unroll
                for (int r = 0; r < 4; ++r) {
                    const int m = m0 + wr * 64 + i * 16 + lr + r;
                    const float t = tanhf(acc[i][j][r] + bv[j]);
                    if (out16) out16[(size_t)z * s16 + (size_t)m * ldc16 + n] = (_Float16)t;
                    if (out32) out32[(size_t)z * s32 + (size_t)m * ldc32 + n] = t;
                }
            }
    }
#undef STGA
#undef STGB
#undef LDA2
#undef LDB2
#undef MM2
#undef BAR
#undef VMW
}

// ---------------------------------------------------------------------------
// f16 MFMA NT-GEMM 128x128 (R3-fallback path only)
// ---------------------------------------------------------------------------
__global__ __launch_bounds__(256) void gemm_f16_nt(
    const _Float16* __restrict__ Alo, long sAlo, int lda_lo,
    const _Float16* __restrict__ Ahi, long sAhi, int lda_hi,
    int ksplit,
    const _Float16* __restrict__ B, long sB, int ldb,
    int K, int mode, float scale,
    float* __restrict__ out32, long s32, int ldc32,
    _Float16* __restrict__ out16, long s16, int ldc16,
    const float* __restrict__ bias,
    float* __restrict__ partial, const float* __restrict__ inv, int npart)
{
    __shared__ _Float16 lsA[128 * 64];
    __shared__ _Float16 lsB[128 * 64];
    __shared__ float psum[128][2];
    const int tid = threadIdx.x;
    const int w = tid >> 6, l = tid & 63;
    const int wr = w >> 1, wc = w & 1;

    int id = blockIdx.x + gridDim.x * (blockIdx.y + gridDim.y * blockIdx.z);
    const int nwg = gridDim.x * gridDim.y * gridDim.z;
    id = (id & 7) * (nwg >> 3) + (id >> 3);
    const int bx = id % gridDim.x;
    const int t2 = id / gridDim.x;
    const int by = t2 % gridDim.y;
    const int z = t2 / gridDim.y;
    const int m0 = by * 128, n0 = bx * 128;

    const _Float16* Abase_lo = Alo + (size_t)z * sAlo + (size_t)m0 * lda_lo;
    const _Float16* Abase_hi = Ahi ? (Ahi + (size_t)z * sAhi + (size_t)m0 * lda_hi) : (const _Float16*)0;
    const _Float16* Bbase = B + (size_t)z * sB + (size_t)n0 * ldb;

    const int srow = l >> 3;
    const int sswz = ((l & 7) ^ srow) << 3;

    f32x4 acc[4][4] = {};

    for (int k0 = 0; k0 < K; k0 += 64) {
        const _Float16* Ap; int kloc, ldaA;
        if (k0 < ksplit) { Ap = Abase_lo; kloc = k0;          ldaA = lda_lo; }
        else             { Ap = Abase_hi; kloc = k0 - ksplit; ldaA = lda_hi; }
        #pragma unroll
        for (int i = 0; i < 4; ++i) {
            const int c = w * 4 + i;
            const int row = c * 8 + srow;
            gl_lds16(Ap + (size_t)row * ldaA + kloc + sswz, &lsA[c * 512]);
        }
        #pragma unroll
        for (int i = 0; i < 4; ++i) {
            const int c = w * 4 + i;
            const int row = c * 8 + srow;
            gl_lds16(Bbase + (size_t)row * ldb + k0 + sswz, &lsB[c * 512]);
        }
        __syncthreads();

        half8 af[4][2], bf[4][2];
        const char* lA = (const char*)lsA;
        const char* lB = (const char*)lsB;
        const int rs = (l & 7) << 4;
        const int cb = (l >> 4) << 4;
        #pragma unroll
        for (int i = 0; i < 4; ++i) {
            const int rowa = wr * 64 + i * 16 + (l & 15);
            const int rowb = wc * 64 + i * 16 + (l & 15);
            #pragma unroll
            for (int kk = 0; kk < 2; ++kk) {
                af[i][kk] = *(const half8*)(lA + rowa * 128 + ((kk * 64 + cb) ^ rs));
                bf[i][kk] = *(const half8*)(lB + rowb * 128 + ((kk * 64 + cb) ^ rs));
            }
        }
        #pragma unroll
        for (int kk = 0; kk < 2; ++kk)
            #pragma unroll
            for (int i = 0; i < 4; ++i)
                #pragma unroll
                for (int j = 0; j < 4; ++j)
                    acc[i][j] = __builtin_amdgcn_mfma_f32_16x16x32_f16(
                        af[i][kk], bf[j][kk], acc[i][j], 0, 0, 0);
        __syncthreads();
    }

    const int lr = (l >> 4) * 4;
    const int lc = l & 15;
    if (mode == 0) {
        _Float16* Cb = out16 + (size_t)z * s16;
        float rsum[4][4];
        #pragma unroll
        for (int i = 0; i < 4; ++i)
            #pragma unroll
            for (int r = 0; r < 4; ++r) rsum[i][r] = 0.0f;
        #pragma unroll
        for (int i = 0; i < 4; ++i)
            #pragma unroll
            for (int j = 0; j < 4; ++j) {
                const int n = n0 + wc * 64 + j * 16 + lc;
                #pragma unroll
                for (int r = 0; r < 4; ++r) {
                    const int m = m0 + wr * 64 + i * 16 + lr + r;
                    const float e = __expf(acc[i][j][r] * scale);
                    Cb[(size_t)m * ldc16 + n] = (_Float16)e;
                    rsum[i][r] += e;
                }
            }
        #pragma unroll
        for (int i = 0; i < 4; ++i)
            #pragma unroll
            for (int r = 0; r < 4; ++r) {
                float s = rsum[i][r];
                s += __shfl_xor(s, 1);
                s += __shfl_xor(s, 2);
                s += __shfl_xor(s, 4);
                s += __shfl_xor(s, 8);
                rsum[i][r] = s;
            }
        if (lc == 0) {
            #pragma unroll
            for (int i = 0; i < 4; ++i)
                #pragma unroll
                for (int r = 0; r < 4; ++r)
                    psum[wr * 64 + i * 16 + lr + r][wc] = rsum[i][r];
        }
        __syncthreads();
        if (tid < 128)
            partial[((size_t)z * LQ + m0 + tid) * npart + bx] = psum[tid][0] + psum[tid][1];
    } else if (mode == 1) {
        _Float16* Cb = out16 + (size_t)z * s16;
        float iv[4][4];
        if (partial) {
            if (tid < 128) {
                const float* pp = partial + ((size_t)z * LQ + m0 + tid) * npart;
                float s = 0.0f;
                for (int c = 0; c < npart; ++c) s += pp[c];
                psum[tid][0] = 1.0f / s;
            }
            __syncthreads();
            #pragma unroll
            for (int i = 0; i < 4; ++i)
                #pragma unroll
                for (int r = 0; r < 4; ++r)
                    iv[i][r] = psum[wr * 64 + i * 16 + lr + r][0];
        } else {
            #pragma unroll
            for (int i = 0; i < 4; ++i)
                #pragma unroll
                for (int r = 0; r < 4; ++r)
                    iv[i][r] = inv ? inv[(size_t)z * LQ + m0 + wr * 64 + i * 16 + lr + r] : 1.0f;
        }
        #pragma unroll
        for (int i = 0; i < 4; ++i)
            #pragma unroll
            for (int j = 0; j < 4; ++j) {
                const int n = n0 + wc * 64 + j * 16 + lc;
                #pragma unroll
                for (int r = 0; r < 4; ++r) {
                    const int m = m0 + wr * 64 + i * 16 + lr + r;
                    Cb[(size_t)m * ldc16 + n] = (_Float16)(acc[i][j][r] * iv[i][r]);
                }
            }
    } else if (mode == 4) {
        float* Cb = out32 + (size_t)z * s32;
        #pragma unroll
        for (int i = 0; i < 4; ++i)
            #pragma unroll
            for (int j = 0; j < 4; ++j) {
                const int n = n0 + wc * 64 + j * 16 + lc;
                #pragma unroll
                for (int r = 0; r < 4; ++r) {
                    const int m = m0 + wr * 64 + i * 16 + lr + r;
                    Cb[(size_t)m * ldc32 + n] = acc[i][j][r] * scale;
                }
            }
    } else {
        float bv[4];
        #pragma unroll
        for (int j = 0; j < 4; ++j)
            bv[j] = bias[n0 + wc * 64 + j * 16 + lc];
        #pragma unroll
        for (int i = 0; i < 4; ++i)
            #pragma unroll
            for (int j = 0; j < 4; ++j) {
                const int n = n0 + wc * 64 + j * 16 + lc;
                #pragma unroll
                for (int r = 0; r < 4; ++r) {
                    const int m = m0 + wr * 64 + i * 16 + lr + r;
                    const float t = tanhf(acc[i][j][r] + bv[j]);
                    if (out16) out16[(size_t)z * s16 + (size_t)m * ldc16 + n] = (_Float16)t;
                    if (out32) out32[(size_t)z * s32 + (size_t)m * ldc32 + n] = t;
                }
            }
    }
}

// one block per row: attn_f32[row,:] = P16[row,:] * (1/sum partial[row,0..npart))
__global__ __launch_bounds__(256) void scale_attn(
    const _Float16* __restrict__ P, const float* __restrict__ partial,
    float* __restrict__ attn, int npart)
{
    __shared__ float sinv;
    const long row = blockIdx.x;
    const int tid = threadIdx.x;
    if (tid < npart) {
        float s = partial[row * npart + tid];
        for (int off = npart >> 1; off > 0; off >>= 1) s += __shfl_xor(s, off);
        if (tid == 0) sinv = 1.0f / s;
    }
    __syncthreads();
    const float inv = sinv;
    const half8 h = *(const half8*)(P + row * 2048 + tid * 8);
    float* o = attn + row * 2048 + tid * 8;
    float4 a = make_float4((float)h[0] * inv, (float)h[1] * inv,
                           (float)h[2] * inv, (float)h[3] * inv);
    float4 b = make_float4((float)h[4] * inv, (float)h[5] * inv,
                           (float)h[6] * inv, (float)h[7] * inv);
    *(float4*)o = a;
    *(float4*)(o + 4) = b;
}

// inv[row] = 1 / sum_{cb<16} partial[row*16+cb]   (R3-fallback path)
__global__ __launch_bounds__(256) void make_inv(
    const float* __restrict__ partial, float* __restrict__ inv)
{
    const int row = blockIdx.x * 256 + threadIdx.x;
    const float4 a = *(const float4*)(partial + (size_t)row * 16);
    const float4 b = *(const float4*)(partial + (size_t)row * 16 + 4);
    const float4 c = *(const float4*)(partial + (size_t)row * 16 + 8);
    const float4 d = *(const float4*)(partial + (size_t)row * 16 + 12);
    const float s = (a.x + a.y + a.z + a.w) + (b.x + b.y + b.z + b.w)
                  + (c.x + c.y + c.z + c.w) + (d.x + d.y + d.z + d.w);
    inv[row] = 1.0f / s;
}

// row softmax over 2048 f32 (R3-fallback hop 2)
__global__ __launch_bounds__(256) void softmax_rows2(
    float* __restrict__ S, _Float16* __restrict__ f16out,
    long f16stride, int write_f32)
{
    __shared__ float red[8];
    const long row = blockIdx.x;
    float* p = S + row * LKK;
    const int tid = threadIdx.x;
    float4 v0 = ((const float4*)p)[tid];
    float4 v1 = ((const float4*)p)[tid + 256];
    float m = fmaxf(fmaxf(fmaxf(v0.x, v0.y), fmaxf(v0.z, v0.w)),
                    fmaxf(fmaxf(v1.x, v1.y), fmaxf(v1.z, v1.w)));
    #pragma unroll
    for (int off = 32; off > 0; off >>= 1) m = fmaxf(m, __shfl_down(m, off));
    if ((tid & 63) == 0) red[tid >> 6] = m;
    __syncthreads();
    m = fmaxf(fmaxf(red[0], red[1]), fmaxf(red[2], red[3]));
    v0.x = expf(v0.x - m); v0.y = expf(v0.y - m);
    v0.z = expf(v0.z - m); v0.w = expf(v0.w - m);
    v1.x = expf(v1.x - m); v1.y = expf(v1.y - m);
    v1.z = expf(v1.z - m); v1.w = expf(v1.w - m);
    float s = v0.x + v0.y + v0.z + v0.w + v1.x + v1.y + v1.z + v1.w;
    #pragma unroll
    for (int off = 32; off > 0; off >>= 1) s += __shfl_down(s, off);
    if ((tid & 63) == 0) red[4 + (tid >> 6)] = s;
    __syncthreads();
    s = red[4] + red[5] + red[6] + red[7];
    const float inv = 1.0f / s;
    v0.x *= inv; v0.y *= inv; v0.z *= inv; v0.w *= inv;
    v1.x *= inv; v1.y *= inv; v1.z *= inv; v1.w *= inv;
    if (write_f32) {
        ((float4*)p)[tid] = v0;
        ((float4*)p)[tid + 256] = v1;
    }
    _Float16* q = f16out + row * f16stride;
    half4 h0 = { (_Float16)v0.x, (_Float16)v0.y, (_Float16)v0.z, (_Float16)v0.w };
    half4 h1 = { (_Float16)v1.x, (_Float16)v1.y, (_Float16)v1.z, (_Float16)v1.w };
    *(half4*)(q + tid * 4) = h0;
    *(half4*)(q + 1024 + tid * 4) = h1;
}

__global__ __launch_bounds__(256) void cvt_f32_to_f16(
    const float* __restrict__ in, _Float16* __restrict__ out, long n)
{
    const long i = ((long)blockIdx.x * 256 + threadIdx.x) * 8;
    if (i + 8 > n) return;
    float4 a = *(const float4*)(in + i);
    float4 b = *(const float4*)(in + i + 4);
    half8 h = { (_Float16)a.x, (_Float16)a.y, (_Float16)a.z, (_Float16)a.w,
                (_Float16)b.x, (_Float16)b.y, (_Float16)b.z, (_Float16)b.w };
    *(half8*)(out + i) = h;
}

// V [B, Lk, D] f32 -> Vt [B, D, Lk] f16, 64x64 tiles via LDS
__global__ __launch_bounds__(256) void transpose_cvt_v(
    const float* __restrict__ V, _Float16* __restrict__ Vt)
{
    __shared__ _Float16 t[64][80];
    const int z = blockIdx.z;
    const int k0 = blockIdx.y * 64, d0 = blockIdx.x * 64;
    const float* Vb = V + (size_t)z * LKK * DD;
    _Float16* Vtb = Vt + (size_t)z * DD * LKK;
    const int r = threadIdx.x >> 2;
    const int c0 = (threadIdx.x & 3) * 16;
    #pragma unroll
    for (int j = 0; j < 4; ++j) {
        float4 v = *(const float4*)(Vb + (size_t)(k0 + r) * DD + d0 + c0 + j * 4);
        t[c0 + j * 4 + 0][r] = (_Float16)v.x;
        t[c0 + j * 4 + 1][r] = (_Float16)v.y;
        t[c0 + j * 4 + 2][r] = (_Float16)v.z;
        t[c0 + j * 4 + 3][r] = (_Float16)v.w;
    }
    __syncthreads();
    #pragma unroll
    for (int j = 0; j < 2; ++j) {
        half8 h = *(const half8*)&t[r][c0 + j * 8];
        *(half8*)(Vtb + (size_t)(d0 + r) * LKK + k0 + c0 + j * 8) = h;
    }
}

// ======================= round-1 f32 fallback kernels =======================
constexpr int TM = 64, TN = 64, TK = 32;
constexpr int PAD = 4;

__global__ __launch_bounds__(256) void gemm_nt_k(
    const float* __restrict__ A, int lda, long sA,
    const float* __restrict__ Bt, int ldb, long sB,
    float* __restrict__ C, int ldc, long sC, int K, float scale)
{
    __shared__ float As[TK][TM + PAD];
    __shared__ float Bs[TK][TN + PAD];
    const float* Ab = A + (long)blockIdx.z * sA;
    const float* Bb = Bt + (long)blockIdx.z * sB;
    float* Cb = C + (long)blockIdx.z * sC;
    const int m0 = blockIdx.y * TM, n0 = blockIdx.x * TN;
    const int tid = threadIdx.x;
    const int tn = tid & 15, tm = tid >> 4;
    float acc[4][4] = {};
    for (int k0 = 0; k0 < K; k0 += TK) {
        #pragma unroll
        for (int c = tid; c < (TM * TK) / 4; c += 256) {
            const int row = c >> 3, kc = (c & 7) << 2;
            const float4 g = *(const float4*)(Ab + (long)(m0 + row) * lda + (k0 + kc));
            As[kc + 0][row] = g.x; As[kc + 1][row] = g.y;
            As[kc + 2][row] = g.z; As[kc + 3][row] = g.w;
        }
        #pragma unroll
        for (int c = tid; c < (TN * TK) / 4; c += 256) {
            const int row = c >> 3, kc = (c & 7) << 2;
            const float4 g = *(const float4*)(Bb + (long)(n0 + row) * ldb + (k0 + kc));
            Bs[kc + 0][row] = g.x; Bs[kc + 1][row] = g.y;
            Bs[kc + 2][row] = g.z; Bs[kc + 3][row] = g.w;
        }
        __syncthreads();
        #pragma unroll
        for (int kk = 0; kk < TK; ++kk) {
            const float4 av = *(const float4*)&As[kk][tm << 2];
            const float4 bv = *(const float4*)&Bs[kk][tn << 2];
            const float a[4] = {av.x, av.y, av.z, av.w};
            const float b[4] = {bv.x, bv.y, bv.z, bv.w};
            #pragma unroll
            for (int i = 0; i < 4; ++i)
                #pragma unroll
                for (int j = 0; j < 4; ++j)
                    acc[i][j] = fmaf(a[i], b[j], acc[i][j]);
        }
        __syncthreads();
    }
    #pragma unroll
    for (int i = 0; i < 4; ++i) {
        float4 o = make_float4(acc[i][0] * scale, acc[i][1] * scale,
                               acc[i][2] * scale, acc[i][3] * scale);
        *(float4*)(Cb + (long)(m0 + (tm << 2) + i) * ldc + n0 + (tn << 2)) = o;
    }
}

__global__ __launch_bounds__(256) void gemm_nn_k(
    const float* __restrict__ A, int lda, long sA,
    const float* __restrict__ B, int ldb, long sB,
    float* __restrict__ C, int ldc, long sC, int K)
{
    __shared__ float As[TK][TM + PAD];
    __shared__ float Bs[TK][TN + PAD];
    const float* Ab = A + (long)blockIdx.z * sA;
    const float* Bb = B + (long)blockIdx.z * sB;
    float* Cb = C + (long)blockIdx.z * sC;
    const int m0 = blockIdx.y * TM, n0 = blockIdx.x * TN;
    const int tid = threadIdx.x;
    const int tn = tid & 15, tm = tid >> 4;
    float acc[4][4] = {};
    for (int k0 = 0; k0 < K; k0 += TK) {
        #pragma unroll
        for (int c = tid; c < (TM * TK) / 4; c += 256) {
            const int row = c >> 3, kc = (c & 7) << 2;
            const float4 g = *(const float4*)(Ab + (long)(m0 + row) * lda + (k0 + kc));
            As[kc + 0][row] = g.x; As[kc + 1][row] = g.y;
            As[kc + 2][row] = g.z; As[kc + 3][row] = g.w;
        }
        #pragma unroll
        for (int c = tid; c < (TK * TN) / 4; c += 256) {
            const int krow = c >> 4, nc = (c & 15) << 2;
            *(float4*)&Bs[krow][nc] =
                *(const float4*)(Bb + (long)(k0 + krow) * ldb + n0 + nc);
        }
        __syncthreads();
        #pragma unroll
        for (int kk = 0; kk < TK; ++kk) {
            const float4 av = *(const float4*)&As[kk][tm << 2];
            const float4 bv = *(const float4*)&Bs[kk][tn << 2];
            const float a[4] = {av.x, av.y, av.z, av.w};
            const float b[4] = {bv.x, bv.y, bv.z, bv.w};
            #pragma unroll
            for (int i = 0; i < 4; ++i)
                #pragma unroll
                for (int j = 0; j < 4; ++j)
                    acc[i][j] = fmaf(a[i], b[j], acc[i][j]);
        }
        __syncthreads();
    }
    #pragma unroll
    for (int i = 0; i < 4; ++i) {
        float4 o = make_float4(acc[i][0], acc[i][1], acc[i][2], acc[i][3]);
        *(float4*)(Cb + (long)(m0 + (tm << 2) + i) * ldc + n0 + (tn << 2)) = o;
    }
}

__global__ __launch_bounds__(256) void gemm_cat_k(
    const float* __restrict__ Qh, const float* __restrict__ R,
    const float* __restrict__ W, const float* __restrict__ bias,
    float* __restrict__ C)
{
    __shared__ float As[TK][TM + PAD];
    __shared__ float Bs[TK][TN + PAD];
    const float* Qb = Qh + (long)blockIdx.z * LQ * DD;
    const float* Rb = R + (long)blockIdx.z * LQ * DD;
    float* Cb = C + (long)blockIdx.z * LQ * DD;
    const int m0 = blockIdx.y * TM, n0 = blockIdx.x * TN;
    const int tid = threadIdx.x;
    const int tn = tid & 15, tm = tid >> 4;
    float acc[4][4] = {};
    for (int k0 = 0; k0 < 2 * DD; k0 += TK) {
        const float* src = (k0 < DD) ? Qb : Rb;
        const int kb = (k0 < DD) ? k0 : k0 - DD;
        #pragma unroll
        for (int c = tid; c < (TM * TK) / 4; c += 256) {
            const int row = c >> 3, kc = (c & 7) << 2;
            const float4 g = *(const float4*)(src + (long)(m0 + row) * DD + (kb + kc));
            As[kc + 0][row] = g.x; As[kc + 1][row] = g.y;
            As[kc + 2][row] = g.z; As[kc + 3][row] = g.w;
        }
        #pragma unroll
        for (int c = tid; c < (TN * TK) / 4; c += 256) {
            const int row = c >> 3, kc = (c & 7) << 2;
            const float4 g = *(const float4*)(W + (long)(n0 + row) * (2 * DD) + (k0 + kc));
            Bs[kc + 0][row] = g.x; Bs[kc + 1][row] = g.y;
            Bs[kc + 2][row] = g.z; Bs[kc + 3][row] = g.w;
        }
        __syncthreads();
        #pragma unroll
        for (int kk = 0; kk < TK; ++kk) {
            const float4 av = *(const float4*)&As[kk][tm << 2];
            const float4 bv = *(const float4*)&Bs[kk][tn << 2];
            const float a[4] = {av.x, av.y, av.z, av.w};
            const float b[4] = {bv.x, bv.y, bv.z, bv.w};
            #pragma unroll
            for (int i = 0; i < 4; ++i)
                #pragma unroll
                for (int j = 0; j < 4; ++j)
                    acc[i][j] = fmaf(a[i], b[j], acc[i][j]);
        }
        __syncthreads();
    }
    #pragma unroll
    for (int i = 0; i < 4; ++i) {
        float4 o;
        o.x = tanhf(acc[i][0] + bias[n0 + (tn << 2) + 0]);
        o.y = tanhf(acc[i][1] + bias[n0 + (tn << 2) + 1]);
        o.z = tanhf(acc[i][2] + bias[n0 + (tn << 2) + 2]);
        o.w = tanhf(acc[i][3] + bias[n0 + (tn << 2) + 3]);
        *(float4*)(Cb + (long)(m0 + (tm << 2) + i) * DD + n0 + (tn << 2)) = o;
    }
}

__global__ __launch_bounds__(256) void softmax_rows(float* __restrict__ S) {
    __shared__ float red[8];
    float* p = S + (size_t)blockIdx.x * LKK;
    const int tid = threadIdx.x;
    float4 v0 = ((const float4*)p)[tid];
    float4 v1 = ((const float4*)p)[tid + 256];
    float m = fmaxf(fmaxf(fmaxf(v0.x, v0.y), fmaxf(v0.z, v0.w)),
                    fmaxf(fmaxf(v1.x, v1.y), fmaxf(v1.z, v1.w)));
    #pragma unroll
    for (int off = 32; off > 0; off >>= 1) m = fmaxf(m, __shfl_down(m, off));
    if ((tid & 63) == 0) red[tid >> 6] = m;
    __syncthreads();
    m = fmaxf(fmaxf(red[0], red[1]), fmaxf(red[2], red[3]));
    v0.x = expf(v0.x - m); v0.y = expf(v0.y - m);
    v0.z = expf(v0.z - m); v0.w = expf(v0.w - m);
    v1.x = expf(v1.x - m); v1.y = expf(v1.y - m);
    v1.z = expf(v1.z - m); v1.w = expf(v1.w - m);
    float s = v0.x + v0.y + v0.z + v0.w + v1.x + v1.y + v1.z + v1.w;
    #pragma unroll
    for (int off = 32; off > 0; off >>= 1) s += __shfl_down(s, off);
    if ((tid & 63) == 0) red[4 + (tid >> 6)] = s;
    __syncthreads();
    s = red[4] + red[5] + red[6] + red[7];
    const float inv = 1.0f / s;
    v0.x *= inv; v0.y *= inv; v0.z *= inv; v0.w *= inv;
    v1.x *= inv; v1.y *= inv; v1.z *= inv; v1.w *= inv;
    ((float4*)p)[tid] = v0;
    ((float4*)p)[tid + 256] = v1;
}

// ===========================================================================
extern "C" void kernel_launch(void* const* d_in, const int* in_sizes, int n_in,
                              void* d_out, int out_size, void* d_ws, size_t ws_size,
                              hipStream_t stream) {
    const float* Q    = (const float*)d_in[0];
    const float* Km   = (const float*)d_in[1];
    const float* V    = (const float*)d_in[2];
    const float* W    = (const float*)d_in[3];
    const float* bias = (const float*)d_in[4];
    const float scale = 0.03125f;  // 1/sqrt(1024)
    dim3 blk(256);

    const size_t NEED_FULL = 189267968ULL;
    const size_t NEED_R3   = 155189248ULL;

    if (ws_size >= NEED_FULL) {
        char* ws = (char*)d_ws;
        _Float16* Kh     = (_Float16*)ws;                    // [16,2048,1024]
        _Float16* Vt     = (_Float16*)(ws + 67108864);       // [16,1024,2048]
        _Float16* Wh     = (_Float16*)(ws + 134217728);      // [1024,2048]
        _Float16* Rh     = (_Float16*)(ws + 138412032);      // [16,512,1024]
        _Float16* Qping  = (_Float16*)(ws + 155189248);      // [16,512,1024]
        _Float16* Qpong  = (_Float16*)(ws + 171966464);      // [16,512,1024]
        float*    partialB = (float*)(ws + 188743680);       // [8192,8]

        float*    outQ  = (float*)d_out;
        _Float16* P2    = (_Float16*)d_out;
        float*    attnF = (float*)((char*)d_out + 33554432);
        _Float16* P01   = (_Float16*)attnF;

        // prep: three exact-grid cvt kernels (proven R6) + V transpose
        cvt_f32_to_f16<<<4096, blk, 0, stream>>>(Q, Qping, (long)NB * LQ * DD);
        cvt_f32_to_f16<<<16384, blk, 0, stream>>>(Km, Kh, (long)NB * LKK * DD);
        cvt_f32_to_f16<<<1024, blk, 0, stream>>>(W, Wh, (long)DD * 2 * DD);
        transpose_cvt_v<<<dim3(DD / 64, LKK / 64, NB), blk, 0, stream>>>(V, Vt);

        dim3 gS2(LKK / 256, LQ / 256, NB);  // 8 x 2 x 16 = 256 blocks
        dim3 gP(DD / 128, LQ / 256, NB);    // 8 x 2 x 16 = 256 blocks

        for (int h = 0; h < 3; ++h) {
            _Float16* qcur = (h == 1) ? Qpong : Qping;
            _Float16* P    = (h == 2) ? P2 : P01;

            gemm_qk_256<<<gS2, dim3(512), 0, stream>>>(
                qcur, (long)LQ * DD, Kh, (long)LKK * DD,
                P, (long)LQ * LKK, partialB, scale);
            if (h == 2)
                scale_attn<<<NB * LQ, blk, 0, stream>>>(P2, partialB, attnF, 8);
            gemm_pc_256x128<<<gP, dim3(512), 0, stream>>>(
                P, (long)LQ * LKK, LKK,
                (const _Float16*)0, 0, 0, LKK * 16,   // ksplit > K: lo only
                Vt, (long)DD * LKK, LKK,
                LKK, 1,
                (float*)0, 0, 0,
                Rh, (long)LQ * DD, DD,
                (const float*)0, partialB, 8);
            _Float16* qn = (h == 0) ? Qpong : (h == 1) ? Qping : (_Float16*)0;
            float* fo = (h == 2) ? outQ : (float*)0;
            gemm_pc_256x128<<<gP, dim3(512), 0, stream>>>(
                qcur, (long)LQ * DD, DD,
                Rh, (long)LQ * DD, DD, DD,            // ksplit = 1024
                Wh, 0, 2 * DD,
                2 * DD, 2,
                fo, (long)LQ * DD, DD,
                qn, (long)LQ * DD, DD,
                bias, (const float*)0, 0);
        }
    } else if (ws_size >= NEED_R3) {
        // -------- proven R3 path --------
        char* ws = (char*)d_ws;
        _Float16* Kh  = (_Float16*)ws;
        _Float16* Vt  = (_Float16*)(ws + 67108864);
        _Float16* Wh  = (_Float16*)(ws + 134217728);
        _Float16* Rh  = (_Float16*)(ws + 138412032);
        _Float16* attn2 = (_Float16*)ws;
        float* Fout = (float*)(ws + 33554432);

        _Float16* Qping = (_Float16*)d_out;
        _Float16* Qpong = Qping + (size_t)NB * LQ * DD;
        float* S = (float*)((char*)d_out + 33554432);
        _Float16* P = (_Float16*)S;
        float* partialB = (float*)((char*)d_out + 73400320);
        float* invB     = (float*)((char*)d_out + 73924608);

        cvt_f32_to_f16<<<4096, blk, 0, stream>>>(Q, Qping, (long)NB * LQ * DD);
        cvt_f32_to_f16<<<16384, blk, 0, stream>>>(Km, Kh, (long)NB * LKK * DD);
        cvt_f32_to_f16<<<1024, blk, 0, stream>>>(W, Wh, (long)DD * 2 * DD);
        transpose_cvt_v<<<dim3(DD / 64, LKK / 64, NB), blk, 0, stream>>>(V, Vt);

        dim3 gS(LKK / 128, LQ / 128, NB);
        dim3 gR(DD / 128, LQ / 128, NB);

        for (int h = 0; h < 3; ++h) {
            _Float16* qcur = (h == 1) ? Qpong : Qping;
            if (h < 2) {
                gemm_f16_nt<<<gS, blk, 0, stream>>>(
                    qcur, (long)LQ * DD, DD, (const _Float16*)0, 0, 0, DD,
                    Kh, (long)LKK * DD, DD, DD,
                    0, scale, (float*)0, 0, 0,
                    P, (long)LQ * LKK, LKK, (const float*)0,
                    partialB, (const float*)0, 16);
                make_inv<<<32, blk, 0, stream>>>(partialB, invB);
                gemm_f16_nt<<<gR, blk, 0, stream>>>(
                    P, (long)LQ * LKK, LKK,
                    (const _Float16*)0, 0, 0, LKK,
                    Vt, (long)DD * LKK, LKK, LKK,
                    1, 1.0f, (float*)0, 0, 0,
                    Rh, (long)LQ * DD, DD, (const float*)0,
                    (float*)0, invB, 0);
            } else {
                gemm_f16_nt<<<gS, blk, 0, stream>>>(
                    qcur, (long)LQ * DD, DD, (const _Float16*)0, 0, 0, DD,
                    Kh, (long)LKK * DD, DD, DD,
                    4, scale, S, (long)LQ * LKK, LKK,
                    (_Float16*)0, 0, 0, (const float*)0,
                    (float*)0, (const float*)0, 0);
                softmax_rows2<<<NB * LQ, blk, 0, stream>>>(S, attn2, 2048L, 1);
                gemm_f16_nt<<<gR, blk, 0, stream>>>(
                    attn2, (long)LQ * LKK, LKK,
                    (const _Float16*)0, 0, 0, LKK,
                    Vt, (long)DD * LKK, LKK, LKK,
                    1, 1.0f, (float*)0, 0, 0,
                    Rh, (long)LQ * DD, DD, (const float*)0,
                    (float*)0, (const float*)0, 0);
            }
            _Float16* qn = (h == 0) ? Qpong : (h == 1) ? Qping : (_Float16*)0;
            float* fo = (h == 2) ? Fout : (float*)0;
            gemm_f16_nt<<<gR, blk, 0, stream>>>(
                qcur, (long)LQ * DD, DD,
                Rh, (long)LQ * DD, DD, DD,
                Wh, 0, 2 * DD, 2 * DD,
                2, 1.0f, fo, (long)LQ * DD, DD,
                qn, (long)LQ * DD, DD, bias,
                (float*)0, (const float*)0, 0);
        }
        hipMemcpyAsync(d_out, Fout, 33554432ULL, hipMemcpyDeviceToDevice, stream);
    } else {
        // -------- round-1 f32 fallback --------
        float* outQ = (float*)d_out;
        float* S    = outQ + (size_t)NB * LQ * DD;
        float* R    = (float*)d_ws;
        float* T    = R + (size_t)NB * LQ * DD;
        dim3 gS(LKK / TN, LQ / TM, NB);
        dim3 gR(DD / TN, LQ / TM, NB);
        for (int h = 0; h < 3; ++h) {
            const float* Qh = (h == 0) ? Q : (h == 1 ? (const float*)T : (const float*)outQ);
            float* cout = (h == 1) ? outQ : T;
            gemm_nt_k<<<gS, blk, 0, stream>>>(Qh, DD, (long)LQ * DD, Km, DD, (long)LKK * DD,
                                              S, LKK, (long)LQ * LKK, DD, scale);
            softmax_rows<<<NB * LQ, blk, 0, stream>>>(S);
            gemm_nn_k<<<gR, blk, 0, stream>>>(S, LKK, (long)LQ * LKK, V, DD, (long)LKK * DD,
                                              R, DD, (long)LQ * DD, LKK);
            gemm_cat_k<<<gR, blk, 0, stream>>>(Qh, R, W, bias, cout);
        }
        hipMemcpyAsync(outQ, T, (size_t)NB * LQ * DD * sizeof(float),
                       hipMemcpyDeviceToDevice, stream);
    }
}

// Round 9
// 486.087 us; speedup vs baseline: 9.1128x; 1.0131x over previous
//
#include <hip/hip_runtime.h>
#include <math.h>

#define NB 16
#define LQ 512
#define LKK 2048
#define DD 1024

typedef _Float16 half8 __attribute__((ext_vector_type(8)));
typedef _Float16 half4 __attribute__((ext_vector_type(4)));
typedef float f32x4 __attribute__((ext_vector_type(4)));

__device__ __forceinline__ void gl_lds16(const void* g, void* l) {
    __builtin_amdgcn_global_load_lds(
        (const __attribute__((address_space(1))) void*)g,
        (__attribute__((address_space(3))) void*)l, 16, 0, 0);
}

// ===========================================================================
// 8-phase 256x256 NT-GEMM for QK^T  [proven R5/R6 — unchanged]
// ===========================================================================
__global__ __launch_bounds__(512, 2) void gemm_qk_256(
    const _Float16* __restrict__ A, long sA,
    const _Float16* __restrict__ B, long sB,
    _Float16* __restrict__ P, long sP,
    float* __restrict__ partial,
    float scale)
{
    __shared__ _Float16 lsA[2][256 * 64];
    __shared__ _Float16 lsB[2][256 * 64];
    const int tid = threadIdx.x;
    const int w = tid >> 6, l = tid & 63;
    const int wr = w >> 2, wc = w & 3;
    const int lrg = l >> 4, lc = l & 15, lr = lrg << 2;

    int id = blockIdx.x + gridDim.x * (blockIdx.y + gridDim.y * blockIdx.z);
    const int nwg = gridDim.x * gridDim.y * gridDim.z;
    id = (id & 7) * (nwg >> 3) + (id >> 3);
    const int bx = id % gridDim.x;
    const int t2 = id / gridDim.x;
    const int by = t2 % gridDim.y;
    const int z  = t2 / gridDim.y;
    const int m0 = by * 256, n0 = bx * 256;

    const _Float16* Ab = A + (size_t)z * sA + (size_t)m0 * DD;
    const _Float16* Bb = B + (size_t)z * sB + (size_t)n0 * DD;

    const int srow = l >> 3;
    const int sk = ((l & 7) ^ srow) << 3;

#define STG(dst, srcbase)                                                     \
    do {                                                                      \
        _Pragma("unroll")                                                     \
        for (int rr = 0; rr < 2; ++rr) {                                      \
            const int c = w + 8 * rr;                                         \
            gl_lds16((srcbase) + (size_t)(c * 8 + srow) * DD + sk,            \
                     (dst) + c * 512);                                        \
        }                                                                     \
    } while (0)

    half8 af[4][2], bf01[2][2], bf23[2][2];
    f32x4 acc[8][4] = {};
    const int rsb = (lc & 7) << 4;

#define LDA(buf, mh)                                                          \
    do {                                                                      \
        const char* p_ = (const char*)lsA[buf];                               \
        _Pragma("unroll")                                                     \
        for (int ii = 0; ii < 4; ++ii) {                                      \
            const int row_ = wr * 128 + (mh) * 64 + ii * 16 + lc;             \
            _Pragma("unroll")                                                 \
            for (int kk = 0; kk < 2; ++kk)                                    \
                af[ii][kk] = *(const half8*)(p_ + row_ * 128 +                \
                             ((kk * 64 + (lrg << 4)) ^ rsb));                 \
        }                                                                     \
    } while (0)

#define LDB(buf, nh, bfr)                                                     \
    do {                                                                      \
        const char* p_ = (const char*)lsB[buf];                               \
        _Pragma("unroll")                                                     \
        for (int jj = 0; jj < 2; ++jj) {                                      \
            const int row_ = wc * 64 + ((nh) * 2 + jj) * 16 + lc;             \
            _Pragma("unroll")                                                 \
            for (int kk = 0; kk < 2; ++kk)                                    \
                bfr[jj][kk] = *(const half8*)(p_ + row_ * 128 +               \
                              ((kk * 64 + (lrg << 4)) ^ rsb));                \
        }                                                                     \
    } while (0)

#define MM(mh, nh, bfr)                                                       \
    do {                                                                      \
        __builtin_amdgcn_s_setprio(1);                                        \
        _Pragma("unroll")                                                     \
        for (int ii = 0; ii < 4; ++ii)                                        \
            _Pragma("unroll")                                                 \
            for (int jj = 0; jj < 2; ++jj)                                    \
                _Pragma("unroll")                                             \
                for (int kk = 0; kk < 2; ++kk)                                \
                    acc[(mh) * 4 + ii][(nh) * 2 + jj] =                       \
                        __builtin_amdgcn_mfma_f32_16x16x32_f16(               \
                            af[ii][kk], bfr[jj][kk],                          \
                            acc[(mh) * 4 + ii][(nh) * 2 + jj], 0, 0, 0);      \
        __builtin_amdgcn_s_setprio(0);                                        \
    } while (0)

#define BAR __builtin_amdgcn_s_barrier()
#define VMW(n) asm volatile("s_waitcnt vmcnt(" #n ")" ::: "memory")

    STG(&lsA[0][0], Ab);
    STG(&lsA[0][128 * 64], Ab + (size_t)128 * DD);
    STG(&lsB[0][0], Bb);
    STG(&lsB[0][128 * 64], Bb + (size_t)128 * DD);
    STG(&lsA[1][0], Ab + 64);
    VMW(2);
    BAR;

    for (int i = 0; i < 7; ++i) {
        const int kt1 = (2 * i + 1) * 64, kt2 = kt1 + 64, kt3 = kt2 + 64;
        LDA(0, 0); LDB(0, 0, bf01);
        STG(&lsA[1][128 * 64], Ab + (size_t)128 * DD + kt1);
        BAR; MM(0, 0, bf01); BAR;
        LDB(0, 1, bf23);
        STG(&lsB[1][0], Bb + kt1);
        BAR; MM(0, 1, bf23); BAR;
        LDA(0, 1);
        STG(&lsB[1][128 * 64], Bb + (size_t)128 * DD + kt1);
        BAR; MM(1, 0, bf01); BAR;
        STG(&lsA[0][0], Ab + kt2);
        BAR; MM(1, 1, bf23);
        VMW(2); BAR;
        LDA(1, 0); LDB(1, 0, bf01);
        STG(&lsA[0][128 * 64], Ab + (size_t)128 * DD + kt2);
        BAR; MM(0, 0, bf01); BAR;
        LDB(1, 1, bf23);
        STG(&lsB[0][0], Bb + kt2);
        BAR; MM(0, 1, bf23); BAR;
        LDA(1, 1);
        STG(&lsB[0][128 * 64], Bb + (size_t)128 * DD + kt2);
        BAR; MM(1, 0, bf01); BAR;
        STG(&lsA[1][0], Ab + kt3);
        BAR; MM(1, 1, bf23);
        VMW(2); BAR;
    }
    {
        const int kt1 = 15 * 64;
        LDA(0, 0); LDB(0, 0, bf01);
        STG(&lsA[1][128 * 64], Ab + (size_t)128 * DD + kt1);
        BAR; MM(0, 0, bf01); BAR;
        LDB(0, 1, bf23);
        STG(&lsB[1][0], Bb + kt1);
        BAR; MM(0, 1, bf23); BAR;
        LDA(0, 1);
        STG(&lsB[1][128 * 64], Bb + (size_t)128 * DD + kt1);
        BAR; MM(1, 0, bf01); BAR;
        BAR; MM(1, 1, bf23);
        VMW(0); BAR;
        LDA(1, 0); LDB(1, 0, bf01);
        BAR; MM(0, 0, bf01); BAR;
        LDB(1, 1, bf23);
        BAR; MM(0, 1, bf23); BAR;
        LDA(1, 1);
        BAR; MM(1, 0, bf01); BAR;
        BAR; MM(1, 1, bf23);
    }
    __syncthreads();

    _Float16* Cb = P + (size_t)z * sP;
    float* psum = (float*)&lsA[0][0];
    #pragma unroll
    for (int i = 0; i < 8; ++i) {
        float rsum[4] = {0.f, 0.f, 0.f, 0.f};
        #pragma unroll
        for (int j = 0; j < 4; ++j) {
            const int n = n0 + wc * 64 + j * 16 + lc;
            #pragma unroll
            for (int r = 0; r < 4; ++r) {
                const int m = m0 + wr * 128 + i * 16 + lr + r;
                const float e = __expf(acc[i][j][r] * scale);
                Cb[(size_t)m * LKK + n] = (_Float16)e;
                rsum[r] += e;
            }
        }
        #pragma unroll
        for (int r = 0; r < 4; ++r) {
            float s = rsum[r];
            s += __shfl_xor(s, 1);
            s += __shfl_xor(s, 2);
            s += __shfl_xor(s, 4);
            s += __shfl_xor(s, 8);
            if (lc == 0) psum[(wr * 128 + i * 16 + lr + r) * 4 + wc] = s;
        }
    }
    __syncthreads();
    if (tid < 256) {
        const float* pr = psum + tid * 4;
        partial[((size_t)z * LQ + m0 + tid) * 8 + bx] = pr[0] + pr[1] + pr[2] + pr[3];
    }
#undef STG
#undef LDA
#undef LDB
#undef MM
}

// ===========================================================================
// 256x128 NT-GEMM for PV / cat — 4M x 2N waves, 3-buffer rolling schedule,
// counted vmcnt(6), 144KB LDS.  [proven R7/R8 — unchanged]
// ===========================================================================
__global__ __launch_bounds__(512, 2) void gemm_pc_256x128(
    const _Float16* __restrict__ Alo, long sAlo, int lda_lo,
    const _Float16* __restrict__ Ahi, long sAhi, int lda_hi,
    int ksplit,
    const _Float16* __restrict__ B, long sB, int ldb,
    int K, int mode,
    float* __restrict__ out32, long s32, int ldc32,
    _Float16* __restrict__ out16, long s16, int ldc16,
    const float* __restrict__ bias,
    const float* __restrict__ partial, int npart)
{
    __shared__ _Float16 ls[3][384 * 64];
    const int tid = threadIdx.x;
    const int w = tid >> 6, l = tid & 63;
    const int wr = w >> 1, wc = w & 1;     // 4M x 2N
    const int lrg = l >> 4, lc = l & 15, lr = lrg << 2;

    int id = blockIdx.x + gridDim.x * (blockIdx.y + gridDim.y * blockIdx.z);
    const int nwg = gridDim.x * gridDim.y * gridDim.z;
    id = (id & 7) * (nwg >> 3) + (id >> 3);
    const int bx = id % gridDim.x;
    const int t2_ = id / gridDim.x;
    const int by = t2_ % gridDim.y;
    const int z  = t2_ / gridDim.y;
    const int m0 = by * 256, n0 = bx * 128;

    const _Float16* Abase_lo = Alo + (size_t)z * sAlo + (size_t)m0 * lda_lo;
    const _Float16* Abase_hi = Ahi ? (Ahi + (size_t)z * sAhi + (size_t)m0 * lda_hi) : (const _Float16*)0;
    const _Float16* Bbase = B + (size_t)z * sB + (size_t)n0 * ldb;

    const int srow = l >> 3;
    const int sk = ((l & 7) ^ srow) << 3;
    const int rsb = (lc & 7) << 4;

    half8 af[4][2], bf[2][2];
    f32x4 acc[4][4] = {};

#define STGA(tt, dbuf)                                                        \
    do {                                                                      \
        const int kb_ = (tt) * 64;                                            \
        const _Float16* s_; int ld_;                                          \
        if (kb_ < ksplit) { s_ = Abase_lo + kb_;           ld_ = lda_lo; }    \
        else              { s_ = Abase_hi + (kb_ - ksplit); ld_ = lda_hi; }   \
        _Float16* d_ = &ls[dbuf][0];                                          \
        _Pragma("unroll")                                                     \
        for (int rr = 0; rr < 4; ++rr) {                                      \
            const int c = w + 8 * rr;                                         \
            gl_lds16(s_ + (size_t)(c * 8 + srow) * ld_ + sk, d_ + c * 512);   \
        }                                                                     \
    } while (0)

#define STGB(tt, dbuf)                                                        \
    do {                                                                      \
        const _Float16* s_ = Bbase + (tt) * 64;                               \
        _Float16* d_ = &ls[dbuf][256 * 64];                                   \
        _Pragma("unroll")                                                     \
        for (int rr = 0; rr < 2; ++rr) {                                      \
            const int c = w + 8 * rr;                                         \
            gl_lds16(s_ + (size_t)(c * 8 + srow) * ldb + sk, d_ + c * 512);   \
        }                                                                     \
    } while (0)

#define LDA2(buf)                                                             \
    do {                                                                      \
        const char* p_ = (const char*)&ls[buf][0];                            \
        _Pragma("unroll")                                                     \
        for (int ii = 0; ii < 4; ++ii) {                                      \
            const int row_ = wr * 64 + ii * 16 + lc;                          \
            _Pragma("unroll")                                                 \
            for (int kk = 0; kk < 2; ++kk)                                    \
                af[ii][kk] = *(const half8*)(p_ + row_ * 128 +                \
                             ((kk * 64 + (lrg << 4)) ^ rsb));                 \
        }                                                                     \
    } while (0)

#define LDB2(buf, nh)                                                         \
    do {                                                                      \
        const char* p_ = (const char*)&ls[buf][256 * 64];                     \
        _Pragma("unroll")                                                     \
        for (int jj = 0; jj < 2; ++jj) {                                      \
            const int row_ = wc * 64 + ((nh) * 2 + jj) * 16 + lc;             \
            _Pragma("unroll")                                                 \
            for (int kk = 0; kk < 2; ++kk)                                    \
                bf[jj][kk] = *(const half8*)(p_ + row_ * 128 +                \
                              ((kk * 64 + (lrg << 4)) ^ rsb));                \
        }                                                                     \
    } while (0)

#define MM2(nh)                                                               \
    do {                                                                      \
        __builtin_amdgcn_s_setprio(1);                                        \
        _Pragma("unroll")                                                     \
        for (int ii = 0; ii < 4; ++ii)                                        \
            _Pragma("unroll")                                                 \
            for (int jj = 0; jj < 2; ++jj)                                    \
                _Pragma("unroll")                                             \
                for (int kk = 0; kk < 2; ++kk)                                \
                    acc[ii][(nh) * 2 + jj] =                                  \
                        __builtin_amdgcn_mfma_f32_16x16x32_f16(               \
                            af[ii][kk], bf[jj][kk],                           \
                            acc[ii][(nh) * 2 + jj], 0, 0, 0);                 \
        __builtin_amdgcn_s_setprio(0);                                        \
    } while (0)

    const int NT = K >> 6;
    STGA(0, 0); STGB(0, 0);
    STGA(1, 1); STGB(1, 1);
    VMW(6);
    BAR;

    int b = 0, b2 = 2;
    for (int t = 0; t < NT; ++t) {
        const int tt = t + 2;
        const bool st = tt < NT;
        LDA2(b); LDB2(b, 0);
        if (st) STGA(tt, b2);
        BAR; MM2(0); BAR;
        LDB2(b, 1);
        if (st) STGB(tt, b2);
        BAR; MM2(1);
        if (t < NT - 2)       VMW(6);
        else if (t == NT - 2) VMW(0);
        BAR;
        b = (b == 2) ? 0 : b + 1;
        b2 = (b2 == 2) ? 0 : b2 + 1;
    }
    __syncthreads();

    if (mode == 1) {
        float* psum = (float*)&ls[0][0];
        if (tid < 256) {
            const float* pp = partial + ((size_t)z * LQ + m0 + tid) * npart;
            float s = 0.0f;
            for (int c = 0; c < npart; ++c) s += pp[c];
            psum[tid] = 1.0f / s;
        }
        __syncthreads();
        _Float16* Cb = out16 + (size_t)z * s16;
        #pragma unroll
        for (int i = 0; i < 4; ++i)
            #pragma unroll
            for (int j = 0; j < 4; ++j) {
                const int n = n0 + wc * 64 + j * 16 + lc;
                #pragma unroll
                for (int r = 0; r < 4; ++r) {
                    const int ml = wr * 64 + i * 16 + lr + r;
                    Cb[(size_t)(m0 + ml) * ldc16 + n] =
                        (_Float16)(acc[i][j][r] * psum[ml]);
                }
            }
    } else {
        float bv[4];
        #pragma unroll
        for (int j = 0; j < 4; ++j)
            bv[j] = bias[n0 + wc * 64 + j * 16 + lc];
        #pragma unroll
        for (int i = 0; i < 4; ++i)
            #pragma unroll
            for (int j = 0; j < 4; ++j) {
                const int n = n0 + wc * 64 + j * 16 + lc;
                #pragma unroll
                for (int r = 0; r < 4; ++r) {
                    const int m = m0 + wr * 64 + i * 16 + lr + r;
                    const float t = tanhf(acc[i][j][r] + bv[j]);
                    if (out16) out16[(size_t)z * s16 + (size_t)m * ldc16 + n] = (_Float16)t;
                    if (out32) out32[(size_t)z * s32 + (size_t)m * ldc32 + n] = t;
                }
            }
    }
#undef STGA
#undef STGB
#undef LDA2
#undef LDB2
#undef MM2
#undef BAR
#undef VMW
}

// ---------------------------------------------------------------------------
// f16 MFMA NT-GEMM 128x128 (R3-fallback path only)
// ---------------------------------------------------------------------------
__global__ __launch_bounds__(256) void gemm_f16_nt(
    const _Float16* __restrict__ Alo, long sAlo, int lda_lo,
    const _Float16* __restrict__ Ahi, long sAhi, int lda_hi,
    int ksplit,
    const _Float16* __restrict__ B, long sB, int ldb,
    int K, int mode, float scale,
    float* __restrict__ out32, long s32, int ldc32,
    _Float16* __restrict__ out16, long s16, int ldc16,
    const float* __restrict__ bias,
    float* __restrict__ partial, const float* __restrict__ inv, int npart)
{
    __shared__ _Float16 lsA[128 * 64];
    __shared__ _Float16 lsB[128 * 64];
    __shared__ float psum[128][2];
    const int tid = threadIdx.x;
    const int w = tid >> 6, l = tid & 63;
    const int wr = w >> 1, wc = w & 1;

    int id = blockIdx.x + gridDim.x * (blockIdx.y + gridDim.y * blockIdx.z);
    const int nwg = gridDim.x * gridDim.y * gridDim.z;
    id = (id & 7) * (nwg >> 3) + (id >> 3);
    const int bx = id % gridDim.x;
    const int t2 = id / gridDim.x;
    const int by = t2 % gridDim.y;
    const int z = t2 / gridDim.y;
    const int m0 = by * 128, n0 = bx * 128;

    const _Float16* Abase_lo = Alo + (size_t)z * sAlo + (size_t)m0 * lda_lo;
    const _Float16* Abase_hi = Ahi ? (Ahi + (size_t)z * sAhi + (size_t)m0 * lda_hi) : (const _Float16*)0;
    const _Float16* Bbase = B + (size_t)z * sB + (size_t)n0 * ldb;

    const int srow = l >> 3;
    const int sswz = ((l & 7) ^ srow) << 3;

    f32x4 acc[4][4] = {};

    for (int k0 = 0; k0 < K; k0 += 64) {
        const _Float16* Ap; int kloc, ldaA;
        if (k0 < ksplit) { Ap = Abase_lo; kloc = k0;          ldaA = lda_lo; }
        else             { Ap = Abase_hi; kloc = k0 - ksplit; ldaA = lda_hi; }
        #pragma unroll
        for (int i = 0; i < 4; ++i) {
            const int c = w * 4 + i;
            const int row = c * 8 + srow;
            gl_lds16(Ap + (size_t)row * ldaA + kloc + sswz, &lsA[c * 512]);
        }
        #pragma unroll
        for (int i = 0; i < 4; ++i) {
            const int c = w * 4 + i;
            const int row = c * 8 + srow;
            gl_lds16(Bbase + (size_t)row * ldb + k0 + sswz, &lsB[c * 512]);
        }
        __syncthreads();

        half8 af[4][2], bf[4][2];
        const char* lA = (const char*)lsA;
        const char* lB = (const char*)lsB;
        const int rs = (l & 7) << 4;
        const int cb = (l >> 4) << 4;
        #pragma unroll
        for (int i = 0; i < 4; ++i) {
            const int rowa = wr * 64 + i * 16 + (l & 15);
            const int rowb = wc * 64 + i * 16 + (l & 15);
            #pragma unroll
            for (int kk = 0; kk < 2; ++kk) {
                af[i][kk] = *(const half8*)(lA + rowa * 128 + ((kk * 64 + cb) ^ rs));
                bf[i][kk] = *(const half8*)(lB + rowb * 128 + ((kk * 64 + cb) ^ rs));
            }
        }
        #pragma unroll
        for (int kk = 0; kk < 2; ++kk)
            #pragma unroll
            for (int i = 0; i < 4; ++i)
                #pragma unroll
                for (int j = 0; j < 4; ++j)
                    acc[i][j] = __builtin_amdgcn_mfma_f32_16x16x32_f16(
                        af[i][kk], bf[j][kk], acc[i][j], 0, 0, 0);
        __syncthreads();
    }

    const int lr = (l >> 4) * 4;
    const int lc = l & 15;
    if (mode == 0) {
        _Float16* Cb = out16 + (size_t)z * s16;
        float rsum[4][4];
        #pragma unroll
        for (int i = 0; i < 4; ++i)
            #pragma unroll
            for (int r = 0; r < 4; ++r) rsum[i][r] = 0.0f;
        #pragma unroll
        for (int i = 0; i < 4; ++i)
            #pragma unroll
            for (int j = 0; j < 4; ++j) {
                const int n = n0 + wc * 64 + j * 16 + lc;
                #pragma unroll
                for (int r = 0; r < 4; ++r) {
                    const int m = m0 + wr * 64 + i * 16 + lr + r;
                    const float e = __expf(acc[i][j][r] * scale);
                    Cb[(size_t)m * ldc16 + n] = (_Float16)e;
                    rsum[i][r] += e;
                }
            }
        #pragma unroll
        for (int i = 0; i < 4; ++i)
            #pragma unroll
            for (int r = 0; r < 4; ++r) {
                float s = rsum[i][r];
                s += __shfl_xor(s, 1);
                s += __shfl_xor(s, 2);
                s += __shfl_xor(s, 4);
                s += __shfl_xor(s, 8);
                rsum[i][r] = s;
            }
        if (lc == 0) {
            #pragma unroll
            for (int i = 0; i < 4; ++i)
                #pragma unroll
                for (int r = 0; r < 4; ++r)
                    psum[wr * 64 + i * 16 + lr + r][wc] = rsum[i][r];
        }
        __syncthreads();
        if (tid < 128)
            partial[((size_t)z * LQ + m0 + tid) * npart + bx] = psum[tid][0] + psum[tid][1];
    } else if (mode == 1) {
        _Float16* Cb = out16 + (size_t)z * s16;
        float iv[4][4];
        if (partial) {
            if (tid < 128) {
                const float* pp = partial + ((size_t)z * LQ + m0 + tid) * npart;
                float s = 0.0f;
                for (int c = 0; c < npart; ++c) s += pp[c];
                psum[tid][0] = 1.0f / s;
            }
            __syncthreads();
            #pragma unroll
            for (int i = 0; i < 4; ++i)
                #pragma unroll
                for (int r = 0; r < 4; ++r)
                    iv[i][r] = psum[wr * 64 + i * 16 + lr + r][0];
        } else {
            #pragma unroll
            for (int i = 0; i < 4; ++i)
                #pragma unroll
                for (int r = 0; r < 4; ++r)
                    iv[i][r] = inv ? inv[(size_t)z * LQ + m0 + wr * 64 + i * 16 + lr + r] : 1.0f;
        }
        #pragma unroll
        for (int i = 0; i < 4; ++i)
            #pragma unroll
            for (int j = 0; j < 4; ++j) {
                const int n = n0 + wc * 64 + j * 16 + lc;
                #pragma unroll
                for (int r = 0; r < 4; ++r) {
                    const int m = m0 + wr * 64 + i * 16 + lr + r;
                    Cb[(size_t)m * ldc16 + n] = (_Float16)(acc[i][j][r] * iv[i][r]);
                }
            }
    } else if (mode == 4) {
        float* Cb = out32 + (size_t)z * s32;
        #pragma unroll
        for (int i = 0; i < 4; ++i)
            #pragma unroll
            for (int j = 0; j < 4; ++j) {
                const int n = n0 + wc * 64 + j * 16 + lc;
                #pragma unroll
                for (int r = 0; r < 4; ++r) {
                    const int m = m0 + wr * 64 + i * 16 + lr + r;
                    Cb[(size_t)m * ldc32 + n] = acc[i][j][r] * scale;
                }
            }
    } else {
        float bv[4];
        #pragma unroll
        for (int j = 0; j < 4; ++j)
            bv[j] = bias[n0 + wc * 64 + j * 16 + lc];
        #pragma unroll
        for (int i = 0; i < 4; ++i)
            #pragma unroll
            for (int j = 0; j < 4; ++j) {
                const int n = n0 + wc * 64 + j * 16 + lc;
                #pragma unroll
                for (int r = 0; r < 4; ++r) {
                    const int m = m0 + wr * 64 + i * 16 + lr + r;
                    const float t = tanhf(acc[i][j][r] + bv[j]);
                    if (out16) out16[(size_t)z * s16 + (size_t)m * ldc16 + n] = (_Float16)t;
                    if (out32) out32[(size_t)z * s32 + (size_t)m * ldc32 + n] = t;
                }
            }
    }
}

// one block per row: attn_f32[row,:] = P16[row,:] * (1/sum partial[row,0..npart))
__global__ __launch_bounds__(256) void scale_attn(
    const _Float16* __restrict__ P, const float* __restrict__ partial,
    float* __restrict__ attn, int npart)
{
    __shared__ float sinv;
    const long row = blockIdx.x;
    const int tid = threadIdx.x;
    if (tid < npart) {
        float s = partial[row * npart + tid];
        for (int off = npart >> 1; off > 0; off >>= 1) s += __shfl_xor(s, off);
        if (tid == 0) sinv = 1.0f / s;
    }
    __syncthreads();
    const float inv = sinv;
    const half8 h = *(const half8*)(P + row * 2048 + tid * 8);
    float* o = attn + row * 2048 + tid * 8;
    float4 a = make_float4((float)h[0] * inv, (float)h[1] * inv,
                           (float)h[2] * inv, (float)h[3] * inv);
    float4 b = make_float4((float)h[4] * inv, (float)h[5] * inv,
                           (float)h[6] * inv, (float)h[7] * inv);
    *(float4*)o = a;
    *(float4*)(o + 4) = b;
}

// inv[row] = 1 / sum_{cb<16} partial[row*16+cb]   (R3-fallback path)
__global__ __launch_bounds__(256) void make_inv(
    const float* __restrict__ partial, float* __restrict__ inv)
{
    const int row = blockIdx.x * 256 + threadIdx.x;
    const float4 a = *(const float4*)(partial + (size_t)row * 16);
    const float4 b = *(const float4*)(partial + (size_t)row * 16 + 4);
    const float4 c = *(const float4*)(partial + (size_t)row * 16 + 8);
    const float4 d = *(const float4*)(partial + (size_t)row * 16 + 12);
    const float s = (a.x + a.y + a.z + a.w) + (b.x + b.y + b.z + b.w)
                  + (c.x + c.y + c.z + c.w) + (d.x + d.y + d.z + d.w);
    inv[row] = 1.0f / s;
}

// row softmax over 2048 f32 (R3-fallback hop 2)
__global__ __launch_bounds__(256) void softmax_rows2(
    float* __restrict__ S, _Float16* __restrict__ f16out,
    long f16stride, int write_f32)
{
    __shared__ float red[8];
    const long row = blockIdx.x;
    float* p = S + row * LKK;
    const int tid = threadIdx.x;
    float4 v0 = ((const float4*)p)[tid];
    float4 v1 = ((const float4*)p)[tid + 256];
    float m = fmaxf(fmaxf(fmaxf(v0.x, v0.y), fmaxf(v0.z, v0.w)),
                    fmaxf(fmaxf(v1.x, v1.y), fmaxf(v1.z, v1.w)));
    #pragma unroll
    for (int off = 32; off > 0; off >>= 1) m = fmaxf(m, __shfl_down(m, off));
    if ((tid & 63) == 0) red[tid >> 6] = m;
    __syncthreads();
    m = fmaxf(fmaxf(red[0], red[1]), fmaxf(red[2], red[3]));
    v0.x = expf(v0.x - m); v0.y = expf(v0.y - m);
    v0.z = expf(v0.z - m); v0.w = expf(v0.w - m);
    v1.x = expf(v1.x - m); v1.y = expf(v1.y - m);
    v1.z = expf(v1.z - m); v1.w = expf(v1.w - m);
    float s = v0.x + v0.y + v0.z + v0.w + v1.x + v1.y + v1.z + v1.w;
    #pragma unroll
    for (int off = 32; off > 0; off >>= 1) s += __shfl_down(s, off);
    if ((tid & 63) == 0) red[4 + (tid >> 6)] = s;
    __syncthreads();
    s = red[4] + red[5] + red[6] + red[7];
    const float inv = 1.0f / s;
    v0.x *= inv; v0.y *= inv; v0.z *= inv; v0.w *= inv;
    v1.x *= inv; v1.y *= inv; v1.z *= inv; v1.w *= inv;
    if (write_f32) {
        ((float4*)p)[tid] = v0;
        ((float4*)p)[tid + 256] = v1;
    }
    _Float16* q = f16out + row * f16stride;
    half4 h0 = { (_Float16)v0.x, (_Float16)v0.y, (_Float16)v0.z, (_Float16)v0.w };
    half4 h1 = { (_Float16)v1.x, (_Float16)v1.y, (_Float16)v1.z, (_Float16)v1.w };
    *(half4*)(q + tid * 4) = h0;
    *(half4*)(q + 1024 + tid * 4) = h1;
}

__global__ __launch_bounds__(256) void cvt_f32_to_f16(
    const float* __restrict__ in, _Float16* __restrict__ out, long n)
{
    const long i = ((long)blockIdx.x * 256 + threadIdx.x) * 8;
    if (i + 8 > n) return;
    float4 a = *(const float4*)(in + i);
    float4 b = *(const float4*)(in + i + 4);
    half8 h = { (_Float16)a.x, (_Float16)a.y, (_Float16)a.z, (_Float16)a.w,
                (_Float16)b.x, (_Float16)b.y, (_Float16)b.z, (_Float16)b.w };
    *(half8*)(out + i) = h;
}

// V [B, Lk, D] f32 -> Vt [B, D, Lk] f16, 64x64 tiles via LDS (fallback paths)
__global__ __launch_bounds__(256) void transpose_cvt_v(
    const float* __restrict__ V, _Float16* __restrict__ Vt)
{
    __shared__ _Float16 t[64][80];
    const int z = blockIdx.z;
    const int k0 = blockIdx.y * 64, d0 = blockIdx.x * 64;
    const float* Vb = V + (size_t)z * LKK * DD;
    _Float16* Vtb = Vt + (size_t)z * DD * LKK;
    const int r = threadIdx.x >> 2;
    const int c0 = (threadIdx.x & 3) * 16;
    #pragma unroll
    for (int j = 0; j < 4; ++j) {
        float4 v = *(const float4*)(Vb + (size_t)(k0 + r) * DD + d0 + c0 + j * 4);
        t[c0 + j * 4 + 0][r] = (_Float16)v.x;
        t[c0 + j * 4 + 1][r] = (_Float16)v.y;
        t[c0 + j * 4 + 2][r] = (_Float16)v.z;
        t[c0 + j * 4 + 3][r] = (_Float16)v.w;
    }
    __syncthreads();
    #pragma unroll
    for (int j = 0; j < 2; ++j) {
        half8 h = *(const half8*)&t[r][c0 + j * 8];
        *(half8*)(Vtb + (size_t)(d0 + r) * LKK + k0 + c0 + j * 8) = h;
    }
}

// ===========================================================================
// R9: all prep in ONE block-range dispatch (exact grids, uniform branch per
// block, identical bodies to the proven R6/R8 kernels):
//   blocks [0,4096)       cvt Q   (8.4M f32 -> f16)
//   blocks [4096,20480)   cvt K   (33.5M)
//   blocks [20480,21504)  cvt W   (2.1M)
//   blocks [21504,29696)  transpose+cvt V (64x64 tiles, 8192 blocks)
// ===========================================================================
__global__ __launch_bounds__(256) void prep_all(
    const float* __restrict__ Q, const float* __restrict__ K,
    const float* __restrict__ W, const float* __restrict__ V,
    _Float16* __restrict__ Qh, _Float16* __restrict__ Kh,
    _Float16* __restrict__ Wh, _Float16* __restrict__ Vt)
{
    __shared__ _Float16 t[64][80];
    const int b = blockIdx.x;
    const int tid = threadIdx.x;

    if (b < 21504) {
        const float* src; _Float16* dst; long bloc;
        if (b < 4096)       { src = Q; dst = Qh; bloc = b; }
        else if (b < 20480) { src = K; dst = Kh; bloc = b - 4096; }
        else                { src = W; dst = Wh; bloc = b - 20480; }
        const long i = (bloc * 256 + tid) * 8;
        float4 a = *(const float4*)(src + i);
        float4 c = *(const float4*)(src + i + 4);
        half8 h = { (_Float16)a.x, (_Float16)a.y, (_Float16)a.z, (_Float16)a.w,
                    (_Float16)c.x, (_Float16)c.y, (_Float16)c.z, (_Float16)c.w };
        *(half8*)(dst + i) = h;
        return;
    }
    // V transpose: bb in [0, 8192): dx 16 x ky 32 x z 16
    const int bb = b - 21504;
    const int dx = bb & 15;
    const int ky = (bb >> 4) & 31;
    const int z  = bb >> 9;
    const int k0 = ky * 64, d0 = dx * 64;
    const float* Vb = V + (size_t)z * LKK * DD;
    _Float16* Vtb = Vt + (size_t)z * DD * LKK;
    const int r = tid >> 2;
    const int c0 = (tid & 3) * 16;
    #pragma unroll
    for (int j = 0; j < 4; ++j) {
        float4 v = *(const float4*)(Vb + (size_t)(k0 + r) * DD + d0 + c0 + j * 4);
        t[c0 + j * 4 + 0][r] = (_Float16)v.x;
        t[c0 + j * 4 + 1][r] = (_Float16)v.y;
        t[c0 + j * 4 + 2][r] = (_Float16)v.z;
        t[c0 + j * 4 + 3][r] = (_Float16)v.w;
    }
    __syncthreads();
    #pragma unroll
    for (int j = 0; j < 2; ++j) {
        half8 h = *(const half8*)&t[r][c0 + j * 8];
        *(half8*)(Vtb + (size_t)(d0 + r) * LKK + k0 + c0 + j * 8) = h;
    }
}

// ======================= round-1 f32 fallback kernels =======================
constexpr int TM = 64, TN = 64, TK = 32;
constexpr int PAD = 4;

__global__ __launch_bounds__(256) void gemm_nt_k(
    const float* __restrict__ A, int lda, long sA,
    const float* __restrict__ Bt, int ldb, long sB,
    float* __restrict__ C, int ldc, long sC, int K, float scale)
{
    __shared__ float As[TK][TM + PAD];
    __shared__ float Bs[TK][TN + PAD];
    const float* Ab = A + (long)blockIdx.z * sA;
    const float* Bb = Bt + (long)blockIdx.z * sB;
    float* Cb = C + (long)blockIdx.z * sC;
    const int m0 = blockIdx.y * TM, n0 = blockIdx.x * TN;
    const int tid = threadIdx.x;
    const int tn = tid & 15, tm = tid >> 4;
    float acc[4][4] = {};
    for (int k0 = 0; k0 < K; k0 += TK) {
        #pragma unroll
        for (int c = tid; c < (TM * TK) / 4; c += 256) {
            const int row = c >> 3, kc = (c & 7) << 2;
            const float4 g = *(const float4*)(Ab + (long)(m0 + row) * lda + (k0 + kc));
            As[kc + 0][row] = g.x; As[kc + 1][row] = g.y;
            As[kc + 2][row] = g.z; As[kc + 3][row] = g.w;
        }
        #pragma unroll
        for (int c = tid; c < (TN * TK) / 4; c += 256) {
            const int row = c >> 3, kc = (c & 7) << 2;
            const float4 g = *(const float4*)(Bb + (long)(n0 + row) * ldb + (k0 + kc));
            Bs[kc + 0][row] = g.x; Bs[kc + 1][row] = g.y;
            Bs[kc + 2][row] = g.z; Bs[kc + 3][row] = g.w;
        }
        __syncthreads();
        #pragma unroll
        for (int kk = 0; kk < TK; ++kk) {
            const float4 av = *(const float4*)&As[kk][tm << 2];
            const float4 bv = *(const float4*)&Bs[kk][tn << 2];
            const float a[4] = {av.x, av.y, av.z, av.w};
            const float b[4] = {bv.x, bv.y, bv.z, bv.w};
            #pragma unroll
            for (int i = 0; i < 4; ++i)
                #pragma unroll
                for (int j = 0; j < 4; ++j)
                    acc[i][j] = fmaf(a[i], b[j], acc[i][j]);
        }
        __syncthreads();
    }
    #pragma unroll
    for (int i = 0; i < 4; ++i) {
        float4 o = make_float4(acc[i][0] * scale, acc[i][1] * scale,
                               acc[i][2] * scale, acc[i][3] * scale);
        *(float4*)(Cb + (long)(m0 + (tm << 2) + i) * ldc + n0 + (tn << 2)) = o;
    }
}

__global__ __launch_bounds__(256) void gemm_nn_k(
    const float* __restrict__ A, int lda, long sA,
    const float* __restrict__ B, int ldb, long sB,
    float* __restrict__ C, int ldc, long sC, int K)
{
    __shared__ float As[TK][TM + PAD];
    __shared__ float Bs[TK][TN + PAD];
    const float* Ab = A + (long)blockIdx.z * sA;
    const float* Bb = B + (long)blockIdx.z * sB;
    float* Cb = C + (long)blockIdx.z * sC;
    const int m0 = blockIdx.y * TM, n0 = blockIdx.x * TN;
    const int tid = threadIdx.x;
    const int tn = tid & 15, tm = tid >> 4;
    float acc[4][4] = {};
    for (int k0 = 0; k0 < K; k0 += TK) {
        #pragma unroll
        for (int c = tid; c < (TM * TK) / 4; c += 256) {
            const int row = c >> 3, kc = (c & 7) << 2;
            const float4 g = *(const float4*)(Ab + (long)(m0 + row) * lda + (k0 + kc));
            As[kc + 0][row] = g.x; As[kc + 1][row] = g.y;
            As[kc + 2][row] = g.z; As[kc + 3][row] = g.w;
        }
        #pragma unroll
        for (int c = tid; c < (TK * TN) / 4; c += 256) {
            const int krow = c >> 4, nc = (c & 15) << 2;
            *(float4*)&Bs[krow][nc] =
                *(const float4*)(Bb + (long)(k0 + krow) * ldb + n0 + nc);
        }
        __syncthreads();
        #pragma unroll
        for (int kk = 0; kk < TK; ++kk) {
            const float4 av = *(const float4*)&As[kk][tm << 2];
            const float4 bv = *(const float4*)&Bs[kk][tn << 2];
            const float a[4] = {av.x, av.y, av.z, av.w};
            const float b[4] = {bv.x, bv.y, bv.z, bv.w};
            #pragma unroll
            for (int i = 0; i < 4; ++i)
                #pragma unroll
                for (int j = 0; j < 4; ++j)
                    acc[i][j] = fmaf(a[i], b[j], acc[i][j]);
        }
        __syncthreads();
    }
    #pragma unroll
    for (int i = 0; i < 4; ++i) {
        float4 o = make_float4(acc[i][0], acc[i][1], acc[i][2], acc[i][3]);
        *(float4*)(Cb + (long)(m0 + (tm << 2) + i) * ldc + n0 + (tn << 2)) = o;
    }
}

__global__ __launch_bounds__(256) void gemm_cat_k(
    const float* __restrict__ Qh, const float* __restrict__ R,
    const float* __restrict__ W, const float* __restrict__ bias,
    float* __restrict__ C)
{
    __shared__ float As[TK][TM + PAD];
    __shared__ float Bs[TK][TN + PAD];
    const float* Qb = Qh + (long)blockIdx.z * LQ * DD;
    const float* Rb = R + (long)blockIdx.z * LQ * DD;
    float* Cb = C + (long)blockIdx.z * LQ * DD;
    const int m0 = blockIdx.y * TM, n0 = blockIdx.x * TN;
    const int tid = threadIdx.x;
    const int tn = tid & 15, tm = tid >> 4;
    float acc[4][4] = {};
    for (int k0 = 0; k0 < 2 * DD; k0 += TK) {
        const float* src = (k0 < DD) ? Qb : Rb;
        const int kb = (k0 < DD) ? k0 : k0 - DD;
        #pragma unroll
        for (int c = tid; c < (TM * TK) / 4; c += 256) {
            const int row = c >> 3, kc = (c & 7) << 2;
            const float4 g = *(const float4*)(src + (long)(m0 + row) * DD + (kb + kc));
            As[kc + 0][row] = g.x; As[kc + 1][row] = g.y;
            As[kc + 2][row] = g.z; As[kc + 3][row] = g.w;
        }
        #pragma unroll
        for (int c = tid; c < (TN * TK) / 4; c += 256) {
            const int row = c >> 3, kc = (c & 7) << 2;
            const float4 g = *(const float4*)(W + (long)(n0 + row) * (2 * DD) + (k0 + kc));
            Bs[kc + 0][row] = g.x; Bs[kc + 1][row] = g.y;
            Bs[kc + 2][row] = g.z; Bs[kc + 3][row] = g.w;
        }
        __syncthreads();
        #pragma unroll
        for (int kk = 0; kk < TK; ++kk) {
            const float4 av = *(const float4*)&As[kk][tm << 2];
            const float4 bv = *(const float4*)&Bs[kk][tn << 2];
            const float a[4] = {av.x, av.y, av.z, av.w};
            const float b[4] = {bv.x, bv.y, bv.z, bv.w};
            #pragma unroll
            for (int i = 0; i < 4; ++i)
                #pragma unroll
                for (int j = 0; j < 4; ++j)
                    acc[i][j] = fmaf(a[i], b[j], acc[i][j]);
        }
        __syncthreads();
    }
    #pragma unroll
    for (int i = 0; i < 4; ++i) {
        float4 o;
        o.x = tanhf(acc[i][0] + bias[n0 + (tn << 2) + 0]);
        o.y = tanhf(acc[i][1] + bias[n0 + (tn << 2) + 1]);
        o.z = tanhf(acc[i][2] + bias[n0 + (tn << 2) + 2]);
        o.w = tanhf(acc[i][3] + bias[n0 + (tn << 2) + 3]);
        *(float4*)(Cb + (long)(m0 + (tm << 2) + i) * DD + n0 + (tn << 2)) = o;
    }
}

__global__ __launch_bounds__(256) void softmax_rows(float* __restrict__ S) {
    __shared__ float red[8];
    float* p = S + (size_t)blockIdx.x * LKK;
    const int tid = threadIdx.x;
    float4 v0 = ((const float4*)p)[tid];
    float4 v1 = ((const float4*)p)[tid + 256];
    float m = fmaxf(fmaxf(fmaxf(v0.x, v0.y), fmaxf(v0.z, v0.w)),
                    fmaxf(fmaxf(v1.x, v1.y), fmaxf(v1.z, v1.w)));
    #pragma unroll
    for (int off = 32; off > 0; off >>= 1) m = fmaxf(m, __shfl_down(m, off));
    if ((tid & 63) == 0) red[tid >> 6] = m;
    __syncthreads();
    m = fmaxf(fmaxf(red[0], red[1]), fmaxf(red[2], red[3]));
    v0.x = expf(v0.x - m); v0.y = expf(v0.y - m);
    v0.z = expf(v0.z - m); v0.w = expf(v0.w - m);
    v1.x = expf(v1.x - m); v1.y = expf(v1.y - m);
    v1.z = expf(v1.z - m); v1.w = expf(v1.w - m);
    float s = v0.x + v0.y + v0.z + v0.w + v1.x + v1.y + v1.z + v1.w;
    #pragma unroll
    for (int off = 32; off > 0; off >>= 1) s += __shfl_down(s, off);
    if ((tid & 63) == 0) red[4 + (tid >> 6)] = s;
    __syncthreads();
    s = red[4] + red[5] + red[6] + red[7];
    const float inv = 1.0f / s;
    v0.x *= inv; v0.y *= inv; v0.z *= inv; v0.w *= inv;
    v1.x *= inv; v1.y *= inv; v1.z *= inv; v1.w *= inv;
    ((float4*)p)[tid] = v0;
    ((float4*)p)[tid + 256] = v1;
}

// ===========================================================================
extern "C" void kernel_launch(void* const* d_in, const int* in_sizes, int n_in,
                              void* d_out, int out_size, void* d_ws, size_t ws_size,
                              hipStream_t stream) {
    const float* Q    = (const float*)d_in[0];
    const float* Km   = (const float*)d_in[1];
    const float* V    = (const float*)d_in[2];
    const float* W    = (const float*)d_in[3];
    const float* bias = (const float*)d_in[4];
    const float scale = 0.03125f;  // 1/sqrt(1024)
    dim3 blk(256);

    const size_t NEED_FULL = 189267968ULL;
    const size_t NEED_R3   = 155189248ULL;

    if (ws_size >= NEED_FULL) {
        char* ws = (char*)d_ws;
        _Float16* Kh     = (_Float16*)ws;                    // [16,2048,1024]
        _Float16* Vt     = (_Float16*)(ws + 67108864);       // [16,1024,2048]
        _Float16* Wh     = (_Float16*)(ws + 134217728);      // [1024,2048]
        _Float16* Rh     = (_Float16*)(ws + 138412032);      // [16,512,1024]
        _Float16* Qping  = (_Float16*)(ws + 155189248);      // [16,512,1024]
        _Float16* Qpong  = (_Float16*)(ws + 171966464);      // [16,512,1024]
        float*    partialB = (float*)(ws + 188743680);       // [8192,8]

        float*    outQ  = (float*)d_out;
        _Float16* P2    = (_Float16*)d_out;
        float*    attnF = (float*)((char*)d_out + 33554432);
        _Float16* P01   = (_Float16*)attnF;

        // R9: single block-range prep dispatch (Q/K/W cvt + V transpose)
        prep_all<<<29696, blk, 0, stream>>>(Q, Km, W, V, Qping, Kh, Wh, Vt);

        dim3 gS2(LKK / 256, LQ / 256, NB);  // 8 x 2 x 16 = 256 blocks
        dim3 gP(DD / 128, LQ / 256, NB);    // 8 x 2 x 16 = 256 blocks

        for (int h = 0; h < 3; ++h) {
            _Float16* qcur = (h == 1) ? Qpong : Qping;
            _Float16* P    = (h == 2) ? P2 : P01;

            gemm_qk_256<<<gS2, dim3(512), 0, stream>>>(
                qcur, (long)LQ * DD, Kh, (long)LKK * DD,
                P, (long)LQ * LKK, partialB, scale);
            if (h == 2)
                scale_attn<<<NB * LQ, blk, 0, stream>>>(P2, partialB, attnF, 8);
            gemm_pc_256x128<<<gP, dim3(512), 0, stream>>>(
                P, (long)LQ * LKK, LKK,
                (const _Float16*)0, 0, 0, LKK * 16,   // ksplit > K: lo only
                Vt, (long)DD * LKK, LKK,
                LKK, 1,
                (float*)0, 0, 0,
                Rh, (long)LQ * DD, DD,
                (const float*)0, partialB, 8);
            _Float16* qn = (h == 0) ? Qpong : (h == 1) ? Qping : (_Float16*)0;
            float* fo = (h == 2) ? outQ : (float*)0;
            gemm_pc_256x128<<<gP, dim3(512), 0, stream>>>(
                qcur, (long)LQ * DD, DD,
                Rh, (long)LQ * DD, DD, DD,            // ksplit = 1024
                Wh, 0, 2 * DD,
                2 * DD, 2,
                fo, (long)LQ * DD, DD,
                qn, (long)LQ * DD, DD,
                bias, (const float*)0, 0);
        }
    } else if (ws_size >= NEED_R3) {
        // -------- proven R3 path --------
        char* ws = (char*)d_ws;
        _Float16* Kh  = (_Float16*)ws;
        _Float16* Vt  = (_Float16*)(ws + 67108864);
        _Float16* Wh  = (_Float16*)(ws + 134217728);
        _Float16* Rh  = (_Float16*)(ws + 138412032);
        _Float16* attn2 = (_Float16*)ws;
        float* Fout = (float*)(ws + 33554432);

        _Float16* Qping = (_Float16*)d_out;
        _Float16* Qpong = Qping + (size_t)NB * LQ * DD;
        float* S = (float*)((char*)d_out + 33554432);
        _Float16* P = (_Float16*)S;
        float* partialB = (float*)((char*)d_out + 73400320);
        float* invB     = (float*)((char*)d_out + 73924608);

        cvt_f32_to_f16<<<4096, blk, 0, stream>>>(Q, Qping, (long)NB * LQ * DD);
        cvt_f32_to_f16<<<16384, blk, 0, stream>>>(Km, Kh, (long)NB * LKK * DD);
        cvt_f32_to_f16<<<1024, blk, 0, stream>>>(W, Wh, (long)DD * 2 * DD);
        transpose_cvt_v<<<dim3(DD / 64, LKK / 64, NB), blk, 0, stream>>>(V, Vt);

        dim3 gS(LKK / 128, LQ / 128, NB);
        dim3 gR(DD / 128, LQ / 128, NB);

        for (int h = 0; h < 3; ++h) {
            _Float16* qcur = (h == 1) ? Qpong : Qping;
            if (h < 2) {
                gemm_f16_nt<<<gS, blk, 0, stream>>>(
                    qcur, (long)LQ * DD, DD, (const _Float16*)0, 0, 0, DD,
                    Kh, (long)LKK * DD, DD, DD,
                    0, scale, (float*)0, 0, 0,
                    P, (long)LQ * LKK, LKK, (const float*)0,
                    partialB, (const float*)0, 16);
                make_inv<<<32, blk, 0, stream>>>(partialB, invB);
                gemm_f16_nt<<<gR, blk, 0, stream>>>(
                    P, (long)LQ * LKK, LKK,
                    (const _Float16*)0, 0, 0, LKK,
                    Vt, (long)DD * LKK, LKK, LKK,
                    1, 1.0f, (float*)0, 0, 0,
                    Rh, (long)LQ * DD, DD, (const float*)0,
                    (float*)0, invB, 0);
            } else {
                gemm_f16_nt<<<gS, blk, 0, stream>>>(
                    qcur, (long)LQ * DD, DD, (const _Float16*)0, 0, 0, DD,
                    Kh, (long)LKK * DD, DD, DD,
                    4, scale, S, (long)LQ * LKK, LKK,
                    (_Float16*)0, 0, 0, (const float*)0,
                    (float*)0, (const float*)0, 0);
                softmax_rows2<<<NB * LQ, blk, 0, stream>>>(S, attn2, 2048L, 1);
                gemm_f16_nt<<<gR, blk, 0, stream>>>(
                    attn2, (long)LQ * LKK, LKK,
                    (const _Float16*)0, 0, 0, LKK,
                    Vt, (long)DD * LKK, LKK, LKK,
                    1, 1.0f, (float*)0, 0, 0,
                    Rh, (long)LQ * DD, DD, (const float*)0,
                    (float*)0, (const float*)0, 0);
            }
            _Float16* qn = (h == 0) ? Qpong : (h == 1) ? Qping : (_Float16*)0;
            float* fo = (h == 2) ? Fout : (float*)0;
            gemm_f16_nt<<<gR, blk, 0, stream>>>(
                qcur, (long)LQ * DD, DD,
                Rh, (long)LQ * DD, DD, DD,
                Wh, 0, 2 * DD, 2 * DD,
                2, 1.0f, fo, (long)LQ * DD, DD,
                qn, (long)LQ * DD, DD, bias,
                (float*)0, (const float*)0, 0);
        }
        hipMemcpyAsync(d_out, Fout, 33554432ULL, hipMemcpyDeviceToDevice, stream);
    } else {
        // -------- round-1 f32 fallback --------
        float* outQ = (float*)d_out;
        float* S    = outQ + (size_t)NB * LQ * DD;
        float* R    = (float*)d_ws;
        float* T    = R + (size_t)NB * LQ * DD;
        dim3 gS(LKK / TN, LQ / TM, NB);
        dim3 gR(DD / TN, LQ / TM, NB);
        for (int h = 0; h < 3; ++h) {
            const float* Qh = (h == 0) ? Q : (h == 1 ? (const float*)T : (const float*)outQ);
            float* cout = (h == 1) ? outQ : T;
            gemm_nt_k<<<gS, blk, 0, stream>>>(Qh, DD, (long)LQ * DD, Km, DD, (long)LKK * DD,
                                              S, LKK, (long)LQ * LKK, DD, scale);
            softmax_rows<<<NB * LQ, blk, 0, stream>>>(S);
            gemm_nn_k<<<gR, blk, 0, stream>>>(S, LKK, (long)LQ * LKK, V, DD, (long)LKK * DD,
                                              R, DD, (long)LQ * DD, LKK);
            gemm_cat_k<<<gR, blk, 0, stream>>>(Qh, R, W, bias, cout);
        }
        hipMemcpyAsync(outQ, T, (size_t)NB * LQ * DD * sizeof(float),
                       hipMemcpyDeviceToDevice, stream);
    }
}